// Round 1
// baseline (4943.568 us; speedup 1.0000x reference)
//
#include <hip/hip_runtime.h>
#include <math.h>

// ---------------------------------------------------------------------------
// GraphUNet + GAT pipeline, fp32 correctness-first implementation.
// N=4096, E=65536, IN=3, H=64, OUT=128, HEADS=4
// ---------------------------------------------------------------------------

#define TPB 256

// ---------------- adjacency build ----------------
__global__ void scatter_edges(const int* __restrict__ ei, int E, float* A, int n) {
    int e = blockIdx.x * TPB + threadIdx.x;
    if (e >= E) return;
    int src = ei[e];
    int dst = ei[E + e];
    atomicAdd(&A[(size_t)dst * n + src], 1.0f);
}

// ---------------- generic GEMM: C = A[MxK] @ B[KxN] (+bias) ----------------
__global__ void gemm_bias(const float* __restrict__ A, const float* __restrict__ B,
                          const float* __restrict__ bias, float* __restrict__ C,
                          int M, int K, int N) {
    __shared__ float As[16][65];
    __shared__ float Bs[16][65];
    int tx = threadIdx.x & 15, ty = threadIdx.x >> 4;
    int i0 = blockIdx.y * 64, j0 = blockIdx.x * 64;
    float acc[4][4] = {};
    for (int k0 = 0; k0 < K; k0 += 16) {
        for (int t = threadIdx.x; t < 1024; t += TPB) {
            int r = t >> 4, c = t & 15;
            int gi = i0 + r, gk = k0 + c;
            As[c][r] = (gi < M && gk < K) ? A[(size_t)gi * K + gk] : 0.f;
        }
        for (int t = threadIdx.x; t < 1024; t += TPB) {
            int r = t >> 6, c = t & 63;
            int gk = k0 + r, gj = j0 + c;
            Bs[r][c] = (gk < K && gj < N) ? B[(size_t)gk * N + gj] : 0.f;
        }
        __syncthreads();
        for (int kk = 0; kk < 16; ++kk) {
            float a[4], b[4];
#pragma unroll
            for (int u = 0; u < 4; ++u) a[u] = As[kk][ty * 4 + u];
#pragma unroll
            for (int v = 0; v < 4; ++v) b[v] = Bs[kk][tx * 4 + v];
#pragma unroll
            for (int u = 0; u < 4; ++u)
#pragma unroll
                for (int v = 0; v < 4; ++v) acc[u][v] += a[u] * b[v];
        }
        __syncthreads();
    }
    for (int u = 0; u < 4; ++u)
        for (int v = 0; v < 4; ++v) {
            int gi = i0 + ty * 4 + u, gj = j0 + tx * 4 + v;
            if (gi < M && gj < N) {
                float val = acc[u][v];
                if (bias) val += bias[gj];
                C[(size_t)gi * N + gj] = val;
            }
        }
}

// ---------------- augment: C = (A+I)@(A+I), diag(C)=0, n%64==0 -------------
__global__ void augment_gemm(const float* __restrict__ A, float* __restrict__ C, int n) {
    __shared__ float As[16][65];
    __shared__ float Bs[16][65];
    int tx = threadIdx.x & 15, ty = threadIdx.x >> 4;
    int i0 = blockIdx.y * 64, j0 = blockIdx.x * 64;
    float acc[4][4] = {};
    for (int k0 = 0; k0 < n; k0 += 16) {
        for (int t = threadIdx.x; t < 1024; t += TPB) {
            int r = t >> 4, c = t & 15;
            float v = A[(size_t)(i0 + r) * n + (k0 + c)];
            if (i0 + r == k0 + c) v += 1.0f;
            As[c][r] = v;
        }
        for (int t = threadIdx.x; t < 1024; t += TPB) {
            int r = t >> 6, c = t & 63;
            float v = A[(size_t)(k0 + r) * n + (j0 + c)];
            if (k0 + r == j0 + c) v += 1.0f;
            Bs[r][c] = v;
        }
        __syncthreads();
        for (int kk = 0; kk < 16; ++kk) {
            float a[4], b[4];
#pragma unroll
            for (int u = 0; u < 4; ++u) a[u] = As[kk][ty * 4 + u];
#pragma unroll
            for (int v = 0; v < 4; ++v) b[v] = Bs[kk][tx * 4 + v];
#pragma unroll
            for (int u = 0; u < 4; ++u)
#pragma unroll
                for (int v = 0; v < 4; ++v) acc[u][v] += a[u] * b[v];
        }
        __syncthreads();
    }
    for (int u = 0; u < 4; ++u)
        for (int v = 0; v < 4; ++v) {
            int gi = i0 + ty * 4 + u, gj = j0 + tx * 4 + v;
            C[(size_t)gi * n + gj] = (gi == gj) ? 0.0f : acc[u][v];
        }
}

// ---------------- GCN helpers ----------------
// dinv[i] = 1/sqrt(rowsum(A)+ (A[i,i]==0?2:0)); selfw[i] = (A[i,i]==0?2:0)
__global__ void rowsum_dinv(const float* __restrict__ A, int n, float* dinv, float* selfw) {
    int i = blockIdx.x;
    const float* row = A + (size_t)i * n;
    float s = 0.f;
    for (int j = threadIdx.x; j < n; j += TPB) s += row[j];
    for (int o = 32; o; o >>= 1) s += __shfl_xor(s, o);
    __shared__ float sh[4];
    if ((threadIdx.x & 63) == 0) sh[threadIdx.x >> 6] = s;
    __syncthreads();
    if (threadIdx.x == 0) {
        float tot = sh[0] + sh[1] + sh[2] + sh[3];
        float d = row[i];
        float sw = (d == 0.f) ? 2.f : 0.f;
        dinv[i] = 1.0f / sqrtf(tot + sw);
        selfw[i] = sw;
    }
}

__global__ void scale_rows(const float* __restrict__ xw, const float* __restrict__ dinv,
                           float* __restrict__ y, int n, int f) {
    int id = blockIdx.x * TPB + threadIdx.x;
    if (id >= n * f) return;
    int r = id / f;
    y[id] = xw[id] * dinv[r];
}

// out[i,c] = dinv[i]*(sum_j A[i,j]*y[j,c] + selfw[i]*y[i,c]) + b[c]; opt relu
__global__ void gcn_spmm(const float* __restrict__ A, const float* __restrict__ y,
                         const float* __restrict__ dinv, const float* __restrict__ selfw,
                         const float* __restrict__ b, float* __restrict__ out,
                         int n, int f, int relu) {
    __shared__ float As[4][64];
    __shared__ float ys[64][64];
    int tx = threadIdx.x;   // 0..63 : column in tile
    int ty = threadIdx.y;   // 0..3  : row
    int tid = ty * 64 + tx;
    int i0 = blockIdx.x * 4;
    int c0 = blockIdx.y * 64;
    float sum = 0.f;
    for (int j0 = 0; j0 < n; j0 += 64) {
        if (tid < 256) {
            int r = tid >> 6, jj = tid & 63;
            As[r][jj] = A[(size_t)(i0 + r) * n + (j0 + jj)];
        }
        for (int t = tid; t < 64 * 64; t += 256) {
            int jj = t >> 6, cc = t & 63;
            ys[jj][cc] = y[(size_t)(j0 + jj) * f + (c0 + cc)];
        }
        __syncthreads();
#pragma unroll 16
        for (int jj = 0; jj < 64; ++jj) sum += As[ty][jj] * ys[jj][tx];
        __syncthreads();
    }
    int i = i0 + ty, c = c0 + tx;
    float yself = y[(size_t)i * f + c];
    float v = dinv[i] * (sum + selfw[i] * yself) + b[c];
    if (relu) v = fmaxf(v, 0.f);
    out[(size_t)i * f + c] = v;
}

// ---------------- pooling ----------------
__global__ void vec_norm(const float* __restrict__ p, int f, float* out) {
    float s = 0.f;
    for (int c = threadIdx.x; c < f; c += 64) { float v = p[c]; s += v * v; }
    for (int o = 32; o; o >>= 1) s += __shfl_xor(s, o);
    if (threadIdx.x == 0) out[0] = sqrtf(s);
}

__global__ void score_kernel(const float* __restrict__ x, const float* __restrict__ p,
                             const float* __restrict__ nrm, float* __restrict__ s, int n, int f) {
    int i = blockIdx.x * TPB + threadIdx.x;
    if (i >= n) return;
    float a = 0.f;
    for (int c = 0; c < f; ++c) a += x[(size_t)i * f + c] * p[c];
    s[i] = tanhf(a / nrm[0]);
}

// rank = #(s[j] > s[i]) + #(s[j]==s[i] && j<i)  -> exact lax.top_k order
__global__ void rank_topk(const float* __restrict__ s, int n, int k,
                          int* __restrict__ perm, float* __restrict__ vals) {
    int i = blockIdx.x * TPB + threadIdx.x;
    if (i >= n) return;
    float si = s[i];
    int r = 0;
    for (int j = 0; j < n; ++j) {
        float sj = s[j];
        r += (sj > si) || (sj == si && j < i);
    }
    if (r < k) { perm[r] = i; vals[r] = si; }
}

__global__ void gather_adj(const float* __restrict__ Asrc, int n, const int* __restrict__ perm,
                           int k, float* __restrict__ Adst) {
    int id = blockIdx.x * TPB + threadIdx.x;
    if (id >= k * k) return;
    int r = id / k, c = id - r * k;
    Adst[(size_t)id] = Asrc[(size_t)perm[r] * n + perm[c]];
}

__global__ void gather_feat(const float* __restrict__ x, const int* __restrict__ perm,
                            const float* __restrict__ vals, int k, int f, float* __restrict__ h) {
    int id = blockIdx.x * TPB + threadIdx.x;
    if (id >= k * f) return;
    int r = id / f, c = id - r * f;
    h[id] = x[(size_t)perm[r] * f + c] * vals[r];
}

// ---------------- up path ----------------
__global__ void copy_k(const float* __restrict__ s, float* __restrict__ d, int n) {
    int id = blockIdx.x * TPB + threadIdx.x;
    if (id < n) d[id] = s[id];
}

__global__ void scatter_add_rows(const float* __restrict__ s, const int* __restrict__ perm,
                                 int k, int f, float* __restrict__ t) {
    int id = blockIdx.x * TPB + threadIdx.x;
    if (id >= k * f) return;
    int r = id / f, c = id - r * f;
    t[(size_t)perm[r] * f + c] += s[id];
}

// ---------------- layernorm (f=128, eps=1e-6) ----------------
__global__ void layernorm(const float* __restrict__ h, const float* __restrict__ g,
                          const float* __restrict__ b, float* __restrict__ u, int n) {
    int i = blockIdx.x;
    int t = threadIdx.x;  // 128 threads
    float v = h[(size_t)i * 128 + t];
    __shared__ float s0[2], s1[2];
    float sum = v;
    for (int o = 32; o; o >>= 1) sum += __shfl_xor(sum, o);
    if ((t & 63) == 0) s0[t >> 6] = sum;
    __syncthreads();
    float mu = (s0[0] + s0[1]) * (1.0f / 128.0f);
    float d = v - mu;
    float sq = d * d;
    for (int o = 32; o; o >>= 1) sq += __shfl_xor(sq, o);
    if ((t & 63) == 0) s1[t >> 6] = sq;
    __syncthreads();
    float var = (s1[0] + s1[1]) * (1.0f / 128.0f);
    u[(size_t)i * 128 + t] = d / sqrtf(var + 1e-6f) * g[t] + b[t];
}

// ---------------- GAT ----------------
// es[j,h] = <h[j,h,:], asrc[h,:]>, ed[j,h] = <h[j,h,:], adst[h,:]>
__global__ void attn_coef(const float* __restrict__ hf, const float* __restrict__ asrc,
                          const float* __restrict__ adst, float* __restrict__ es,
                          float* __restrict__ ed, int n, int heads) {
    int id = blockIdx.x * TPB + threadIdx.x;
    if (id >= n * heads) return;
    int j = id / heads, h = id - j * heads;
    const float* hp = hf + (size_t)j * heads * 128 + h * 128;
    float a = 0.f, d = 0.f;
    for (int c = 0; c < 128; ++c) {
        float v = hp[c];
        a += v * asrc[h * 128 + c];
        d += v * adst[h * 128 + c];
    }
    es[id] = a;
    ed[id] = d;
}

// one block per destination node; sparse softmax-attention over in-neighbors
#define MAXD 1024
__global__ void gat_kernel(const float* __restrict__ A0, int n, const float* __restrict__ hf,
                           const float* __restrict__ es, const float* __restrict__ ed,
                           const float* __restrict__ bias, const float* __restrict__ resid,
                           float* __restrict__ out, int heads, int mode) {
    int i = blockIdx.x;
    int tid = threadIdx.x;
    __shared__ int cnt;
    __shared__ int idx[MAXD];
    __shared__ float lg[MAXD * 4];
    __shared__ float hmax[4], hsum[4];
    if (tid == 0) cnt = 0;
    __syncthreads();
    const float* row = A0 + (size_t)i * n;
    for (int j = tid; j < n; j += TPB) {
        if (row[j] > 0.f || j == i) {
            int p = atomicAdd(&cnt, 1);
            if (p < MAXD) idx[p] = j;
        }
    }
    __syncthreads();
    int m = min(cnt, MAXD);
    for (int t = tid; t < m * heads; t += TPB) {
        int jl = t / heads, h = t - jl * heads;
        float l = ed[i * heads + h] + es[idx[jl] * heads + h];
        lg[jl * heads + h] = (l > 0.f) ? l : 0.2f * l;
    }
    __syncthreads();
    int h = tid >> 6, lane = tid & 63;
    if (h < heads) {
        float mx = -3.4e38f;
        for (int jl = lane; jl < m; jl += 64) mx = fmaxf(mx, lg[jl * heads + h]);
        for (int o = 32; o; o >>= 1) mx = fmaxf(mx, __shfl_xor(mx, o));
        if (lane == 0) hmax[h] = mx;
    }
    __syncthreads();
    if (h < heads) {
        float mx = hmax[h];
        float sm = 0.f;
        for (int jl = lane; jl < m; jl += 64) {
            float p = expf(lg[jl * heads + h] - mx);
            lg[jl * heads + h] = p;
            sm += p;
        }
        for (int o = 32; o; o >>= 1) sm += __shfl_xor(sm, o);
        if (lane == 0) hsum[h] = sm;
    }
    __syncthreads();
    int width = heads * 128;
    for (int o = tid; o < width; o += TPB) {
        int hh = o >> 7;
        float acc = 0.f;
        for (int jl = 0; jl < m; ++jl)
            acc += lg[jl * heads + hh] * hf[(size_t)idx[jl] * width + o];
        float v = acc / hsum[hh] + bias[o];
        if (mode == 0) v = (v > 0.f) ? v : expm1f(v);          // ELU
        else v += resid[(size_t)i * width + o];                 // + residual
        out[(size_t)i * width + o] = v;
    }
}

// ---------------------------------------------------------------------------
static inline int cdiv(int a, int b) { return (a + b - 1) / b; }

static void run_gcn(hipStream_t stream, const float* A, int n, const float* xin, int fin,
                    const float* W, const float* b, int fout, float* xw, float* y,
                    float* dinv, float* selfw, float* out, int relu) {
    gemm_bias<<<dim3(cdiv(fout, 64), cdiv(n, 64)), TPB, 0, stream>>>(xin, W, nullptr, xw, n, fin, fout);
    rowsum_dinv<<<n, TPB, 0, stream>>>(A, n, dinv, selfw);
    scale_rows<<<cdiv(n * fout, TPB), TPB, 0, stream>>>(xw, dinv, y, n, fout);
    gcn_spmm<<<dim3(n / 4, fout / 64), dim3(64, 4), 0, stream>>>(A, y, dinv, selfw, b, out, n, fout, relu);
}

extern "C" void kernel_launch(void* const* d_in, const int* in_sizes, int n_in,
                              void* d_out, int out_size, void* d_ws, size_t ws_size,
                              hipStream_t stream) {
    const float* x   = (const float*)d_in[0];
    const int*   ei  = (const int*)d_in[1];
    const float* w0  = (const float*)d_in[2];  const float* b0  = (const float*)d_in[3];
    const float* w1  = (const float*)d_in[4];  const float* b1  = (const float*)d_in[5];
    const float* w2  = (const float*)d_in[6];  const float* b2  = (const float*)d_in[7];
    const float* w3  = (const float*)d_in[8];  const float* b3  = (const float*)d_in[9];
    const float* p1  = (const float*)d_in[10];
    const float* p2  = (const float*)d_in[11];
    const float* p3  = (const float*)d_in[12];
    const float* uw0 = (const float*)d_in[13]; const float* ub0 = (const float*)d_in[14];
    const float* uw1 = (const float*)d_in[15]; const float* ub1 = (const float*)d_in[16];
    const float* uw2 = (const float*)d_in[17]; const float* ub2 = (const float*)d_in[18];
    const float* lng = (const float*)d_in[19]; const float* lnb = (const float*)d_in[20];
    const float* rw  = (const float*)d_in[21]; const float* rb  = (const float*)d_in[22];
    const float* g1w = (const float*)d_in[23];
    const float* g1as = (const float*)d_in[24]; const float* g1ad = (const float*)d_in[25];
    const float* g1b = (const float*)d_in[26];
    const float* g2w = (const float*)d_in[27];
    const float* g2as = (const float*)d_in[28]; const float* g2ad = (const float*)d_in[29];
    const float* g2b = (const float*)d_in[30];

    const int N = 4096, E = 65536;
    const int K1 = 2048, K2 = 1024, K3 = 512;

    // ---- workspace bump allocator (floats) ----
    float* base = (float*)d_ws;
    size_t off = 0;
    auto alloc = [&](size_t nf) { float* p = base + off; off += (nf + 63) & ~(size_t)63; return p; };

    float* A0   = alloc((size_t)N * N);
    float* Aaug = alloc((size_t)N * N);
    float* A1   = alloc((size_t)K1 * K1);
    float* A2   = alloc((size_t)K2 * K2);
    float* A3   = alloc((size_t)K3 * K3);
    float* x0   = alloc((size_t)N * 64);
    float* x1   = alloc((size_t)K1 * 64);
    float* x2   = alloc((size_t)K2 * 64);
    float* x3   = alloc((size_t)K3 * 64);
    float* h1   = alloc((size_t)K1 * 64);
    float* h2   = alloc((size_t)K2 * 64);
    float* h3   = alloc((size_t)K3 * 64);
    float* xw   = alloc((size_t)N * 128);
    float* yb   = alloc((size_t)N * 128);
    float* dinv = alloc(N);
    float* selfw= alloc(N);
    float* score= alloc(N);
    float* vals1= alloc(K1); float* vals2 = alloc(K2); float* vals3 = alloc(K3);
    int*   perm1= (int*)alloc(K1); int* perm2 = (int*)alloc(K2); int* perm3 = (int*)alloc(K3);
    float* t2   = alloc((size_t)K2 * 64);
    float* t1   = alloc((size_t)K1 * 64);
    float* t0   = alloc((size_t)N * 64);
    float* hfin = alloc((size_t)N * 128);
    float* u    = alloc((size_t)N * 128);
    float* resid= alloc((size_t)N * 128);
    float* hf1  = alloc((size_t)N * 512);
    float* es1  = alloc((size_t)N * 4); float* ed1 = alloc((size_t)N * 4);
    float* g1   = alloc((size_t)N * 512);
    float* hf2  = alloc((size_t)N * 128);
    float* es2  = alloc(N); float* ed2 = alloc(N);
    float* pn   = alloc(64);
    (void)ws_size; (void)n_in; (void)in_sizes; (void)out_size;

    // ---- A0 build ----
    hipMemsetAsync(A0, 0, (size_t)N * N * sizeof(float), stream);
    scatter_edges<<<cdiv(E, TPB), TPB, 0, stream>>>(ei, E, A0, N);

    // ---- down path ----
    run_gcn(stream, A0, N, x, 3, w0, b0, 64, xw, yb, dinv, selfw, x0, 1);

    // level 1
    augment_gemm<<<dim3(N / 64, N / 64), TPB, 0, stream>>>(A0, Aaug, N);
    vec_norm<<<1, 64, 0, stream>>>(p1, 64, pn);
    score_kernel<<<cdiv(N, TPB), TPB, 0, stream>>>(x0, p1, pn, score, N, 64);
    rank_topk<<<cdiv(N, TPB), TPB, 0, stream>>>(score, N, K1, perm1, vals1);
    gather_adj<<<cdiv(K1 * K1, TPB), TPB, 0, stream>>>(Aaug, N, perm1, K1, A1);
    gather_feat<<<cdiv(K1 * 64, TPB), TPB, 0, stream>>>(x0, perm1, vals1, K1, 64, h1);
    run_gcn(stream, A1, K1, h1, 64, w1, b1, 64, xw, yb, dinv, selfw, x1, 1);

    // level 2
    augment_gemm<<<dim3(K1 / 64, K1 / 64), TPB, 0, stream>>>(A1, Aaug, K1);
    vec_norm<<<1, 64, 0, stream>>>(p2, 64, pn);
    score_kernel<<<cdiv(K1, TPB), TPB, 0, stream>>>(x1, p2, pn, score, K1, 64);
    rank_topk<<<cdiv(K1, TPB), TPB, 0, stream>>>(score, K1, K2, perm2, vals2);
    gather_adj<<<cdiv(K2 * K2, TPB), TPB, 0, stream>>>(Aaug, K1, perm2, K2, A2);
    gather_feat<<<cdiv(K2 * 64, TPB), TPB, 0, stream>>>(x1, perm2, vals2, K2, 64, h2);
    run_gcn(stream, A2, K2, h2, 64, w2, b2, 64, xw, yb, dinv, selfw, x2, 1);

    // level 3
    augment_gemm<<<dim3(K2 / 64, K2 / 64), TPB, 0, stream>>>(A2, Aaug, K2);
    vec_norm<<<1, 64, 0, stream>>>(p3, 64, pn);
    score_kernel<<<cdiv(K2, TPB), TPB, 0, stream>>>(x2, p3, pn, score, K2, 64);
    rank_topk<<<cdiv(K2, TPB), TPB, 0, stream>>>(score, K2, K3, perm3, vals3);
    gather_adj<<<cdiv(K3 * K3, TPB), TPB, 0, stream>>>(Aaug, K2, perm3, K3, A3);
    gather_feat<<<cdiv(K3 * 64, TPB), TPB, 0, stream>>>(x2, perm3, vals3, K3, 64, h3);
    run_gcn(stream, A3, K3, h3, 64, w3, b3, 64, xw, yb, dinv, selfw, x3, 1);

    // ---- up path ----
    copy_k<<<cdiv(K2 * 64, TPB), TPB, 0, stream>>>(x2, t2, K2 * 64);
    scatter_add_rows<<<cdiv(K3 * 64, TPB), TPB, 0, stream>>>(x3, perm3, K3, 64, t2);
    run_gcn(stream, A2, K2, t2, 64, uw0, ub0, 64, xw, yb, dinv, selfw, h2, 1);

    copy_k<<<cdiv(K1 * 64, TPB), TPB, 0, stream>>>(x1, t1, K1 * 64);
    scatter_add_rows<<<cdiv(K2 * 64, TPB), TPB, 0, stream>>>(h2, perm2, K2, 64, t1);
    run_gcn(stream, A1, K1, t1, 64, uw1, ub1, 64, xw, yb, dinv, selfw, h1, 1);

    copy_k<<<cdiv(N * 64, TPB), TPB, 0, stream>>>(x0, t0, N * 64);
    scatter_add_rows<<<cdiv(K1 * 64, TPB), TPB, 0, stream>>>(h1, perm1, K1, 64, t0);
    run_gcn(stream, A0, N, t0, 64, uw2, ub2, 128, xw, yb, dinv, selfw, hfin, 0);

    // ---- layernorm + residual ----
    layernorm<<<N, 128, 0, stream>>>(hfin, lng, lnb, u, N);
    gemm_bias<<<dim3(cdiv(128, 64), cdiv(N, 64)), TPB, 0, stream>>>(u, rw, rb, resid, N, 128, 128);

    // ---- GAT layer 1 (4 heads, concat, ELU) ----
    gemm_bias<<<dim3(cdiv(512, 64), cdiv(N, 64)), TPB, 0, stream>>>(u, g1w, nullptr, hf1, N, 128, 512);
    attn_coef<<<cdiv(N * 4, TPB), TPB, 0, stream>>>(hf1, g1as, g1ad, es1, ed1, N, 4);
    gat_kernel<<<N, TPB, 0, stream>>>(A0, N, hf1, es1, ed1, g1b, nullptr, g1, 4, 0);

    // ---- GAT layer 2 (1 head) + residual ----
    gemm_bias<<<dim3(cdiv(128, 64), cdiv(N, 64)), TPB, 0, stream>>>(g1, g2w, nullptr, hf2, N, 512, 128);
    attn_coef<<<cdiv(N, TPB), TPB, 0, stream>>>(hf2, g2as, g2ad, es2, ed2, N, 1);
    gat_kernel<<<N, TPB, 0, stream>>>(A0, N, hf2, es2, ed2, g2b, resid, (float*)d_out, 1, 1);
}

// Round 2
// 1716.760 us; speedup vs baseline: 2.8796x; 2.8796x over previous
//
#include <hip/hip_runtime.h>
#include <math.h>

// ---------------------------------------------------------------------------
// GraphUNet + GAT pipeline. N=4096, E=65536, IN=3, H=64, OUT=128, HEADS=4
// Round 2: augment via gathered-submatrix bf16 MFMA GEMM (exact: small-int
// entries < 256 are bf16-exact; fp32 MFMA accumulation exact). rank_topk via
// LDS-staged scores.
// ---------------------------------------------------------------------------

#define TPB 256

typedef __attribute__((ext_vector_type(8))) short bf16x8;
typedef __attribute__((ext_vector_type(4))) float f32x4;

__device__ inline ushort f32_to_bf16(float v) {
    unsigned b = __float_as_uint(v);
    return (ushort)((b + 0x7FFF + ((b >> 16) & 1)) >> 16);
}

// ---------------- adjacency build ----------------
__global__ void scatter_edges(const int* __restrict__ ei, int E, float* A, int n) {
    int e = blockIdx.x * TPB + threadIdx.x;
    if (e >= E) return;
    int src = ei[e];
    int dst = ei[E + e];
    atomicAdd(&A[(size_t)dst * n + src], 1.0f);
}

// ---------------- generic GEMM: C = A[MxK] @ B[KxN] (+bias) ----------------
__global__ void gemm_bias(const float* __restrict__ A, const float* __restrict__ B,
                          const float* __restrict__ bias, float* __restrict__ C,
                          int M, int K, int N) {
    __shared__ float As[16][65];
    __shared__ float Bs[16][65];
    int tx = threadIdx.x & 15, ty = threadIdx.x >> 4;
    int i0 = blockIdx.y * 64, j0 = blockIdx.x * 64;
    float acc[4][4] = {};
    for (int k0 = 0; k0 < K; k0 += 16) {
        for (int t = threadIdx.x; t < 1024; t += TPB) {
            int r = t >> 4, c = t & 15;
            int gi = i0 + r, gk = k0 + c;
            As[c][r] = (gi < M && gk < K) ? A[(size_t)gi * K + gk] : 0.f;
        }
        for (int t = threadIdx.x; t < 1024; t += TPB) {
            int r = t >> 6, c = t & 63;
            int gk = k0 + r, gj = j0 + c;
            Bs[r][c] = (gk < K && gj < N) ? B[(size_t)gk * N + gj] : 0.f;
        }
        __syncthreads();
        for (int kk = 0; kk < 16; ++kk) {
            float a[4], b[4];
#pragma unroll
            for (int u = 0; u < 4; ++u) a[u] = As[kk][ty * 4 + u];
#pragma unroll
            for (int v = 0; v < 4; ++v) b[v] = Bs[kk][tx * 4 + v];
#pragma unroll
            for (int u = 0; u < 4; ++u)
#pragma unroll
                for (int v = 0; v < 4; ++v) acc[u][v] += a[u] * b[v];
        }
        __syncthreads();
    }
    for (int u = 0; u < 4; ++u)
        for (int v = 0; v < 4; ++v) {
            int gi = i0 + ty * 4 + u, gj = j0 + tx * 4 + v;
            if (gi < M && gj < N) {
                float val = acc[u][v];
                if (bias) val += bias[gj];
                C[(size_t)gi * N + gj] = val;
            }
        }
}

// ---------------- augment path (bf16, gathered submatrix) ----------------
// T[c][t] = bf16( A[t][c] + (t==c) )   -- transpose of (A+I)
__global__ void transpose_aug(const float* __restrict__ A, ushort* __restrict__ T, int n) {
    __shared__ float tile[64][65];
    int c0 = blockIdx.x * 64, r0 = blockIdx.y * 64;
    for (int t = threadIdx.x; t < 4096; t += TPB) {
        int r = t >> 6, c = t & 63;
        float v = A[(size_t)(r0 + r) * n + (c0 + c)];
        if (r0 + r == c0 + c) v += 1.0f;
        tile[c][r] = v;
    }
    __syncthreads();
    for (int t = threadIdx.x; t < 4096; t += TPB) {
        int c = t >> 6, r = t & 63;
        T[(size_t)(c0 + c) * n + (r0 + r)] = f32_to_bf16(tile[c][r]);
    }
}

// Ag[r][t] = bf16( A[perm[r]][t] + (perm[r]==t) )
__global__ void gather_rows_aug(const float* __restrict__ A, const int* __restrict__ perm,
                                ushort* __restrict__ Ag, int n, int rows) {
    int id = blockIdx.x * TPB + threadIdx.x;
    if (id >= rows * n) return;
    int r = id / n, t = id - r * n;
    int pr = perm[r];
    float v = A[(size_t)pr * n + t];
    if (pr == t) v += 1.0f;
    Ag[id] = f32_to_bf16(v);
}

// Bg[c][t] = T[perm[c]][t]
__global__ void gather_rows_u16(const ushort* __restrict__ T, const int* __restrict__ perm,
                                ushort* __restrict__ Bg, int n, int rows) {
    int id = blockIdx.x * TPB + threadIdx.x;
    if (id >= rows * n) return;
    int r = id / n, t = id - r * n;
    Bg[id] = T[(size_t)perm[r] * n + t];
}

// C[r][c] = sum_t Ag[r][t]*Bg[c][t]; diag zeroed. M=N=k (mult of 64), K mult of 64.
#define LDK 88
__global__ void __launch_bounds__(256)
gemm_bt_bf16(const ushort* __restrict__ Ag, const ushort* __restrict__ Bg,
             float* __restrict__ C, int K, int ldc) {
    __shared__ __align__(16) ushort As[64 * LDK];
    __shared__ __align__(16) ushort Bs[64 * LDK];
    int tid = threadIdx.x;
    int wave = tid >> 6, lane = tid & 63;
    int wr = wave >> 1, wc = wave & 1;
    int m = lane & 15, quad = lane >> 4;
    int i0 = blockIdx.y * 64, j0 = blockIdx.x * 64;
    f32x4 acc[2][2];
#pragma unroll
    for (int a = 0; a < 2; ++a)
#pragma unroll
        for (int b = 0; b < 2; ++b) acc[a][b] = (f32x4){0.f, 0.f, 0.f, 0.f};
    const ushort* Ab = Ag + (size_t)i0 * K;
    const ushort* Bb = Bg + (size_t)j0 * K;
    for (int k0 = 0; k0 < K; k0 += 64) {
#pragma unroll
        for (int v = 0; v < 2; ++v) {
            int idx = tid + (v << 8);          // 0..511
            int r = idx >> 3, c8 = idx & 7;
            *(uint4*)&As[r * LDK + c8 * 8] = *(const uint4*)&Ab[(size_t)r * K + k0 + c8 * 8];
            *(uint4*)&Bs[r * LDK + c8 * 8] = *(const uint4*)&Bb[(size_t)r * K + k0 + c8 * 8];
        }
        __syncthreads();
#pragma unroll
        for (int kk = 0; kk < 2; ++kk) {
            bf16x8 af[2], bfr[2];
#pragma unroll
            for (int mi = 0; mi < 2; ++mi)
                af[mi] = *(const bf16x8*)&As[(wr * 32 + mi * 16 + m) * LDK + kk * 32 + quad * 8];
#pragma unroll
            for (int ni = 0; ni < 2; ++ni)
                bfr[ni] = *(const bf16x8*)&Bs[(wc * 32 + ni * 16 + m) * LDK + kk * 32 + quad * 8];
#pragma unroll
            for (int mi = 0; mi < 2; ++mi)
#pragma unroll
                for (int ni = 0; ni < 2; ++ni)
                    acc[mi][ni] = __builtin_amdgcn_mfma_f32_16x16x32_bf16(
                        af[mi], bfr[ni], acc[mi][ni], 0, 0, 0);
        }
        __syncthreads();
    }
#pragma unroll
    for (int mi = 0; mi < 2; ++mi)
#pragma unroll
        for (int ni = 0; ni < 2; ++ni)
#pragma unroll
            for (int r = 0; r < 4; ++r) {
                int gi = i0 + wr * 32 + mi * 16 + quad * 4 + r;
                int gj = j0 + wc * 32 + ni * 16 + m;
                C[(size_t)gi * ldc + gj] = (gi == gj) ? 0.f : acc[mi][ni][r];
            }
}

// ---------------- GCN helpers ----------------
__global__ void rowsum_dinv(const float* __restrict__ A, int n, float* dinv, float* selfw) {
    int i = blockIdx.x;
    const float* row = A + (size_t)i * n;
    float s = 0.f;
    for (int j = threadIdx.x; j < n; j += TPB) s += row[j];
    for (int o = 32; o; o >>= 1) s += __shfl_xor(s, o);
    __shared__ float sh[4];
    if ((threadIdx.x & 63) == 0) sh[threadIdx.x >> 6] = s;
    __syncthreads();
    if (threadIdx.x == 0) {
        float tot = sh[0] + sh[1] + sh[2] + sh[3];
        float d = row[i];
        float sw = (d == 0.f) ? 2.f : 0.f;
        dinv[i] = 1.0f / sqrtf(tot + sw);
        selfw[i] = sw;
    }
}

__global__ void scale_rows(const float* __restrict__ xw, const float* __restrict__ dinv,
                           float* __restrict__ y, int n, int f) {
    int id = blockIdx.x * TPB + threadIdx.x;
    if (id >= n * f) return;
    int r = id / f;
    y[id] = xw[id] * dinv[r];
}

__global__ void gcn_spmm(const float* __restrict__ A, const float* __restrict__ y,
                         const float* __restrict__ dinv, const float* __restrict__ selfw,
                         const float* __restrict__ b, float* __restrict__ out,
                         int n, int f, int relu) {
    __shared__ float As[4][64];
    __shared__ float ys[64][64];
    int tx = threadIdx.x;
    int ty = threadIdx.y;
    int tid = ty * 64 + tx;
    int i0 = blockIdx.x * 4;
    int c0 = blockIdx.y * 64;
    float sum = 0.f;
    for (int j0 = 0; j0 < n; j0 += 64) {
        if (tid < 256) {
            int r = tid >> 6, jj = tid & 63;
            As[r][jj] = A[(size_t)(i0 + r) * n + (j0 + jj)];
        }
        for (int t = tid; t < 64 * 64; t += 256) {
            int jj = t >> 6, cc = t & 63;
            ys[jj][cc] = y[(size_t)(j0 + jj) * f + (c0 + cc)];
        }
        __syncthreads();
#pragma unroll 16
        for (int jj = 0; jj < 64; ++jj) sum += As[ty][jj] * ys[jj][tx];
        __syncthreads();
    }
    int i = i0 + ty, c = c0 + tx;
    float yself = y[(size_t)i * f + c];
    float v = dinv[i] * (sum + selfw[i] * yself) + b[c];
    if (relu) v = fmaxf(v, 0.f);
    out[(size_t)i * f + c] = v;
}

// ---------------- pooling ----------------
__global__ void vec_norm(const float* __restrict__ p, int f, float* out) {
    float s = 0.f;
    for (int c = threadIdx.x; c < f; c += 64) { float v = p[c]; s += v * v; }
    for (int o = 32; o; o >>= 1) s += __shfl_xor(s, o);
    if (threadIdx.x == 0) out[0] = sqrtf(s);
}

__global__ void score_kernel(const float* __restrict__ x, const float* __restrict__ p,
                             const float* __restrict__ nrm, float* __restrict__ s, int n, int f) {
    int i = blockIdx.x * TPB + threadIdx.x;
    if (i >= n) return;
    float a = 0.f;
    for (int c = 0; c < f; ++c) a += x[(size_t)i * f + c] * p[c];
    s[i] = tanhf(a / nrm[0]);
}

// rank = #(s[j] > s[i]) + #(s[j]==s[i] && j<i)  -> exact lax.top_k order
__global__ void rank_topk(const float* __restrict__ s, int n, int k,
                          int* __restrict__ perm, float* __restrict__ vals) {
    extern __shared__ float ss[];
    for (int j = threadIdx.x; j < n; j += TPB) ss[j] = s[j];
    __syncthreads();
    int i = blockIdx.x * TPB + threadIdx.x;
    if (i >= n) return;
    float si = ss[i];
    int r = 0;
    for (int j = 0; j < n; ++j) {
        float sj = ss[j];
        r += (sj > si) || (sj == si && j < i);
    }
    if (r < k) { perm[r] = i; vals[r] = si; }
}

__global__ void gather_feat(const float* __restrict__ x, const int* __restrict__ perm,
                            const float* __restrict__ vals, int k, int f, float* __restrict__ h) {
    int id = blockIdx.x * TPB + threadIdx.x;
    if (id >= k * f) return;
    int r = id / f, c = id - r * f;
    h[id] = x[(size_t)perm[r] * f + c] * vals[r];
}

// ---------------- up path ----------------
__global__ void copy_k(const float* __restrict__ s, float* __restrict__ d, int n) {
    int id = blockIdx.x * TPB + threadIdx.x;
    if (id < n) d[id] = s[id];
}

__global__ void scatter_add_rows(const float* __restrict__ s, const int* __restrict__ perm,
                                 int k, int f, float* __restrict__ t) {
    int id = blockIdx.x * TPB + threadIdx.x;
    if (id >= k * f) return;
    int r = id / f, c = id - r * f;
    t[(size_t)perm[r] * f + c] += s[id];
}

// ---------------- layernorm (f=128, eps=1e-6) ----------------
__global__ void layernorm(const float* __restrict__ h, const float* __restrict__ g,
                          const float* __restrict__ b, float* __restrict__ u, int n) {
    int i = blockIdx.x;
    int t = threadIdx.x;  // 128 threads
    float v = h[(size_t)i * 128 + t];
    __shared__ float s0[2], s1[2];
    float sum = v;
    for (int o = 32; o; o >>= 1) sum += __shfl_xor(sum, o);
    if ((t & 63) == 0) s0[t >> 6] = sum;
    __syncthreads();
    float mu = (s0[0] + s0[1]) * (1.0f / 128.0f);
    float d = v - mu;
    float sq = d * d;
    for (int o = 32; o; o >>= 1) sq += __shfl_xor(sq, o);
    if ((t & 63) == 0) s1[t >> 6] = sq;
    __syncthreads();
    float var = (s1[0] + s1[1]) * (1.0f / 128.0f);
    u[(size_t)i * 128 + t] = d / sqrtf(var + 1e-6f) * g[t] + b[t];
}

// ---------------- GAT ----------------
__global__ void attn_coef(const float* __restrict__ hf, const float* __restrict__ asrc,
                          const float* __restrict__ adst, float* __restrict__ es,
                          float* __restrict__ ed, int n, int heads) {
    int id = blockIdx.x * TPB + threadIdx.x;
    if (id >= n * heads) return;
    int j = id / heads, h = id - j * heads;
    const float* hp = hf + (size_t)j * heads * 128 + h * 128;
    float a = 0.f, d = 0.f;
    for (int c = 0; c < 128; ++c) {
        float v = hp[c];
        a += v * asrc[h * 128 + c];
        d += v * adst[h * 128 + c];
    }
    es[id] = a;
    ed[id] = d;
}

#define MAXD 1024
__global__ void gat_kernel(const float* __restrict__ A0, int n, const float* __restrict__ hf,
                           const float* __restrict__ es, const float* __restrict__ ed,
                           const float* __restrict__ bias, const float* __restrict__ resid,
                           float* __restrict__ out, int heads, int mode) {
    int i = blockIdx.x;
    int tid = threadIdx.x;
    __shared__ int cnt;
    __shared__ int idx[MAXD];
    __shared__ float lg[MAXD * 4];
    __shared__ float hmax[4], hsum[4];
    if (tid == 0) cnt = 0;
    __syncthreads();
    const float* row = A0 + (size_t)i * n;
    for (int j = tid; j < n; j += TPB) {
        if (row[j] > 0.f || j == i) {
            int p = atomicAdd(&cnt, 1);
            if (p < MAXD) idx[p] = j;
        }
    }
    __syncthreads();
    int m = min(cnt, MAXD);
    for (int t = tid; t < m * heads; t += TPB) {
        int jl = t / heads, h = t - jl * heads;
        float l = ed[i * heads + h] + es[idx[jl] * heads + h];
        lg[jl * heads + h] = (l > 0.f) ? l : 0.2f * l;
    }
    __syncthreads();
    int h = tid >> 6, lane = tid & 63;
    if (h < heads) {
        float mx = -3.4e38f;
        for (int jl = lane; jl < m; jl += 64) mx = fmaxf(mx, lg[jl * heads + h]);
        for (int o = 32; o; o >>= 1) mx = fmaxf(mx, __shfl_xor(mx, o));
        if (lane == 0) hmax[h] = mx;
    }
    __syncthreads();
    if (h < heads) {
        float mx = hmax[h];
        float sm = 0.f;
        for (int jl = lane; jl < m; jl += 64) {
            float p = expf(lg[jl * heads + h] - mx);
            lg[jl * heads + h] = p;
            sm += p;
        }
        for (int o = 32; o; o >>= 1) sm += __shfl_xor(sm, o);
        if (lane == 0) hsum[h] = sm;
    }
    __syncthreads();
    int width = heads * 128;
    for (int o = tid; o < width; o += TPB) {
        int hh = o >> 7;
        float acc = 0.f;
        for (int jl = 0; jl < m; ++jl)
            acc += lg[jl * heads + hh] * hf[(size_t)idx[jl] * width + o];
        float v = acc / hsum[hh] + bias[o];
        if (mode == 0) v = (v > 0.f) ? v : expm1f(v);
        else v += resid[(size_t)i * width + o];
        out[(size_t)i * width + o] = v;
    }
}

// ---------------------------------------------------------------------------
static inline int cdiv(int a, int b) { return (a + b - 1) / b; }

static void run_gcn(hipStream_t stream, const float* A, int n, const float* xin, int fin,
                    const float* W, const float* b, int fout, float* xw, float* y,
                    float* dinv, float* selfw, float* out, int relu) {
    gemm_bias<<<dim3(cdiv(fout, 64), cdiv(n, 64)), TPB, 0, stream>>>(xin, W, nullptr, xw, n, fin, fout);
    rowsum_dinv<<<n, TPB, 0, stream>>>(A, n, dinv, selfw);
    scale_rows<<<cdiv(n * fout, TPB), TPB, 0, stream>>>(xw, dinv, y, n, fout);
    gcn_spmm<<<dim3(n / 4, fout / 64), dim3(64, 4), 0, stream>>>(A, y, dinv, selfw, b, out, n, fout, relu);
}

// augment submatrix: Anext[k x k] = gathered (A+I)@(A+I) with zeroed diag
static void run_augment(hipStream_t stream, const float* A, int n, const int* perm, int k,
                        ushort* Tbf, ushort* Agb, ushort* Bgb, float* Anext) {
    transpose_aug<<<dim3(n / 64, n / 64), TPB, 0, stream>>>(A, Tbf, n);
    gather_rows_aug<<<cdiv(k * n, TPB), TPB, 0, stream>>>(A, perm, Agb, n, k);
    gather_rows_u16<<<cdiv(k * n, TPB), TPB, 0, stream>>>(Tbf, perm, Bgb, n, k);
    gemm_bt_bf16<<<dim3(k / 64, k / 64), TPB, 0, stream>>>(Agb, Bgb, Anext, n, k);
}

extern "C" void kernel_launch(void* const* d_in, const int* in_sizes, int n_in,
                              void* d_out, int out_size, void* d_ws, size_t ws_size,
                              hipStream_t stream) {
    const float* x   = (const float*)d_in[0];
    const int*   ei  = (const int*)d_in[1];
    const float* w0  = (const float*)d_in[2];  const float* b0  = (const float*)d_in[3];
    const float* w1  = (const float*)d_in[4];  const float* b1  = (const float*)d_in[5];
    const float* w2  = (const float*)d_in[6];  const float* b2  = (const float*)d_in[7];
    const float* w3  = (const float*)d_in[8];  const float* b3  = (const float*)d_in[9];
    const float* p1  = (const float*)d_in[10];
    const float* p2  = (const float*)d_in[11];
    const float* p3  = (const float*)d_in[12];
    const float* uw0 = (const float*)d_in[13]; const float* ub0 = (const float*)d_in[14];
    const float* uw1 = (const float*)d_in[15]; const float* ub1 = (const float*)d_in[16];
    const float* uw2 = (const float*)d_in[17]; const float* ub2 = (const float*)d_in[18];
    const float* lng = (const float*)d_in[19]; const float* lnb = (const float*)d_in[20];
    const float* rw  = (const float*)d_in[21]; const float* rb  = (const float*)d_in[22];
    const float* g1w = (const float*)d_in[23];
    const float* g1as = (const float*)d_in[24]; const float* g1ad = (const float*)d_in[25];
    const float* g1b = (const float*)d_in[26];
    const float* g2w = (const float*)d_in[27];
    const float* g2as = (const float*)d_in[28]; const float* g2ad = (const float*)d_in[29];
    const float* g2b = (const float*)d_in[30];

    const int N = 4096, E = 65536;
    const int K1 = 2048, K2 = 1024, K3 = 512;

    float* base = (float*)d_ws;
    size_t off = 0;
    auto alloc = [&](size_t nf) { float* p = base + off; off += (nf + 63) & ~(size_t)63; return p; };

    float* A0   = alloc((size_t)N * N);
    float* A1   = alloc((size_t)K1 * K1);
    float* A2   = alloc((size_t)K2 * K2);
    float* A3   = alloc((size_t)K3 * K3);
    ushort* Tbf = (ushort*)alloc((size_t)N * N / 2);       // n x n bf16
    ushort* Agb = (ushort*)alloc((size_t)K1 * N / 2);      // k x n bf16
    ushort* Bgb = (ushort*)alloc((size_t)K1 * N / 2);
    float* x0   = alloc((size_t)N * 64);
    float* x1   = alloc((size_t)K1 * 64);
    float* x2   = alloc((size_t)K2 * 64);
    float* x3   = alloc((size_t)K3 * 64);
    float* h1   = alloc((size_t)K1 * 64);
    float* h2   = alloc((size_t)K2 * 64);
    float* h3   = alloc((size_t)K3 * 64);
    float* xw   = alloc((size_t)N * 128);
    float* yb   = alloc((size_t)N * 128);
    float* dinv = alloc(N);
    float* selfw= alloc(N);
    float* score= alloc(N);
    float* vals1= alloc(K1); float* vals2 = alloc(K2); float* vals3 = alloc(K3);
    int*   perm1= (int*)alloc(K1); int* perm2 = (int*)alloc(K2); int* perm3 = (int*)alloc(K3);
    float* t2   = alloc((size_t)K2 * 64);
    float* t1   = alloc((size_t)K1 * 64);
    float* t0   = alloc((size_t)N * 64);
    float* hfin = alloc((size_t)N * 128);
    float* u    = alloc((size_t)N * 128);
    float* resid= alloc((size_t)N * 128);
    float* hf1  = alloc((size_t)N * 512);
    float* es1  = alloc((size_t)N * 4); float* ed1 = alloc((size_t)N * 4);
    float* g1   = alloc((size_t)N * 512);
    float* hf2  = alloc((size_t)N * 128);
    float* es2  = alloc(N); float* ed2 = alloc(N);
    float* pn   = alloc(64);
    (void)ws_size; (void)n_in; (void)in_sizes; (void)out_size;

    // ---- A0 build ----
    hipMemsetAsync(A0, 0, (size_t)N * N * sizeof(float), stream);
    scatter_edges<<<cdiv(E, TPB), TPB, 0, stream>>>(ei, E, A0, N);

    // ---- down path ----
    run_gcn(stream, A0, N, x, 3, w0, b0, 64, xw, yb, dinv, selfw, x0, 1);

    // level 1
    vec_norm<<<1, 64, 0, stream>>>(p1, 64, pn);
    score_kernel<<<cdiv(N, TPB), TPB, 0, stream>>>(x0, p1, pn, score, N, 64);
    rank_topk<<<cdiv(N, TPB), TPB, N * sizeof(float), stream>>>(score, N, K1, perm1, vals1);
    run_augment(stream, A0, N, perm1, K1, Tbf, Agb, Bgb, A1);
    gather_feat<<<cdiv(K1 * 64, TPB), TPB, 0, stream>>>(x0, perm1, vals1, K1, 64, h1);
    run_gcn(stream, A1, K1, h1, 64, w1, b1, 64, xw, yb, dinv, selfw, x1, 1);

    // level 2
    vec_norm<<<1, 64, 0, stream>>>(p2, 64, pn);
    score_kernel<<<cdiv(K1, TPB), TPB, 0, stream>>>(x1, p2, pn, score, K1, 64);
    rank_topk<<<cdiv(K1, TPB), TPB, K1 * sizeof(float), stream>>>(score, K1, K2, perm2, vals2);
    run_augment(stream, A1, K1, perm2, K2, Tbf, Agb, Bgb, A2);
    gather_feat<<<cdiv(K2 * 64, TPB), TPB, 0, stream>>>(x1, perm2, vals2, K2, 64, h2);
    run_gcn(stream, A2, K2, h2, 64, w2, b2, 64, xw, yb, dinv, selfw, x2, 1);

    // level 3
    vec_norm<<<1, 64, 0, stream>>>(p3, 64, pn);
    score_kernel<<<cdiv(K2, TPB), TPB, 0, stream>>>(x2, p3, pn, score, K2, 64);
    rank_topk<<<cdiv(K2, TPB), TPB, K2 * sizeof(float), stream>>>(score, K2, K3, perm3, vals3);
    run_augment(stream, A2, K2, perm3, K3, Tbf, Agb, Bgb, A3);
    gather_feat<<<cdiv(K3 * 64, TPB), TPB, 0, stream>>>(x2, perm3, vals3, K3, 64, h3);
    run_gcn(stream, A3, K3, h3, 64, w3, b3, 64, xw, yb, dinv, selfw, x3, 1);

    // ---- up path ----
    copy_k<<<cdiv(K2 * 64, TPB), TPB, 0, stream>>>(x2, t2, K2 * 64);
    scatter_add_rows<<<cdiv(K3 * 64, TPB), TPB, 0, stream>>>(x3, perm3, K3, 64, t2);
    run_gcn(stream, A2, K2, t2, 64, uw0, ub0, 64, xw, yb, dinv, selfw, h2, 1);

    copy_k<<<cdiv(K1 * 64, TPB), TPB, 0, stream>>>(x1, t1, K1 * 64);
    scatter_add_rows<<<cdiv(K2 * 64, TPB), TPB, 0, stream>>>(h2, perm2, K2, 64, t1);
    run_gcn(stream, A1, K1, t1, 64, uw1, ub1, 64, xw, yb, dinv, selfw, h1, 1);

    copy_k<<<cdiv(N * 64, TPB), TPB, 0, stream>>>(x0, t0, N * 64);
    scatter_add_rows<<<cdiv(K1 * 64, TPB), TPB, 0, stream>>>(h1, perm1, K1, 64, t0);
    run_gcn(stream, A0, N, t0, 64, uw2, ub2, 128, xw, yb, dinv, selfw, hfin, 0);

    // ---- layernorm + residual ----
    layernorm<<<N, 128, 0, stream>>>(hfin, lng, lnb, u, N);
    gemm_bias<<<dim3(cdiv(128, 64), cdiv(N, 64)), TPB, 0, stream>>>(u, rw, rb, resid, N, 128, 128);

    // ---- GAT layer 1 (4 heads, concat, ELU) ----
    gemm_bias<<<dim3(cdiv(512, 64), cdiv(N, 64)), TPB, 0, stream>>>(u, g1w, nullptr, hf1, N, 128, 512);
    attn_coef<<<cdiv(N * 4, TPB), TPB, 0, stream>>>(hf1, g1as, g1ad, es1, ed1, N, 4);
    gat_kernel<<<N, TPB, 0, stream>>>(A0, N, hf1, es1, ed1, g1b, nullptr, g1, 4, 0);

    // ---- GAT layer 2 (1 head) + residual ----
    gemm_bias<<<dim3(cdiv(128, 64), cdiv(N, 64)), TPB, 0, stream>>>(g1, g2w, nullptr, hf2, N, 512, 128);
    attn_coef<<<cdiv(N, TPB), TPB, 0, stream>>>(hf2, g2as, g2ad, es2, ed2, N, 1);
    gat_kernel<<<N, TPB, 0, stream>>>(A0, N, hf2, es2, ed2, g2b, resid, (float*)d_out, 1, 1);
}

// Round 3
// 1118.527 us; speedup vs baseline: 4.4197x; 1.5348x over previous
//
#include <hip/hip_runtime.h>
#include <math.h>

// ---------------------------------------------------------------------------
// GraphUNet + GAT pipeline. N=4096, E=65536, IN=3, H=64, OUT=128, HEADS=4
// Round 3: GCN aggregation (A @ y) via split-bf16 MFMA GEMM with split-K
// atomics; A1..A3 stored as bf16 hi/lo pairs (written by augment epilogue);
// dinv/selfw computed once per adjacency level.
// ---------------------------------------------------------------------------

#define TPB 256
#define LDK 88

typedef __attribute__((ext_vector_type(8))) short bf16x8;
typedef __attribute__((ext_vector_type(4))) float f32x4;

__device__ inline ushort f32_to_bf16(float v) {
    unsigned b = __float_as_uint(v);
    return (ushort)((b + 0x7FFF + ((b >> 16) & 1)) >> 16);
}
__device__ inline float bf2f(ushort u) { return __uint_as_float(((unsigned)u) << 16); }

// ---------------- adjacency build ----------------
__global__ void scatter_edges(const int* __restrict__ ei, int E, float* A, int n) {
    int e = blockIdx.x * TPB + threadIdx.x;
    if (e >= E) return;
    int src = ei[e];
    int dst = ei[E + e];
    atomicAdd(&A[(size_t)dst * n + src], 1.0f);
}

// ---------------- generic fp32 GEMM: C = A[MxK] @ B[KxN] (+bias) -----------
__global__ void gemm_bias(const float* __restrict__ A, const float* __restrict__ B,
                          const float* __restrict__ bias, float* __restrict__ C,
                          int M, int K, int N) {
    __shared__ float As[16][65];
    __shared__ float Bs[16][65];
    int tx = threadIdx.x & 15, ty = threadIdx.x >> 4;
    int i0 = blockIdx.y * 64, j0 = blockIdx.x * 64;
    float acc[4][4] = {};
    for (int k0 = 0; k0 < K; k0 += 16) {
        for (int t = threadIdx.x; t < 1024; t += TPB) {
            int r = t >> 4, c = t & 15;
            int gi = i0 + r, gk = k0 + c;
            As[c][r] = (gi < M && gk < K) ? A[(size_t)gi * K + gk] : 0.f;
        }
        for (int t = threadIdx.x; t < 1024; t += TPB) {
            int r = t >> 6, c = t & 63;
            int gk = k0 + r, gj = j0 + c;
            Bs[r][c] = (gk < K && gj < N) ? B[(size_t)gk * N + gj] : 0.f;
        }
        __syncthreads();
        for (int kk = 0; kk < 16; ++kk) {
            float a[4], b[4];
#pragma unroll
            for (int u = 0; u < 4; ++u) a[u] = As[kk][ty * 4 + u];
#pragma unroll
            for (int v = 0; v < 4; ++v) b[v] = Bs[kk][tx * 4 + v];
#pragma unroll
            for (int u = 0; u < 4; ++u)
#pragma unroll
                for (int v = 0; v < 4; ++v) acc[u][v] += a[u] * b[v];
        }
        __syncthreads();
    }
    for (int u = 0; u < 4; ++u)
        for (int v = 0; v < 4; ++v) {
            int gi = i0 + ty * 4 + u, gj = j0 + tx * 4 + v;
            if (gi < M && gj < N) {
                float val = acc[u][v];
                if (bias) val += bias[gj];
                C[(size_t)gi * N + gj] = val;
            }
        }
}

// ---------------- augment path ----------------
// level-0: T[c][t] = bf16( A[t][c] + (t==c) ) from fp32 A
__global__ void transpose_aug(const float* __restrict__ A, ushort* __restrict__ T, int n) {
    __shared__ float tile[64][65];
    int c0 = blockIdx.x * 64, r0 = blockIdx.y * 64;
    for (int t = threadIdx.x; t < 4096; t += TPB) {
        int r = t >> 6, c = t & 63;
        float v = A[(size_t)(r0 + r) * n + (c0 + c)];
        if (r0 + r == c0 + c) v += 1.0f;
        tile[c][r] = v;
    }
    __syncthreads();
    for (int t = threadIdx.x; t < 4096; t += TPB) {
        int c = t >> 6, r = t & 63;
        T[(size_t)(c0 + c) * n + (r0 + r)] = f32_to_bf16(tile[c][r]);
    }
}

// levels >=1: same but from hi/lo bf16 pair
__global__ void transpose_aug_hl(const ushort* __restrict__ Ahi, const ushort* __restrict__ Alo,
                                 ushort* __restrict__ T, int n) {
    __shared__ float tile[64][65];
    int c0 = blockIdx.x * 64, r0 = blockIdx.y * 64;
    for (int t = threadIdx.x; t < 4096; t += TPB) {
        int r = t >> 6, c = t & 63;
        size_t o = (size_t)(r0 + r) * n + (c0 + c);
        float v = bf2f(Ahi[o]) + bf2f(Alo[o]);
        if (r0 + r == c0 + c) v += 1.0f;
        tile[c][r] = v;
    }
    __syncthreads();
    for (int t = threadIdx.x; t < 4096; t += TPB) {
        int c = t >> 6, r = t & 63;
        T[(size_t)(c0 + c) * n + (r0 + r)] = f32_to_bf16(tile[c][r]);
    }
}

// Ag[r][t] = bf16( A[perm[r]][t] + (perm[r]==t) )  (fp32 source)
__global__ void gather_rows_aug(const float* __restrict__ A, const int* __restrict__ perm,
                                ushort* __restrict__ Ag, int n, int rows) {
    int id = blockIdx.x * TPB + threadIdx.x;
    if (id >= rows * n) return;
    int r = id / n, t = id - r * n;
    int pr = perm[r];
    float v = A[(size_t)pr * n + t];
    if (pr == t) v += 1.0f;
    Ag[id] = f32_to_bf16(v);
}

// hi/lo source
__global__ void gather_rows_aug_hl(const ushort* __restrict__ Ahi, const ushort* __restrict__ Alo,
                                   const int* __restrict__ perm, ushort* __restrict__ Ag,
                                   int n, int rows) {
    int id = blockIdx.x * TPB + threadIdx.x;
    if (id >= rows * n) return;
    int r = id / n, t = id - r * n;
    int pr = perm[r];
    size_t o = (size_t)pr * n + t;
    float v = bf2f(Ahi[o]) + bf2f(Alo[o]);
    if (pr == t) v += 1.0f;
    Ag[id] = f32_to_bf16(v);
}

// Bg[c][t] = T[perm[c]][t]
__global__ void gather_rows_u16(const ushort* __restrict__ T, const int* __restrict__ perm,
                                ushort* __restrict__ Bg, int n, int rows) {
    int id = blockIdx.x * TPB + threadIdx.x;
    if (id >= rows * n) return;
    int r = id / n, t = id - r * n;
    Bg[id] = T[(size_t)perm[r] * n + t];
}

// C[r][c] = sum_t Ag[r][t]*Bg[c][t]; diag zeroed; output split to bf16 hi/lo.
__global__ void __launch_bounds__(256)
augment_gemm_hl(const ushort* __restrict__ Ag, const ushort* __restrict__ Bg,
                ushort* __restrict__ Chi, ushort* __restrict__ Clo, int K, int ldc) {
    __shared__ __align__(16) ushort As[64 * LDK];
    __shared__ __align__(16) ushort Bs[64 * LDK];
    int tid = threadIdx.x;
    int wave = tid >> 6, lane = tid & 63;
    int wr = wave >> 1, wc = wave & 1;
    int m = lane & 15, quad = lane >> 4;
    int i0 = blockIdx.y * 64, j0 = blockIdx.x * 64;
    f32x4 acc[2][2];
#pragma unroll
    for (int a = 0; a < 2; ++a)
#pragma unroll
        for (int b = 0; b < 2; ++b) acc[a][b] = (f32x4){0.f, 0.f, 0.f, 0.f};
    const ushort* Ab = Ag + (size_t)i0 * K;
    const ushort* Bb = Bg + (size_t)j0 * K;
    for (int k0 = 0; k0 < K; k0 += 64) {
#pragma unroll
        for (int v = 0; v < 2; ++v) {
            int idx = tid + (v << 8);
            int r = idx >> 3, c8 = idx & 7;
            *(uint4*)&As[r * LDK + c8 * 8] = *(const uint4*)&Ab[(size_t)r * K + k0 + c8 * 8];
            *(uint4*)&Bs[r * LDK + c8 * 8] = *(const uint4*)&Bb[(size_t)r * K + k0 + c8 * 8];
        }
        __syncthreads();
#pragma unroll
        for (int kk = 0; kk < 2; ++kk) {
            bf16x8 af[2], bfr[2];
#pragma unroll
            for (int mi = 0; mi < 2; ++mi)
                af[mi] = *(const bf16x8*)&As[(wr * 32 + mi * 16 + m) * LDK + kk * 32 + quad * 8];
#pragma unroll
            for (int ni = 0; ni < 2; ++ni)
                bfr[ni] = *(const bf16x8*)&Bs[(wc * 32 + ni * 16 + m) * LDK + kk * 32 + quad * 8];
#pragma unroll
            for (int mi = 0; mi < 2; ++mi)
#pragma unroll
                for (int ni = 0; ni < 2; ++ni)
                    acc[mi][ni] = __builtin_amdgcn_mfma_f32_16x16x32_bf16(
                        af[mi], bfr[ni], acc[mi][ni], 0, 0, 0);
        }
        __syncthreads();
    }
#pragma unroll
    for (int mi = 0; mi < 2; ++mi)
#pragma unroll
        for (int ni = 0; ni < 2; ++ni)
#pragma unroll
            for (int r = 0; r < 4; ++r) {
                int gi = i0 + wr * 32 + mi * 16 + quad * 4 + r;
                int gj = j0 + wc * 32 + ni * 16 + m;
                float val = (gi == gj) ? 0.f : acc[mi][ni][r];
                ushort hi = f32_to_bf16(val);
                size_t o = (size_t)gi * ldc + gj;
                Chi[o] = hi;
                Clo[o] = f32_to_bf16(val - bf2f(hi));
            }
}

// ---------------- GCN aggregation: C += A @ y (split bf16 MFMA) ----------------
// Bhi/Blo = yT hi/lo (f x K row-major, row c holds column c of y over k).
// amode 0: A fp32 (exact small ints -> single bf16 term); amode 1: A hi/lo.
__global__ void __launch_bounds__(256)
gcn_gemm(const float* __restrict__ Af, const ushort* __restrict__ Ahi,
         const ushort* __restrict__ Alo, const ushort* __restrict__ Bhi,
         const ushort* __restrict__ Blo, float* __restrict__ C,
         int K, int ldc, int kpb, int amode) {
    __shared__ __align__(16) ushort sAh[64 * LDK];
    __shared__ __align__(16) ushort sAl[64 * LDK];
    __shared__ __align__(16) ushort sBh[64 * LDK];
    __shared__ __align__(16) ushort sBl[64 * LDK];
    int tid = threadIdx.x;
    int wave = tid >> 6, lane = tid & 63;
    int wr = wave >> 1, wc = wave & 1;
    int m = lane & 15, quad = lane >> 4;
    int i0 = blockIdx.y * 64, j0 = blockIdx.x * 64;
    int kbeg = blockIdx.z * kpb;
    f32x4 acc[2][2];
#pragma unroll
    for (int a = 0; a < 2; ++a)
#pragma unroll
        for (int b = 0; b < 2; ++b) acc[a][b] = (f32x4){0.f, 0.f, 0.f, 0.f};
    for (int k0 = kbeg; k0 < kbeg + kpb; k0 += 64) {
#pragma unroll
        for (int v = 0; v < 2; ++v) {
            int idx = tid + (v << 8);
            int r = idx >> 3, c8 = idx & 7;
            size_t boff = (size_t)(j0 + r) * K + k0 + c8 * 8;
            *(uint4*)&sBh[r * LDK + c8 * 8] = *(const uint4*)&Bhi[boff];
            *(uint4*)&sBl[r * LDK + c8 * 8] = *(const uint4*)&Blo[boff];
            size_t aoff = (size_t)(i0 + r) * K + k0 + c8 * 8;
            if (amode) {
                *(uint4*)&sAh[r * LDK + c8 * 8] = *(const uint4*)&Ahi[aoff];
                *(uint4*)&sAl[r * LDK + c8 * 8] = *(const uint4*)&Alo[aoff];
            } else {
                float4 fa = *(const float4*)&Af[aoff];
                float4 fb = *(const float4*)&Af[aoff + 4];
                uint4 pk;
                pk.x = (uint)f32_to_bf16(fa.x) | ((uint)f32_to_bf16(fa.y) << 16);
                pk.y = (uint)f32_to_bf16(fa.z) | ((uint)f32_to_bf16(fa.w) << 16);
                pk.z = (uint)f32_to_bf16(fb.x) | ((uint)f32_to_bf16(fb.y) << 16);
                pk.w = (uint)f32_to_bf16(fb.z) | ((uint)f32_to_bf16(fb.w) << 16);
                *(uint4*)&sAh[r * LDK + c8 * 8] = pk;
            }
        }
        __syncthreads();
#pragma unroll
        for (int kk = 0; kk < 2; ++kk) {
            bf16x8 ah[2], bh[2], bl[2];
#pragma unroll
            for (int mi = 0; mi < 2; ++mi)
                ah[mi] = *(const bf16x8*)&sAh[(wr * 32 + mi * 16 + m) * LDK + kk * 32 + quad * 8];
#pragma unroll
            for (int ni = 0; ni < 2; ++ni) {
                bh[ni] = *(const bf16x8*)&sBh[(wc * 32 + ni * 16 + m) * LDK + kk * 32 + quad * 8];
                bl[ni] = *(const bf16x8*)&sBl[(wc * 32 + ni * 16 + m) * LDK + kk * 32 + quad * 8];
            }
#pragma unroll
            for (int mi = 0; mi < 2; ++mi)
#pragma unroll
                for (int ni = 0; ni < 2; ++ni) {
                    acc[mi][ni] = __builtin_amdgcn_mfma_f32_16x16x32_bf16(ah[mi], bh[ni], acc[mi][ni], 0, 0, 0);
                    acc[mi][ni] = __builtin_amdgcn_mfma_f32_16x16x32_bf16(ah[mi], bl[ni], acc[mi][ni], 0, 0, 0);
                }
            if (amode) {
                bf16x8 al[2];
#pragma unroll
                for (int mi = 0; mi < 2; ++mi)
                    al[mi] = *(const bf16x8*)&sAl[(wr * 32 + mi * 16 + m) * LDK + kk * 32 + quad * 8];
#pragma unroll
                for (int mi = 0; mi < 2; ++mi)
#pragma unroll
                    for (int ni = 0; ni < 2; ++ni)
                        acc[mi][ni] = __builtin_amdgcn_mfma_f32_16x16x32_bf16(al[mi], bh[ni], acc[mi][ni], 0, 0, 0);
            }
        }
        __syncthreads();
    }
#pragma unroll
    for (int mi = 0; mi < 2; ++mi)
#pragma unroll
        for (int ni = 0; ni < 2; ++ni)
#pragma unroll
            for (int r = 0; r < 4; ++r) {
                int gi = i0 + wr * 32 + mi * 16 + quad * 4 + r;
                int gj = j0 + wc * 32 + ni * 16 + m;
                atomicAdd(&C[(size_t)gi * ldc + gj], acc[mi][ni][r]);
            }
}

// yT build: Bhi/Blo[c][k] = split_bf16( xw[k][c] * dinv[k] ), tiles 64x64
__global__ void build_yT(const float* __restrict__ xw, const float* __restrict__ dinv,
                         ushort* __restrict__ Bhi, ushort* __restrict__ Blo, int n, int f) {
    __shared__ float t[64][65];
    int k0 = blockIdx.x * 64, c0 = blockIdx.y * 64;
#pragma unroll
    for (int v = 0; v < 16; ++v) {
        int idx = threadIdx.x + v * 256;
        int r = idx >> 6, c = idx & 63;
        t[r][c] = xw[(size_t)(k0 + r) * f + (c0 + c)] * dinv[k0 + r];
    }
    __syncthreads();
#pragma unroll
    for (int v = 0; v < 16; ++v) {
        int idx = threadIdx.x + v * 256;
        int c = idx >> 6, k = idx & 63;
        float val = t[k][c];
        ushort hi = f32_to_bf16(val);
        size_t o = (size_t)(c0 + c) * n + (k0 + k);
        Bhi[o] = hi;
        Blo[o] = f32_to_bf16(val - bf2f(hi));
    }
}

__global__ void gcn_epilogue(const float* __restrict__ C, const float* __restrict__ xw,
                             const float* __restrict__ dinv, const float* __restrict__ selfw,
                             const float* __restrict__ b, float* __restrict__ out,
                             int n, int f, int relu) {
    int id = blockIdx.x * TPB + threadIdx.x;
    if (id >= n * f) return;
    int i = id / f, c = id - i * f;
    float y = xw[id] * dinv[i];
    float v = dinv[i] * (C[id] + selfw[i] * y) + b[c];
    if (relu) v = fmaxf(v, 0.f);
    out[id] = v;
}

// ---------------- degree/norm ----------------
__global__ void rowsum_dinv(const float* __restrict__ A, int n, float* dinv, float* selfw) {
    int i = blockIdx.x;
    const float* row = A + (size_t)i * n;
    float s = 0.f;
    for (int j = threadIdx.x; j < n; j += TPB) s += row[j];
    for (int o = 32; o; o >>= 1) s += __shfl_xor(s, o);
    __shared__ float sh[4];
    if ((threadIdx.x & 63) == 0) sh[threadIdx.x >> 6] = s;
    __syncthreads();
    if (threadIdx.x == 0) {
        float tot = sh[0] + sh[1] + sh[2] + sh[3];
        float d = row[i];
        float sw = (d == 0.f) ? 2.f : 0.f;
        dinv[i] = 1.0f / sqrtf(tot + sw);
        selfw[i] = sw;
    }
}

__global__ void rowsum_dinv_hl(const ushort* __restrict__ Ahi, const ushort* __restrict__ Alo,
                               int n, float* dinv, float* selfw) {
    int i = blockIdx.x;
    const ushort* rh = Ahi + (size_t)i * n;
    const ushort* rl = Alo + (size_t)i * n;
    float s = 0.f;
    for (int j = threadIdx.x; j < n; j += TPB) s += bf2f(rh[j]) + bf2f(rl[j]);
    for (int o = 32; o; o >>= 1) s += __shfl_xor(s, o);
    __shared__ float sh[4];
    if ((threadIdx.x & 63) == 0) sh[threadIdx.x >> 6] = s;
    __syncthreads();
    if (threadIdx.x == 0) {
        float tot = sh[0] + sh[1] + sh[2] + sh[3];
        float d = bf2f(rh[i]) + bf2f(rl[i]);
        float sw = (d == 0.f) ? 2.f : 0.f;
        dinv[i] = 1.0f / sqrtf(tot + sw);
        selfw[i] = sw;
    }
}

// ---------------- pooling ----------------
__global__ void vec_norm(const float* __restrict__ p, int f, float* out) {
    float s = 0.f;
    for (int c = threadIdx.x; c < f; c += 64) { float v = p[c]; s += v * v; }
    for (int o = 32; o; o >>= 1) s += __shfl_xor(s, o);
    if (threadIdx.x == 0) out[0] = sqrtf(s);
}

__global__ void score_kernel(const float* __restrict__ x, const float* __restrict__ p,
                             const float* __restrict__ nrm, float* __restrict__ s, int n, int f) {
    int i = blockIdx.x * TPB + threadIdx.x;
    if (i >= n) return;
    float a = 0.f;
    for (int c = 0; c < f; ++c) a += x[(size_t)i * f + c] * p[c];
    s[i] = tanhf(a / nrm[0]);
}

__global__ void rank_topk(const float* __restrict__ s, int n, int k,
                          int* __restrict__ perm, float* __restrict__ vals) {
    extern __shared__ float ss[];
    for (int j = threadIdx.x; j < n; j += TPB) ss[j] = s[j];
    __syncthreads();
    int i = blockIdx.x * TPB + threadIdx.x;
    if (i >= n) return;
    float si = ss[i];
    int r = 0;
    for (int j = 0; j < n; ++j) {
        float sj = ss[j];
        r += (sj > si) || (sj == si && j < i);
    }
    if (r < k) { perm[r] = i; vals[r] = si; }
}

__global__ void gather_feat(const float* __restrict__ x, const int* __restrict__ perm,
                            const float* __restrict__ vals, int k, int f, float* __restrict__ h) {
    int id = blockIdx.x * TPB + threadIdx.x;
    if (id >= k * f) return;
    int r = id / f, c = id - r * f;
    h[id] = x[(size_t)perm[r] * f + c] * vals[r];
}

// ---------------- up path ----------------
__global__ void copy_k(const float* __restrict__ s, float* __restrict__ d, int n) {
    int id = blockIdx.x * TPB + threadIdx.x;
    if (id < n) d[id] = s[id];
}

__global__ void scatter_add_rows(const float* __restrict__ s, const int* __restrict__ perm,
                                 int k, int f, float* __restrict__ t) {
    int id = blockIdx.x * TPB + threadIdx.x;
    if (id >= k * f) return;
    int r = id / f, c = id - r * f;
    t[(size_t)perm[r] * f + c] += s[id];
}

// ---------------- layernorm ----------------
__global__ void layernorm(const float* __restrict__ h, const float* __restrict__ g,
                          const float* __restrict__ b, float* __restrict__ u, int n) {
    int i = blockIdx.x;
    int t = threadIdx.x;
    float v = h[(size_t)i * 128 + t];
    __shared__ float s0[2], s1[2];
    float sum = v;
    for (int o = 32; o; o >>= 1) sum += __shfl_xor(sum, o);
    if ((t & 63) == 0) s0[t >> 6] = sum;
    __syncthreads();
    float mu = (s0[0] + s0[1]) * (1.0f / 128.0f);
    float d = v - mu;
    float sq = d * d;
    for (int o = 32; o; o >>= 1) sq += __shfl_xor(sq, o);
    if ((t & 63) == 0) s1[t >> 6] = sq;
    __syncthreads();
    float var = (s1[0] + s1[1]) * (1.0f / 128.0f);
    u[(size_t)i * 128 + t] = d / sqrtf(var + 1e-6f) * g[t] + b[t];
}

// ---------------- GAT ----------------
__global__ void attn_coef(const float* __restrict__ hf, const float* __restrict__ asrc,
                          const float* __restrict__ adst, float* __restrict__ es,
                          float* __restrict__ ed, int n, int heads) {
    int id = blockIdx.x * TPB + threadIdx.x;
    if (id >= n * heads) return;
    int j = id / heads, h = id - j * heads;
    const float* hp = hf + (size_t)j * heads * 128 + h * 128;
    float a = 0.f, d = 0.f;
    for (int c = 0; c < 128; ++c) {
        float v = hp[c];
        a += v * asrc[h * 128 + c];
        d += v * adst[h * 128 + c];
    }
    es[id] = a;
    ed[id] = d;
}

#define MAXD 1024
__global__ void gat_kernel(const float* __restrict__ A0, int n, const float* __restrict__ hf,
                           const float* __restrict__ es, const float* __restrict__ ed,
                           const float* __restrict__ bias, const float* __restrict__ resid,
                           float* __restrict__ out, int heads, int mode) {
    int i = blockIdx.x;
    int tid = threadIdx.x;
    __shared__ int cnt;
    __shared__ int idx[MAXD];
    __shared__ float lg[MAXD * 4];
    __shared__ float hmax[4], hsum[4];
    if (tid == 0) cnt = 0;
    __syncthreads();
    const float* row = A0 + (size_t)i * n;
    for (int j = tid; j < n; j += TPB) {
        if (row[j] > 0.f || j == i) {
            int p = atomicAdd(&cnt, 1);
            if (p < MAXD) idx[p] = j;
        }
    }
    __syncthreads();
    int m = min(cnt, MAXD);
    for (int t = tid; t < m * heads; t += TPB) {
        int jl = t / heads, h = t - jl * heads;
        float l = ed[i * heads + h] + es[idx[jl] * heads + h];
        lg[jl * heads + h] = (l > 0.f) ? l : 0.2f * l;
    }
    __syncthreads();
    int h = tid >> 6, lane = tid & 63;
    if (h < heads) {
        float mx = -3.4e38f;
        for (int jl = lane; jl < m; jl += 64) mx = fmaxf(mx, lg[jl * heads + h]);
        for (int o = 32; o; o >>= 1) mx = fmaxf(mx, __shfl_xor(mx, o));
        if (lane == 0) hmax[h] = mx;
    }
    __syncthreads();
    if (h < heads) {
        float mx = hmax[h];
        float sm = 0.f;
        for (int jl = lane; jl < m; jl += 64) {
            float p = expf(lg[jl * heads + h] - mx);
            lg[jl * heads + h] = p;
            sm += p;
        }
        for (int o = 32; o; o >>= 1) sm += __shfl_xor(sm, o);
        if (lane == 0) hsum[h] = sm;
    }
    __syncthreads();
    int width = heads * 128;
    for (int o = tid; o < width; o += TPB) {
        int hh = o >> 7;
        float acc = 0.f;
        for (int jl = 0; jl < m; ++jl)
            acc += lg[jl * heads + hh] * hf[(size_t)idx[jl] * width + o];
        float v = acc / hsum[hh] + bias[o];
        if (mode == 0) v = (v > 0.f) ? v : expm1f(v);
        else v += resid[(size_t)i * width + o];
        out[(size_t)i * width + o] = v;
    }
}

// ---------------------------------------------------------------------------
static inline int cdiv(int a, int b) { return (a + b - 1) / b; }

static int pick_z(int gx, int gy, int K) {
    int z = 1;
    while (gx * gy * z < 384 && K / (2 * z) >= 64) z <<= 1;
    return z;
}

static void run_gcn(hipStream_t stream, int amode, const float* Af, const ushort* Ahi,
                    const ushort* Alo, int n, const float* xin, int fin,
                    const float* W, const float* bias, int f,
                    const float* dinv, const float* selfw,
                    float* xw, ushort* yThi, ushort* yTlo, float* Cp,
                    float* out, int relu) {
    gemm_bias<<<dim3(cdiv(f, 64), cdiv(n, 64)), TPB, 0, stream>>>(xin, W, nullptr, xw, n, fin, f);
    build_yT<<<dim3(n / 64, f / 64), TPB, 0, stream>>>(xw, dinv, yThi, yTlo, n, f);
    hipMemsetAsync(Cp, 0, (size_t)n * f * sizeof(float), stream);
    int z = pick_z(f / 64, n / 64, n);
    gcn_gemm<<<dim3(f / 64, n / 64, z), TPB, 0, stream>>>(Af, Ahi, Alo, yThi, yTlo, Cp, n, f, n / z, amode);
    gcn_epilogue<<<cdiv(n * f, TPB), TPB, 0, stream>>>(Cp, xw, dinv, selfw, bias, out, n, f, relu);
}

extern "C" void kernel_launch(void* const* d_in, const int* in_sizes, int n_in,
                              void* d_out, int out_size, void* d_ws, size_t ws_size,
                              hipStream_t stream) {
    const float* x   = (const float*)d_in[0];
    const int*   ei  = (const int*)d_in[1];
    const float* w0  = (const float*)d_in[2];  const float* b0  = (const float*)d_in[3];
    const float* w1  = (const float*)d_in[4];  const float* b1  = (const float*)d_in[5];
    const float* w2  = (const float*)d_in[6];  const float* b2  = (const float*)d_in[7];
    const float* w3  = (const float*)d_in[8];  const float* b3  = (const float*)d_in[9];
    const float* p1  = (const float*)d_in[10];
    const float* p2  = (const float*)d_in[11];
    const float* p3  = (const float*)d_in[12];
    const float* uw0 = (const float*)d_in[13]; const float* ub0 = (const float*)d_in[14];
    const float* uw1 = (const float*)d_in[15]; const float* ub1 = (const float*)d_in[16];
    const float* uw2 = (const float*)d_in[17]; const float* ub2 = (const float*)d_in[18];
    const float* lng = (const float*)d_in[19]; const float* lnb = (const float*)d_in[20];
    const float* rw  = (const float*)d_in[21]; const float* rb  = (const float*)d_in[22];
    const float* g1w = (const float*)d_in[23];
    const float* g1as = (const float*)d_in[24]; const float* g1ad = (const float*)d_in[25];
    const float* g1b = (const float*)d_in[26];
    const float* g2w = (const float*)d_in[27];
    const float* g2as = (const float*)d_in[28]; const float* g2ad = (const float*)d_in[29];
    const float* g2b = (const float*)d_in[30];

    const int N = 4096, E = 65536;
    const int K1 = 2048, K2 = 1024, K3 = 512;

    float* base = (float*)d_ws;
    size_t off = 0;
    auto alloc = [&](size_t nf) { float* p = base + off; off += (nf + 63) & ~(size_t)63; return p; };

    float* A0    = alloc((size_t)N * N);
    ushort* A1hi = (ushort*)alloc((size_t)K1 * K1 / 2);
    ushort* A1lo = (ushort*)alloc((size_t)K1 * K1 / 2);
    ushort* A2hi = (ushort*)alloc((size_t)K2 * K2 / 2);
    ushort* A2lo = (ushort*)alloc((size_t)K2 * K2 / 2);
    ushort* A3hi = (ushort*)alloc((size_t)K3 * K3 / 2);
    ushort* A3lo = (ushort*)alloc((size_t)K3 * K3 / 2);
    ushort* Tbf  = (ushort*)alloc((size_t)N * N / 2);
    ushort* Agb  = (ushort*)alloc((size_t)K1 * N / 2);
    ushort* Bgb  = (ushort*)alloc((size_t)K1 * N / 2);
    ushort* yThi = (ushort*)alloc((size_t)128 * N / 2);
    ushort* yTlo = (ushort*)alloc((size_t)128 * N / 2);
    float* Cp    = alloc((size_t)N * 128);
    float* x0    = alloc((size_t)N * 64);
    float* x1    = alloc((size_t)K1 * 64);
    float* x2    = alloc((size_t)K2 * 64);
    float* x3    = alloc((size_t)K3 * 64);
    float* h1    = alloc((size_t)K1 * 64);
    float* h2    = alloc((size_t)K2 * 64);
    float* h3    = alloc((size_t)K3 * 64);
    float* xw    = alloc((size_t)N * 128);
    float* dinv0 = alloc(N);  float* selfw0 = alloc(N);
    float* dinv1 = alloc(K1); float* selfw1 = alloc(K1);
    float* dinv2 = alloc(K2); float* selfw2 = alloc(K2);
    float* dinv3 = alloc(K3); float* selfw3 = alloc(K3);
    float* score = alloc(N);
    float* vals1 = alloc(K1); float* vals2 = alloc(K2); float* vals3 = alloc(K3);
    int*   perm1 = (int*)alloc(K1); int* perm2 = (int*)alloc(K2); int* perm3 = (int*)alloc(K3);
    float* t2    = alloc((size_t)K2 * 64);
    float* t1    = alloc((size_t)K1 * 64);
    float* t0    = alloc((size_t)N * 64);
    float* hfin  = alloc((size_t)N * 128);
    float* u     = alloc((size_t)N * 128);
    float* resid = alloc((size_t)N * 128);
    float* hf1   = alloc((size_t)N * 512);
    float* es1   = alloc((size_t)N * 4); float* ed1 = alloc((size_t)N * 4);
    float* g1    = alloc((size_t)N * 512);
    float* hf2   = alloc((size_t)N * 128);
    float* es2   = alloc(N); float* ed2 = alloc(N);
    float* pn    = alloc(64);
    (void)ws_size; (void)n_in; (void)in_sizes; (void)out_size;

    // ---- A0 build + level-0 norm ----
    hipMemsetAsync(A0, 0, (size_t)N * N * sizeof(float), stream);
    scatter_edges<<<cdiv(E, TPB), TPB, 0, stream>>>(ei, E, A0, N);
    rowsum_dinv<<<N, TPB, 0, stream>>>(A0, N, dinv0, selfw0);

    // ---- down level 0 ----
    run_gcn(stream, 0, A0, nullptr, nullptr, N, x, 3, w0, b0, 64,
            dinv0, selfw0, xw, yThi, yTlo, Cp, x0, 1);

    // ---- level 1 ----
    vec_norm<<<1, 64, 0, stream>>>(p1, 64, pn);
    score_kernel<<<cdiv(N, TPB), TPB, 0, stream>>>(x0, p1, pn, score, N, 64);
    rank_topk<<<cdiv(N, TPB), TPB, N * sizeof(float), stream>>>(score, N, K1, perm1, vals1);
    transpose_aug<<<dim3(N / 64, N / 64), TPB, 0, stream>>>(A0, Tbf, N);
    gather_rows_aug<<<cdiv(K1 * N, TPB), TPB, 0, stream>>>(A0, perm1, Agb, N, K1);
    gather_rows_u16<<<cdiv(K1 * N, TPB), TPB, 0, stream>>>(Tbf, perm1, Bgb, N, K1);
    augment_gemm_hl<<<dim3(K1 / 64, K1 / 64), TPB, 0, stream>>>(Agb, Bgb, A1hi, A1lo, N, K1);
    rowsum_dinv_hl<<<K1, TPB, 0, stream>>>(A1hi, A1lo, K1, dinv1, selfw1);
    gather_feat<<<cdiv(K1 * 64, TPB), TPB, 0, stream>>>(x0, perm1, vals1, K1, 64, h1);
    run_gcn(stream, 1, nullptr, A1hi, A1lo, K1, h1, 64, w1, b1, 64,
            dinv1, selfw1, xw, yThi, yTlo, Cp, x1, 1);

    // ---- level 2 ----
    vec_norm<<<1, 64, 0, stream>>>(p2, 64, pn);
    score_kernel<<<cdiv(K1, TPB), TPB, 0, stream>>>(x1, p2, pn, score, K1, 64);
    rank_topk<<<cdiv(K1, TPB), TPB, K1 * sizeof(float), stream>>>(score, K1, K2, perm2, vals2);
    transpose_aug_hl<<<dim3(K1 / 64, K1 / 64), TPB, 0, stream>>>(A1hi, A1lo, Tbf, K1);
    gather_rows_aug_hl<<<cdiv(K2 * K1, TPB), TPB, 0, stream>>>(A1hi, A1lo, perm2, Agb, K1, K2);
    gather_rows_u16<<<cdiv(K2 * K1, TPB), TPB, 0, stream>>>(Tbf, perm2, Bgb, K1, K2);
    augment_gemm_hl<<<dim3(K2 / 64, K2 / 64), TPB, 0, stream>>>(Agb, Bgb, A2hi, A2lo, K1, K2);
    rowsum_dinv_hl<<<K2, TPB, 0, stream>>>(A2hi, A2lo, K2, dinv2, selfw2);
    gather_feat<<<cdiv(K2 * 64, TPB), TPB, 0, stream>>>(x1, perm2, vals2, K2, 64, h2);
    run_gcn(stream, 1, nullptr, A2hi, A2lo, K2, h2, 64, w2, b2, 64,
            dinv2, selfw2, xw, yThi, yTlo, Cp, x2, 1);

    // ---- level 3 ----
    vec_norm<<<1, 64, 0, stream>>>(p3, 64, pn);
    score_kernel<<<cdiv(K2, TPB), TPB, 0, stream>>>(x2, p3, pn, score, K2, 64);
    rank_topk<<<cdiv(K2, TPB), TPB, K2 * sizeof(float), stream>>>(score, K2, K3, perm3, vals3);
    transpose_aug_hl<<<dim3(K2 / 64, K2 / 64), TPB, 0, stream>>>(A2hi, A2lo, Tbf, K2);
    gather_rows_aug_hl<<<cdiv(K3 * K2, TPB), TPB, 0, stream>>>(A2hi, A2lo, perm3, Agb, K2, K3);
    gather_rows_u16<<<cdiv(K3 * K2, TPB), TPB, 0, stream>>>(Tbf, perm3, Bgb, K2, K3);
    augment_gemm_hl<<<dim3(K3 / 64, K3 / 64), TPB, 0, stream>>>(Agb, Bgb, A3hi, A3lo, K2, K3);
    rowsum_dinv_hl<<<K3, TPB, 0, stream>>>(A3hi, A3lo, K3, dinv3, selfw3);
    gather_feat<<<cdiv(K3 * 64, TPB), TPB, 0, stream>>>(x2, perm3, vals3, K3, 64, h3);
    run_gcn(stream, 1, nullptr, A3hi, A3lo, K3, h3, 64, w3, b3, 64,
            dinv3, selfw3, xw, yThi, yTlo, Cp, x3, 1);

    // ---- up path ----
    copy_k<<<cdiv(K2 * 64, TPB), TPB, 0, stream>>>(x2, t2, K2 * 64);
    scatter_add_rows<<<cdiv(K3 * 64, TPB), TPB, 0, stream>>>(x3, perm3, K3, 64, t2);
    run_gcn(stream, 1, nullptr, A2hi, A2lo, K2, t2, 64, uw0, ub0, 64,
            dinv2, selfw2, xw, yThi, yTlo, Cp, h2, 1);

    copy_k<<<cdiv(K1 * 64, TPB), TPB, 0, stream>>>(x1, t1, K1 * 64);
    scatter_add_rows<<<cdiv(K2 * 64, TPB), TPB, 0, stream>>>(h2, perm2, K2, 64, t1);
    run_gcn(stream, 1, nullptr, A1hi, A1lo, K1, t1, 64, uw1, ub1, 64,
            dinv1, selfw1, xw, yThi, yTlo, Cp, h1, 1);

    copy_k<<<cdiv(N * 64, TPB), TPB, 0, stream>>>(x0, t0, N * 64);
    scatter_add_rows<<<cdiv(K1 * 64, TPB), TPB, 0, stream>>>(h1, perm1, K1, 64, t0);
    run_gcn(stream, 0, A0, nullptr, nullptr, N, t0, 64, uw2, ub2, 128,
            dinv0, selfw0, xw, yThi, yTlo, Cp, hfin, 0);

    // ---- layernorm + residual ----
    layernorm<<<N, 128, 0, stream>>>(hfin, lng, lnb, u, N);
    gemm_bias<<<dim3(cdiv(128, 64), cdiv(N, 64)), TPB, 0, stream>>>(u, rw, rb, resid, N, 128, 128);

    // ---- GAT layer 1 (4 heads, concat, ELU) ----
    gemm_bias<<<dim3(cdiv(512, 64), cdiv(N, 64)), TPB, 0, stream>>>(u, g1w, nullptr, hf1, N, 128, 512);
    attn_coef<<<cdiv(N * 4, TPB), TPB, 0, stream>>>(hf1, g1as, g1ad, es1, ed1, N, 4);
    gat_kernel<<<N, TPB, 0, stream>>>(A0, N, hf1, es1, ed1, g1b, nullptr, g1, 4, 0);

    // ---- GAT layer 2 (1 head) + residual ----
    gemm_bias<<<dim3(cdiv(128, 64), cdiv(N, 64)), TPB, 0, stream>>>(g1, g2w, nullptr, hf2, N, 512, 128);
    attn_coef<<<cdiv(N, TPB), TPB, 0, stream>>>(hf2, g2as, g2ad, es2, ed2, N, 1);
    gat_kernel<<<N, TPB, 0, stream>>>(A0, N, hf2, es2, ed2, g2b, resid, (float*)d_out, 1, 1);
}

// Round 4
// 960.641 us; speedup vs baseline: 5.1461x; 1.1644x over previous
//
#include <hip/hip_runtime.h>
#include <math.h>

// ---------------------------------------------------------------------------
// GraphUNet + GAT pipeline. N=4096, E=65536, IN=3, H=64, OUT=128, HEADS=4
// Round 4: parallel rank-count top-k; A0 kept as exact bf16 for all
// downstream consumers (GEMM A-operand, transpose, gathers, GAT row scan).
// ---------------------------------------------------------------------------

#define TPB 256
#define LDK 88

typedef __attribute__((ext_vector_type(8))) short bf16x8;
typedef __attribute__((ext_vector_type(4))) float f32x4;

__device__ inline ushort f32_to_bf16(float v) {
    unsigned b = __float_as_uint(v);
    return (ushort)((b + 0x7FFF + ((b >> 16) & 1)) >> 16);
}
__device__ inline float bf2f(ushort u) { return __uint_as_float(((unsigned)u) << 16); }

// ---------------- adjacency build ----------------
__global__ void scatter_edges(const int* __restrict__ ei, int E, float* A, int n) {
    int e = blockIdx.x * TPB + threadIdx.x;
    if (e >= E) return;
    int src = ei[e];
    int dst = ei[E + e];
    atomicAdd(&A[(size_t)dst * n + src], 1.0f);
}

__global__ void f32_arr_to_bf16(const float* __restrict__ A, ushort* __restrict__ B, size_t total4) {
    size_t id = (size_t)blockIdx.x * TPB + threadIdx.x;
    if (id >= total4) return;
    size_t i4 = id * 4;
    float4 v = *(const float4*)&A[i4];
    uint2 p;
    p.x = (uint)f32_to_bf16(v.x) | ((uint)f32_to_bf16(v.y) << 16);
    p.y = (uint)f32_to_bf16(v.z) | ((uint)f32_to_bf16(v.w) << 16);
    *(uint2*)&B[i4] = p;
}

// ---------------- generic fp32 GEMM: C = A[MxK] @ B[KxN] (+bias) -----------
__global__ void gemm_bias(const float* __restrict__ A, const float* __restrict__ B,
                          const float* __restrict__ bias, float* __restrict__ C,
                          int M, int K, int N) {
    __shared__ float As[16][65];
    __shared__ float Bs[16][65];
    int tx = threadIdx.x & 15, ty = threadIdx.x >> 4;
    int i0 = blockIdx.y * 64, j0 = blockIdx.x * 64;
    float acc[4][4] = {};
    for (int k0 = 0; k0 < K; k0 += 16) {
        for (int t = threadIdx.x; t < 1024; t += TPB) {
            int r = t >> 4, c = t & 15;
            int gi = i0 + r, gk = k0 + c;
            As[c][r] = (gi < M && gk < K) ? A[(size_t)gi * K + gk] : 0.f;
        }
        for (int t = threadIdx.x; t < 1024; t += TPB) {
            int r = t >> 6, c = t & 63;
            int gk = k0 + r, gj = j0 + c;
            Bs[r][c] = (gk < K && gj < N) ? B[(size_t)gk * N + gj] : 0.f;
        }
        __syncthreads();
        for (int kk = 0; kk < 16; ++kk) {
            float a[4], b[4];
#pragma unroll
            for (int u = 0; u < 4; ++u) a[u] = As[kk][ty * 4 + u];
#pragma unroll
            for (int v = 0; v < 4; ++v) b[v] = Bs[kk][tx * 4 + v];
#pragma unroll
            for (int u = 0; u < 4; ++u)
#pragma unroll
                for (int v = 0; v < 4; ++v) acc[u][v] += a[u] * b[v];
        }
        __syncthreads();
    }
    for (int u = 0; u < 4; ++u)
        for (int v = 0; v < 4; ++v) {
            int gi = i0 + ty * 4 + u, gj = j0 + tx * 4 + v;
            if (gi < M && gj < N) {
                float val = acc[u][v];
                if (bias) val += bias[gj];
                C[(size_t)gi * N + gj] = val;
            }
        }
}

// ---------------- augment path ----------------
// T[c][t] = bf16( A[t][c] + (t==c) ) from bf16 A (exact small ints)
__global__ void transpose_aug_b(const ushort* __restrict__ A, ushort* __restrict__ T, int n) {
    __shared__ float tile[64][65];
    int c0 = blockIdx.x * 64, r0 = blockIdx.y * 64;
    for (int t = threadIdx.x; t < 4096; t += TPB) {
        int r = t >> 6, c = t & 63;
        float v = bf2f(A[(size_t)(r0 + r) * n + (c0 + c)]);
        if (r0 + r == c0 + c) v += 1.0f;
        tile[c][r] = v;
    }
    __syncthreads();
    for (int t = threadIdx.x; t < 4096; t += TPB) {
        int c = t >> 6, r = t & 63;
        T[(size_t)(c0 + c) * n + (r0 + r)] = f32_to_bf16(tile[c][r]);
    }
}

// levels >=1: from hi/lo bf16 pair
__global__ void transpose_aug_hl(const ushort* __restrict__ Ahi, const ushort* __restrict__ Alo,
                                 ushort* __restrict__ T, int n) {
    __shared__ float tile[64][65];
    int c0 = blockIdx.x * 64, r0 = blockIdx.y * 64;
    for (int t = threadIdx.x; t < 4096; t += TPB) {
        int r = t >> 6, c = t & 63;
        size_t o = (size_t)(r0 + r) * n + (c0 + c);
        float v = bf2f(Ahi[o]) + bf2f(Alo[o]);
        if (r0 + r == c0 + c) v += 1.0f;
        tile[c][r] = v;
    }
    __syncthreads();
    for (int t = threadIdx.x; t < 4096; t += TPB) {
        int c = t >> 6, r = t & 63;
        T[(size_t)(c0 + c) * n + (r0 + r)] = f32_to_bf16(tile[c][r]);
    }
}

// Ag[r][t] = bf16( A[perm[r]][t] + (perm[r]==t) )  (bf16 source, exact)
__global__ void gather_rows_aug_b(const ushort* __restrict__ A, const int* __restrict__ perm,
                                  ushort* __restrict__ Ag, int n, int rows) {
    int id = blockIdx.x * TPB + threadIdx.x;
    if (id >= rows * n) return;
    int r = id / n, t = id - r * n;
    int pr = perm[r];
    float v = bf2f(A[(size_t)pr * n + t]);
    if (pr == t) v += 1.0f;
    Ag[id] = f32_to_bf16(v);
}

// hi/lo source
__global__ void gather_rows_aug_hl(const ushort* __restrict__ Ahi, const ushort* __restrict__ Alo,
                                   const int* __restrict__ perm, ushort* __restrict__ Ag,
                                   int n, int rows) {
    int id = blockIdx.x * TPB + threadIdx.x;
    if (id >= rows * n) return;
    int r = id / n, t = id - r * n;
    int pr = perm[r];
    size_t o = (size_t)pr * n + t;
    float v = bf2f(Ahi[o]) + bf2f(Alo[o]);
    if (pr == t) v += 1.0f;
    Ag[id] = f32_to_bf16(v);
}

// Bg[c][t] = T[perm[c]][t]
__global__ void gather_rows_u16(const ushort* __restrict__ T, const int* __restrict__ perm,
                                ushort* __restrict__ Bg, int n, int rows) {
    int id = blockIdx.x * TPB + threadIdx.x;
    if (id >= rows * n) return;
    int r = id / n, t = id - r * n;
    Bg[id] = T[(size_t)perm[r] * n + t];
}

// C[r][c] = sum_t Ag[r][t]*Bg[c][t]; diag zeroed; output split to bf16 hi/lo.
__global__ void __launch_bounds__(256)
augment_gemm_hl(const ushort* __restrict__ Ag, const ushort* __restrict__ Bg,
                ushort* __restrict__ Chi, ushort* __restrict__ Clo, int K, int ldc) {
    __shared__ __align__(16) ushort As[64 * LDK];
    __shared__ __align__(16) ushort Bs[64 * LDK];
    int tid = threadIdx.x;
    int wave = tid >> 6, lane = tid & 63;
    int wr = wave >> 1, wc = wave & 1;
    int m = lane & 15, quad = lane >> 4;
    int i0 = blockIdx.y * 64, j0 = blockIdx.x * 64;
    f32x4 acc[2][2];
#pragma unroll
    for (int a = 0; a < 2; ++a)
#pragma unroll
        for (int b = 0; b < 2; ++b) acc[a][b] = (f32x4){0.f, 0.f, 0.f, 0.f};
    const ushort* Ab = Ag + (size_t)i0 * K;
    const ushort* Bb = Bg + (size_t)j0 * K;
    for (int k0 = 0; k0 < K; k0 += 64) {
#pragma unroll
        for (int v = 0; v < 2; ++v) {
            int idx = tid + (v << 8);
            int r = idx >> 3, c8 = idx & 7;
            *(uint4*)&As[r * LDK + c8 * 8] = *(const uint4*)&Ab[(size_t)r * K + k0 + c8 * 8];
            *(uint4*)&Bs[r * LDK + c8 * 8] = *(const uint4*)&Bb[(size_t)r * K + k0 + c8 * 8];
        }
        __syncthreads();
#pragma unroll
        for (int kk = 0; kk < 2; ++kk) {
            bf16x8 af[2], bfr[2];
#pragma unroll
            for (int mi = 0; mi < 2; ++mi)
                af[mi] = *(const bf16x8*)&As[(wr * 32 + mi * 16 + m) * LDK + kk * 32 + quad * 8];
#pragma unroll
            for (int ni = 0; ni < 2; ++ni)
                bfr[ni] = *(const bf16x8*)&Bs[(wc * 32 + ni * 16 + m) * LDK + kk * 32 + quad * 8];
#pragma unroll
            for (int mi = 0; mi < 2; ++mi)
#pragma unroll
                for (int ni = 0; ni < 2; ++ni)
                    acc[mi][ni] = __builtin_amdgcn_mfma_f32_16x16x32_bf16(
                        af[mi], bfr[ni], acc[mi][ni], 0, 0, 0);
        }
        __syncthreads();
    }
#pragma unroll
    for (int mi = 0; mi < 2; ++mi)
#pragma unroll
        for (int ni = 0; ni < 2; ++ni)
#pragma unroll
            for (int r = 0; r < 4; ++r) {
                int gi = i0 + wr * 32 + mi * 16 + quad * 4 + r;
                int gj = j0 + wc * 32 + ni * 16 + m;
                float val = (gi == gj) ? 0.f : acc[mi][ni][r];
                ushort hi = f32_to_bf16(val);
                size_t o = (size_t)gi * ldc + gj;
                Chi[o] = hi;
                Clo[o] = f32_to_bf16(val - bf2f(hi));
            }
}

// ---------------- GCN aggregation: C += A @ y (split bf16 MFMA) ------------
// amode 0: A single exact bf16 (2 MFMA/term); amode 1: A hi/lo (3 MFMA).
__global__ void __launch_bounds__(256)
gcn_gemm(const ushort* __restrict__ Ahi, const ushort* __restrict__ Alo,
         const ushort* __restrict__ Bhi, const ushort* __restrict__ Blo,
         float* __restrict__ C, int K, int ldc, int kpb, int amode) {
    __shared__ __align__(16) ushort sAh[64 * LDK];
    __shared__ __align__(16) ushort sAl[64 * LDK];
    __shared__ __align__(16) ushort sBh[64 * LDK];
    __shared__ __align__(16) ushort sBl[64 * LDK];
    int tid = threadIdx.x;
    int wave = tid >> 6, lane = tid & 63;
    int wr = wave >> 1, wc = wave & 1;
    int m = lane & 15, quad = lane >> 4;
    int i0 = blockIdx.y * 64, j0 = blockIdx.x * 64;
    int kbeg = blockIdx.z * kpb;
    f32x4 acc[2][2];
#pragma unroll
    for (int a = 0; a < 2; ++a)
#pragma unroll
        for (int b = 0; b < 2; ++b) acc[a][b] = (f32x4){0.f, 0.f, 0.f, 0.f};
    for (int k0 = kbeg; k0 < kbeg + kpb; k0 += 64) {
#pragma unroll
        for (int v = 0; v < 2; ++v) {
            int idx = tid + (v << 8);
            int r = idx >> 3, c8 = idx & 7;
            size_t boff = (size_t)(j0 + r) * K + k0 + c8 * 8;
            *(uint4*)&sBh[r * LDK + c8 * 8] = *(const uint4*)&Bhi[boff];
            *(uint4*)&sBl[r * LDK + c8 * 8] = *(const uint4*)&Blo[boff];
            size_t aoff = (size_t)(i0 + r) * K + k0 + c8 * 8;
            *(uint4*)&sAh[r * LDK + c8 * 8] = *(const uint4*)&Ahi[aoff];
            if (amode)
                *(uint4*)&sAl[r * LDK + c8 * 8] = *(const uint4*)&Alo[aoff];
        }
        __syncthreads();
#pragma unroll
        for (int kk = 0; kk < 2; ++kk) {
            bf16x8 ah[2], bh[2], bl[2];
#pragma unroll
            for (int mi = 0; mi < 2; ++mi)
                ah[mi] = *(const bf16x8*)&sAh[(wr * 32 + mi * 16 + m) * LDK + kk * 32 + quad * 8];
#pragma unroll
            for (int ni = 0; ni < 2; ++ni) {
                bh[ni] = *(const bf16x8*)&sBh[(wc * 32 + ni * 16 + m) * LDK + kk * 32 + quad * 8];
                bl[ni] = *(const bf16x8*)&sBl[(wc * 32 + ni * 16 + m) * LDK + kk * 32 + quad * 8];
            }
#pragma unroll
            for (int mi = 0; mi < 2; ++mi)
#pragma unroll
                for (int ni = 0; ni < 2; ++ni) {
                    acc[mi][ni] = __builtin_amdgcn_mfma_f32_16x16x32_bf16(ah[mi], bh[ni], acc[mi][ni], 0, 0, 0);
                    acc[mi][ni] = __builtin_amdgcn_mfma_f32_16x16x32_bf16(ah[mi], bl[ni], acc[mi][ni], 0, 0, 0);
                }
            if (amode) {
                bf16x8 al[2];
#pragma unroll
                for (int mi = 0; mi < 2; ++mi)
                    al[mi] = *(const bf16x8*)&sAl[(wr * 32 + mi * 16 + m) * LDK + kk * 32 + quad * 8];
#pragma unroll
                for (int mi = 0; mi < 2; ++mi)
#pragma unroll
                    for (int ni = 0; ni < 2; ++ni)
                        acc[mi][ni] = __builtin_amdgcn_mfma_f32_16x16x32_bf16(al[mi], bh[ni], acc[mi][ni], 0, 0, 0);
            }
        }
        __syncthreads();
    }
#pragma unroll
    for (int mi = 0; mi < 2; ++mi)
#pragma unroll
        for (int ni = 0; ni < 2; ++ni)
#pragma unroll
            for (int r = 0; r < 4; ++r) {
                int gi = i0 + wr * 32 + mi * 16 + quad * 4 + r;
                int gj = j0 + wc * 32 + ni * 16 + m;
                atomicAdd(&C[(size_t)gi * ldc + gj], acc[mi][ni][r]);
            }
}

// yT build: Bhi/Blo[c][k] = split_bf16( xw[k][c] * dinv[k] )
__global__ void build_yT(const float* __restrict__ xw, const float* __restrict__ dinv,
                         ushort* __restrict__ Bhi, ushort* __restrict__ Blo, int n, int f) {
    __shared__ float t[64][65];
    int k0 = blockIdx.x * 64, c0 = blockIdx.y * 64;
#pragma unroll
    for (int v = 0; v < 16; ++v) {
        int idx = threadIdx.x + v * 256;
        int r = idx >> 6, c = idx & 63;
        t[r][c] = xw[(size_t)(k0 + r) * f + (c0 + c)] * dinv[k0 + r];
    }
    __syncthreads();
#pragma unroll
    for (int v = 0; v < 16; ++v) {
        int idx = threadIdx.x + v * 256;
        int c = idx >> 6, k = idx & 63;
        float val = t[k][c];
        ushort hi = f32_to_bf16(val);
        size_t o = (size_t)(c0 + c) * n + (k0 + k);
        Bhi[o] = hi;
        Blo[o] = f32_to_bf16(val - bf2f(hi));
    }
}

__global__ void gcn_epilogue(const float* __restrict__ C, const float* __restrict__ xw,
                             const float* __restrict__ dinv, const float* __restrict__ selfw,
                             const float* __restrict__ b, float* __restrict__ out,
                             int n, int f, int relu) {
    int id = blockIdx.x * TPB + threadIdx.x;
    if (id >= n * f) return;
    int i = id / f, c = id - i * f;
    float y = xw[id] * dinv[i];
    float v = dinv[i] * (C[id] + selfw[i] * y) + b[c];
    if (relu) v = fmaxf(v, 0.f);
    out[id] = v;
}

// ---------------- degree/norm ----------------
__global__ void rowsum_dinv(const float* __restrict__ A, int n, float* dinv, float* selfw) {
    int i = blockIdx.x;
    const float* row = A + (size_t)i * n;
    float s = 0.f;
    for (int j = threadIdx.x; j < n; j += TPB) s += row[j];
    for (int o = 32; o; o >>= 1) s += __shfl_xor(s, o);
    __shared__ float sh[4];
    if ((threadIdx.x & 63) == 0) sh[threadIdx.x >> 6] = s;
    __syncthreads();
    if (threadIdx.x == 0) {
        float tot = sh[0] + sh[1] + sh[2] + sh[3];
        float d = row[i];
        float sw = (d == 0.f) ? 2.f : 0.f;
        dinv[i] = 1.0f / sqrtf(tot + sw);
        selfw[i] = sw;
    }
}

__global__ void rowsum_dinv_hl(const ushort* __restrict__ Ahi, const ushort* __restrict__ Alo,
                               int n, float* dinv, float* selfw) {
    int i = blockIdx.x;
    const ushort* rh = Ahi + (size_t)i * n;
    const ushort* rl = Alo + (size_t)i * n;
    float s = 0.f;
    for (int j = threadIdx.x; j < n; j += TPB) s += bf2f(rh[j]) + bf2f(rl[j]);
    for (int o = 32; o; o >>= 1) s += __shfl_xor(s, o);
    __shared__ float sh[4];
    if ((threadIdx.x & 63) == 0) sh[threadIdx.x >> 6] = s;
    __syncthreads();
    if (threadIdx.x == 0) {
        float tot = sh[0] + sh[1] + sh[2] + sh[3];
        float d = bf2f(rh[i]) + bf2f(rl[i]);
        float sw = (d == 0.f) ? 2.f : 0.f;
        dinv[i] = 1.0f / sqrtf(tot + sw);
        selfw[i] = sw;
    }
}

// ---------------- pooling ----------------
__global__ void vec_norm(const float* __restrict__ p, int f, float* out) {
    float s = 0.f;
    for (int c = threadIdx.x; c < f; c += 64) { float v = p[c]; s += v * v; }
    for (int o = 32; o; o >>= 1) s += __shfl_xor(s, o);
    if (threadIdx.x == 0) out[0] = sqrtf(s);
}

__global__ void score_kernel(const float* __restrict__ x, const float* __restrict__ p,
                             const float* __restrict__ nrm, float* __restrict__ s, int n, int f) {
    int i = blockIdx.x * TPB + threadIdx.x;
    if (i >= n) return;
    float a = 0.f;
    for (int c = 0; c < f; ++c) a += x[(size_t)i * f + c] * p[c];
    s[i] = tanhf(a / nrm[0]);
}

// parallel rank count: rank[i] += #(s[j]>s[i]) + #(s[j]==s[i] && j<i) over j-chunk
__global__ void rank_count(const float* __restrict__ s, int n, int* __restrict__ rank) {
    __shared__ float sj[256];
    int i = blockIdx.x * 256 + threadIdx.x;
    int j0 = blockIdx.y * 256;
    sj[threadIdx.x] = s[j0 + threadIdx.x];
    float si = s[i];
    __syncthreads();
    int r = 0;
#pragma unroll 8
    for (int jj = 0; jj < 256; ++jj) {
        float v = sj[jj];
        r += (v > si) || (v == si && (j0 + jj) < i);
    }
    atomicAdd(&rank[i], r);
}

__global__ void scatter_topk(const float* __restrict__ s, const int* __restrict__ rank,
                             int n, int k, int* __restrict__ perm, float* __restrict__ vals) {
    int i = blockIdx.x * TPB + threadIdx.x;
    if (i >= n) return;
    int r = rank[i];
    if (r < k) { perm[r] = i; vals[r] = s[i]; }
}

__global__ void gather_feat(const float* __restrict__ x, const int* __restrict__ perm,
                            const float* __restrict__ vals, int k, int f, float* __restrict__ h) {
    int id = blockIdx.x * TPB + threadIdx.x;
    if (id >= k * f) return;
    int r = id / f, c = id - r * f;
    h[id] = x[(size_t)perm[r] * f + c] * vals[r];
}

// ---------------- up path ----------------
__global__ void copy_k(const float* __restrict__ s, float* __restrict__ d, int n) {
    int id = blockIdx.x * TPB + threadIdx.x;
    if (id < n) d[id] = s[id];
}

__global__ void scatter_add_rows(const float* __restrict__ s, const int* __restrict__ perm,
                                 int k, int f, float* __restrict__ t) {
    int id = blockIdx.x * TPB + threadIdx.x;
    if (id >= k * f) return;
    int r = id / f, c = id - r * f;
    t[(size_t)perm[r] * f + c] += s[id];
}

// ---------------- layernorm ----------------
__global__ void layernorm(const float* __restrict__ h, const float* __restrict__ g,
                          const float* __restrict__ b, float* __restrict__ u, int n) {
    int i = blockIdx.x;
    int t = threadIdx.x;
    float v = h[(size_t)i * 128 + t];
    __shared__ float s0[2], s1[2];
    float sum = v;
    for (int o = 32; o; o >>= 1) sum += __shfl_xor(sum, o);
    if ((t & 63) == 0) s0[t >> 6] = sum;
    __syncthreads();
    float mu = (s0[0] + s0[1]) * (1.0f / 128.0f);
    float d = v - mu;
    float sq = d * d;
    for (int o = 32; o; o >>= 1) sq += __shfl_xor(sq, o);
    if ((t & 63) == 0) s1[t >> 6] = sq;
    __syncthreads();
    float var = (s1[0] + s1[1]) * (1.0f / 128.0f);
    u[(size_t)i * 128 + t] = d / sqrtf(var + 1e-6f) * g[t] + b[t];
}

// ---------------- GAT ----------------
__global__ void attn_coef(const float* __restrict__ hf, const float* __restrict__ asrc,
                          const float* __restrict__ adst, float* __restrict__ es,
                          float* __restrict__ ed, int n, int heads) {
    int id = blockIdx.x * TPB + threadIdx.x;
    if (id >= n * heads) return;
    int j = id / heads, h = id - j * heads;
    const float* hp = hf + (size_t)j * heads * 128 + h * 128;
    float a = 0.f, d = 0.f;
    for (int c = 0; c < 128; ++c) {
        float v = hp[c];
        a += v * asrc[h * 128 + c];
        d += v * adst[h * 128 + c];
    }
    es[id] = a;
    ed[id] = d;
}

#define MAXD 1024
__global__ void gat_kernel(const ushort* __restrict__ A0b, int n, const float* __restrict__ hf,
                           const float* __restrict__ es, const float* __restrict__ ed,
                           const float* __restrict__ bias, const float* __restrict__ resid,
                           float* __restrict__ out, int heads, int mode) {
    int i = blockIdx.x;
    int tid = threadIdx.x;
    __shared__ int cnt;
    __shared__ int idx[MAXD];
    __shared__ float lg[MAXD * 4];
    __shared__ float hmax[4], hsum[4];
    if (tid == 0) cnt = 0;
    __syncthreads();
    const ushort* row = A0b + (size_t)i * n;
    for (int j = tid; j < n; j += TPB) {
        if (row[j] != 0 || j == i) {
            int p = atomicAdd(&cnt, 1);
            if (p < MAXD) idx[p] = j;
        }
    }
    __syncthreads();
    int m = min(cnt, MAXD);
    for (int t = tid; t < m * heads; t += TPB) {
        int jl = t / heads, h = t - jl * heads;
        float l = ed[i * heads + h] + es[idx[jl] * heads + h];
        lg[jl * heads + h] = (l > 0.f) ? l : 0.2f * l;
    }
    __syncthreads();
    int h = tid >> 6, lane = tid & 63;
    if (h < heads) {
        float mx = -3.4e38f;
        for (int jl = lane; jl < m; jl += 64) mx = fmaxf(mx, lg[jl * heads + h]);
        for (int o = 32; o; o >>= 1) mx = fmaxf(mx, __shfl_xor(mx, o));
        if (lane == 0) hmax[h] = mx;
    }
    __syncthreads();
    if (h < heads) {
        float mx = hmax[h];
        float sm = 0.f;
        for (int jl = lane; jl < m; jl += 64) {
            float p = expf(lg[jl * heads + h] - mx);
            lg[jl * heads + h] = p;
            sm += p;
        }
        for (int o = 32; o; o >>= 1) sm += __shfl_xor(sm, o);
        if (lane == 0) hsum[h] = sm;
    }
    __syncthreads();
    int width = heads * 128;
    for (int o = tid; o < width; o += TPB) {
        int hh = o >> 7;
        float acc = 0.f;
        for (int jl = 0; jl < m; ++jl)
            acc += lg[jl * heads + hh] * hf[(size_t)idx[jl] * width + o];
        float v = acc / hsum[hh] + bias[o];
        if (mode == 0) v = (v > 0.f) ? v : expm1f(v);
        else v += resid[(size_t)i * width + o];
        out[(size_t)i * width + o] = v;
    }
}

// ---------------------------------------------------------------------------
static inline int cdiv(int a, int b) { return (a + b - 1) / b; }

static int pick_z(int gx, int gy, int K) {
    int z = 1;
    while (gx * gy * z < 384 && K / (2 * z) >= 64) z <<= 1;
    return z;
}

static void run_gcn(hipStream_t stream, int amode, const ushort* Ahi, const ushort* Alo,
                    int n, const float* xin, int fin,
                    const float* W, const float* bias, int f,
                    const float* dinv, const float* selfw,
                    float* xw, ushort* yThi, ushort* yTlo, float* Cp,
                    float* out, int relu) {
    gemm_bias<<<dim3(cdiv(f, 64), cdiv(n, 64)), TPB, 0, stream>>>(xin, W, nullptr, xw, n, fin, f);
    build_yT<<<dim3(n / 64, f / 64), TPB, 0, stream>>>(xw, dinv, yThi, yTlo, n, f);
    hipMemsetAsync(Cp, 0, (size_t)n * f * sizeof(float), stream);
    int z = pick_z(f / 64, n / 64, n);
    gcn_gemm<<<dim3(f / 64, n / 64, z), TPB, 0, stream>>>(Ahi, Alo, yThi, yTlo, Cp, n, f, n / z, amode);
    gcn_epilogue<<<cdiv(n * f, TPB), TPB, 0, stream>>>(Cp, xw, dinv, selfw, bias, out, n, f, relu);
}

static void run_topk(hipStream_t stream, const float* score, int n, int k, int* rank,
                     int* perm, float* vals) {
    hipMemsetAsync(rank, 0, n * sizeof(int), stream);
    rank_count<<<dim3(n / 256, n / 256), 256, 0, stream>>>(score, n, rank);
    scatter_topk<<<cdiv(n, TPB), TPB, 0, stream>>>(score, rank, n, k, perm, vals);
}

extern "C" void kernel_launch(void* const* d_in, const int* in_sizes, int n_in,
                              void* d_out, int out_size, void* d_ws, size_t ws_size,
                              hipStream_t stream) {
    const float* x   = (const float*)d_in[0];
    const int*   ei  = (const int*)d_in[1];
    const float* w0  = (const float*)d_in[2];  const float* b0  = (const float*)d_in[3];
    const float* w1  = (const float*)d_in[4];  const float* b1  = (const float*)d_in[5];
    const float* w2  = (const float*)d_in[6];  const float* b2  = (const float*)d_in[7];
    const float* w3  = (const float*)d_in[8];  const float* b3  = (const float*)d_in[9];
    const float* p1  = (const float*)d_in[10];
    const float* p2  = (const float*)d_in[11];
    const float* p3  = (const float*)d_in[12];
    const float* uw0 = (const float*)d_in[13]; const float* ub0 = (const float*)d_in[14];
    const float* uw1 = (const float*)d_in[15]; const float* ub1 = (const float*)d_in[16];
    const float* uw2 = (const float*)d_in[17]; const float* ub2 = (const float*)d_in[18];
    const float* lng = (const float*)d_in[19]; const float* lnb = (const float*)d_in[20];
    const float* rw  = (const float*)d_in[21]; const float* rb  = (const float*)d_in[22];
    const float* g1w = (const float*)d_in[23];
    const float* g1as = (const float*)d_in[24]; const float* g1ad = (const float*)d_in[25];
    const float* g1b = (const float*)d_in[26];
    const float* g2w = (const float*)d_in[27];
    const float* g2as = (const float*)d_in[28]; const float* g2ad = (const float*)d_in[29];
    const float* g2b = (const float*)d_in[30];

    const int N = 4096, E = 65536;
    const int K1 = 2048, K2 = 1024, K3 = 512;

    float* base = (float*)d_ws;
    size_t off = 0;
    auto alloc = [&](size_t nf) { float* p = base + off; off += (nf + 63) & ~(size_t)63; return p; };

    float* A0    = alloc((size_t)N * N);
    ushort* A0b  = (ushort*)alloc((size_t)N * N / 2);
    ushort* A1hi = (ushort*)alloc((size_t)K1 * K1 / 2);
    ushort* A1lo = (ushort*)alloc((size_t)K1 * K1 / 2);
    ushort* A2hi = (ushort*)alloc((size_t)K2 * K2 / 2);
    ushort* A2lo = (ushort*)alloc((size_t)K2 * K2 / 2);
    ushort* A3hi = (ushort*)alloc((size_t)K3 * K3 / 2);
    ushort* A3lo = (ushort*)alloc((size_t)K3 * K3 / 2);
    ushort* Tbf  = (ushort*)alloc((size_t)N * N / 2);
    ushort* Agb  = (ushort*)alloc((size_t)K1 * N / 2);
    ushort* Bgb  = (ushort*)alloc((size_t)K1 * N / 2);
    ushort* yThi = (ushort*)alloc((size_t)128 * N / 2);
    ushort* yTlo = (ushort*)alloc((size_t)128 * N / 2);
    float* Cp    = alloc((size_t)N * 128);
    float* x0    = alloc((size_t)N * 64);
    float* x1    = alloc((size_t)K1 * 64);
    float* x2    = alloc((size_t)K2 * 64);
    float* x3    = alloc((size_t)K3 * 64);
    float* h1    = alloc((size_t)K1 * 64);
    float* h2    = alloc((size_t)K2 * 64);
    float* h3    = alloc((size_t)K3 * 64);
    float* xw    = alloc((size_t)N * 128);
    float* dinv0 = alloc(N);  float* selfw0 = alloc(N);
    float* dinv1 = alloc(K1); float* selfw1 = alloc(K1);
    float* dinv2 = alloc(K2); float* selfw2 = alloc(K2);
    float* dinv3 = alloc(K3); float* selfw3 = alloc(K3);
    float* score = alloc(N);
    int*   rank  = (int*)alloc(N);
    float* vals1 = alloc(K1); float* vals2 = alloc(K2); float* vals3 = alloc(K3);
    int*   perm1 = (int*)alloc(K1); int* perm2 = (int*)alloc(K2); int* perm3 = (int*)alloc(K3);
    float* t2    = alloc((size_t)K2 * 64);
    float* t1    = alloc((size_t)K1 * 64);
    float* t0    = alloc((size_t)N * 64);
    float* hfin  = alloc((size_t)N * 128);
    float* u     = alloc((size_t)N * 128);
    float* resid = alloc((size_t)N * 128);
    float* hf1   = alloc((size_t)N * 512);
    float* es1   = alloc((size_t)N * 4); float* ed1 = alloc((size_t)N * 4);
    float* g1    = alloc((size_t)N * 512);
    float* hf2   = alloc((size_t)N * 128);
    float* es2   = alloc(N); float* ed2 = alloc(N);
    float* pn    = alloc(64);
    (void)ws_size; (void)n_in; (void)in_sizes; (void)out_size;

    // ---- A0 build + bf16 mirror + level-0 norm ----
    hipMemsetAsync(A0, 0, (size_t)N * N * sizeof(float), stream);
    scatter_edges<<<cdiv(E, TPB), TPB, 0, stream>>>(ei, E, A0, N);
    f32_arr_to_bf16<<<cdiv(N * N / 4, TPB), TPB, 0, stream>>>(A0, A0b, (size_t)N * N / 4);
    rowsum_dinv<<<N, TPB, 0, stream>>>(A0, N, dinv0, selfw0);

    // ---- down level 0 ----
    run_gcn(stream, 0, A0b, nullptr, N, x, 3, w0, b0, 64,
            dinv0, selfw0, xw, yThi, yTlo, Cp, x0, 1);

    // ---- level 1 ----
    vec_norm<<<1, 64, 0, stream>>>(p1, 64, pn);
    score_kernel<<<cdiv(N, TPB), TPB, 0, stream>>>(x0, p1, pn, score, N, 64);
    run_topk(stream, score, N, K1, rank, perm1, vals1);
    transpose_aug_b<<<dim3(N / 64, N / 64), TPB, 0, stream>>>(A0b, Tbf, N);
    gather_rows_aug_b<<<cdiv(K1 * N, TPB), TPB, 0, stream>>>(A0b, perm1, Agb, N, K1);
    gather_rows_u16<<<cdiv(K1 * N, TPB), TPB, 0, stream>>>(Tbf, perm1, Bgb, N, K1);
    augment_gemm_hl<<<dim3(K1 / 64, K1 / 64), TPB, 0, stream>>>(Agb, Bgb, A1hi, A1lo, N, K1);
    rowsum_dinv_hl<<<K1, TPB, 0, stream>>>(A1hi, A1lo, K1, dinv1, selfw1);
    gather_feat<<<cdiv(K1 * 64, TPB), TPB, 0, stream>>>(x0, perm1, vals1, K1, 64, h1);
    run_gcn(stream, 1, A1hi, A1lo, K1, h1, 64, w1, b1, 64,
            dinv1, selfw1, xw, yThi, yTlo, Cp, x1, 1);

    // ---- level 2 ----
    vec_norm<<<1, 64, 0, stream>>>(p2, 64, pn);
    score_kernel<<<cdiv(K1, TPB), TPB, 0, stream>>>(x1, p2, pn, score, K1, 64);
    run_topk(stream, score, K1, K2, rank, perm2, vals2);
    transpose_aug_hl<<<dim3(K1 / 64, K1 / 64), TPB, 0, stream>>>(A1hi, A1lo, Tbf, K1);
    gather_rows_aug_hl<<<cdiv(K2 * K1, TPB), TPB, 0, stream>>>(A1hi, A1lo, perm2, Agb, K1, K2);
    gather_rows_u16<<<cdiv(K2 * K1, TPB), TPB, 0, stream>>>(Tbf, perm2, Bgb, K1, K2);
    augment_gemm_hl<<<dim3(K2 / 64, K2 / 64), TPB, 0, stream>>>(Agb, Bgb, A2hi, A2lo, K1, K2);
    rowsum_dinv_hl<<<K2, TPB, 0, stream>>>(A2hi, A2lo, K2, dinv2, selfw2);
    gather_feat<<<cdiv(K2 * 64, TPB), TPB, 0, stream>>>(x1, perm2, vals2, K2, 64, h2);
    run_gcn(stream, 1, A2hi, A2lo, K2, h2, 64, w2, b2, 64,
            dinv2, selfw2, xw, yThi, yTlo, Cp, x2, 1);

    // ---- level 3 ----
    vec_norm<<<1, 64, 0, stream>>>(p3, 64, pn);
    score_kernel<<<cdiv(K2, TPB), TPB, 0, stream>>>(x2, p3, pn, score, K2, 64);
    run_topk(stream, score, K2, K3, rank, perm3, vals3);
    transpose_aug_hl<<<dim3(K2 / 64, K2 / 64), TPB, 0, stream>>>(A2hi, A2lo, Tbf, K2);
    gather_rows_aug_hl<<<cdiv(K3 * K2, TPB), TPB, 0, stream>>>(A2hi, A2lo, perm3, Agb, K2, K3);
    gather_rows_u16<<<cdiv(K3 * K2, TPB), TPB, 0, stream>>>(Tbf, perm3, Bgb, K2, K3);
    augment_gemm_hl<<<dim3(K3 / 64, K3 / 64), TPB, 0, stream>>>(Agb, Bgb, A3hi, A3lo, K2, K3);
    rowsum_dinv_hl<<<K3, TPB, 0, stream>>>(A3hi, A3lo, K3, dinv3, selfw3);
    gather_feat<<<cdiv(K3 * 64, TPB), TPB, 0, stream>>>(x2, perm3, vals3, K3, 64, h3);
    run_gcn(stream, 1, A3hi, A3lo, K3, h3, 64, w3, b3, 64,
            dinv3, selfw3, xw, yThi, yTlo, Cp, x3, 1);

    // ---- up path ----
    copy_k<<<cdiv(K2 * 64, TPB), TPB, 0, stream>>>(x2, t2, K2 * 64);
    scatter_add_rows<<<cdiv(K3 * 64, TPB), TPB, 0, stream>>>(x3, perm3, K3, 64, t2);
    run_gcn(stream, 1, A2hi, A2lo, K2, t2, 64, uw0, ub0, 64,
            dinv2, selfw2, xw, yThi, yTlo, Cp, h2, 1);

    copy_k<<<cdiv(K1 * 64, TPB), TPB, 0, stream>>>(x1, t1, K1 * 64);
    scatter_add_rows<<<cdiv(K2 * 64, TPB), TPB, 0, stream>>>(h2, perm2, K2, 64, t1);
    run_gcn(stream, 1, A1hi, A1lo, K1, t1, 64, uw1, ub1, 64,
            dinv1, selfw1, xw, yThi, yTlo, Cp, h1, 1);

    copy_k<<<cdiv(N * 64, TPB), TPB, 0, stream>>>(x0, t0, N * 64);
    scatter_add_rows<<<cdiv(K1 * 64, TPB), TPB, 0, stream>>>(h1, perm1, K1, 64, t0);
    run_gcn(stream, 0, A0b, nullptr, N, t0, 64, uw2, ub2, 128,
            dinv0, selfw0, xw, yThi, yTlo, Cp, hfin, 0);

    // ---- layernorm + residual ----
    layernorm<<<N, 128, 0, stream>>>(hfin, lng, lnb, u, N);
    gemm_bias<<<dim3(cdiv(128, 64), cdiv(N, 64)), TPB, 0, stream>>>(u, rw, rb, resid, N, 128, 128);

    // ---- GAT layer 1 (4 heads, concat, ELU) ----
    gemm_bias<<<dim3(cdiv(512, 64), cdiv(N, 64)), TPB, 0, stream>>>(u, g1w, nullptr, hf1, N, 128, 512);
    attn_coef<<<cdiv(N * 4, TPB), TPB, 0, stream>>>(hf1, g1as, g1ad, es1, ed1, N, 4);
    gat_kernel<<<N, TPB, 0, stream>>>(A0b, N, hf1, es1, ed1, g1b, nullptr, g1, 4, 0);

    // ---- GAT layer 2 (1 head) + residual ----
    gemm_bias<<<dim3(cdiv(128, 64), cdiv(N, 64)), TPB, 0, stream>>>(g1, g2w, nullptr, hf2, N, 512, 128);
    attn_coef<<<cdiv(N, TPB), TPB, 0, stream>>>(hf2, g2as, g2ad, es2, ed2, N, 1);
    gat_kernel<<<N, TPB, 0, stream>>>(A0b, N, hf2, es2, ed2, g2b, resid, (float*)d_out, 1, 1);
}

// Round 5
// 771.598 us; speedup vs baseline: 6.4069x; 1.2450x over previous
//
#include <hip/hip_runtime.h>
#include <math.h>

// ---------------------------------------------------------------------------
// GraphUNet + GAT pipeline. N=4096, E=65536, IN=3, H=64, OUT=128, HEADS=4
// Round 5: m97-style 128-tile global_load_lds GEMM for K1 augment; A0 built
// directly as bf16 (CAS); degrees from edge list; sparse neighbor list for
// GAT; split-bf16 MFMA for resid/hf1/hf2 projections.
// ---------------------------------------------------------------------------

#define TPB 256
#define LDK 88
#define MAXN 128

typedef __attribute__((ext_vector_type(8))) short bf16x8;
typedef __attribute__((ext_vector_type(4))) float f32x4;

__device__ inline ushort f32_to_bf16(float v) {
    unsigned b = __float_as_uint(v);
    return (ushort)((b + 0x7FFF + ((b >> 16) & 1)) >> 16);
}
__device__ inline float bf2f(ushort u) { return __uint_as_float(((unsigned)u) << 16); }

__device__ __forceinline__ void gl_lds16(const ushort* g, ushort* l) {
    __builtin_amdgcn_global_load_lds((const __attribute__((address_space(1))) void*)g,
                                     (__attribute__((address_space(3))) void*)l, 16, 0, 0);
}

// ---------------- adjacency build (direct bf16 + degree from edges) --------
__global__ void scatter_edges_b(const int* __restrict__ ei, int E, ushort* __restrict__ A,
                                int n, int* __restrict__ deg, int* __restrict__ diag) {
    int e = blockIdx.x * TPB + threadIdx.x;
    if (e >= E) return;
    int src = ei[e];
    int dst = ei[E + e];
    atomicAdd(&deg[dst], 1);
    if (src == dst) diag[src] = 1;
    size_t idx = (size_t)dst * n + src;
    uint* word = (uint*)(A + (idx & ~(size_t)1));
    bool hi = (idx & 1);
    uint old = *word, assumed;
    do {
        assumed = old;
        ushort cur = hi ? (ushort)(assumed >> 16) : (ushort)(assumed & 0xffff);
        ushort nv = f32_to_bf16(bf2f(cur) + 1.0f);
        uint neww = hi ? ((assumed & 0x0000ffffu) | ((uint)nv << 16))
                       : ((assumed & 0xffff0000u) | nv);
        old = atomicCAS(word, assumed, neww);
    } while (old != assumed);
}

__global__ void dinv_from_deg(const int* __restrict__ deg, const int* __restrict__ diag,
                              int n, float* __restrict__ dinv, float* __restrict__ selfw) {
    int i = blockIdx.x * TPB + threadIdx.x;
    if (i >= n) return;
    float sw = diag[i] ? 0.f : 2.f;
    dinv[i] = 1.0f / sqrtf((float)deg[i] + sw);
    selfw[i] = sw;
}

// ---------------- generic fp32 GEMM (small xw projections only) ------------
__global__ void gemm_bias(const float* __restrict__ A, const float* __restrict__ B,
                          const float* __restrict__ bias, float* __restrict__ C,
                          int M, int K, int N) {
    __shared__ float As[16][65];
    __shared__ float Bs[16][65];
    int tx = threadIdx.x & 15, ty = threadIdx.x >> 4;
    int i0 = blockIdx.y * 64, j0 = blockIdx.x * 64;
    float acc[4][4] = {};
    for (int k0 = 0; k0 < K; k0 += 16) {
        for (int t = threadIdx.x; t < 1024; t += TPB) {
            int r = t >> 4, c = t & 15;
            int gi = i0 + r, gk = k0 + c;
            As[c][r] = (gi < M && gk < K) ? A[(size_t)gi * K + gk] : 0.f;
        }
        for (int t = threadIdx.x; t < 1024; t += TPB) {
            int r = t >> 6, c = t & 63;
            int gk = k0 + r, gj = j0 + c;
            Bs[r][c] = (gk < K && gj < N) ? B[(size_t)gk * N + gj] : 0.f;
        }
        __syncthreads();
        for (int kk = 0; kk < 16; ++kk) {
            float a[4], b[4];
#pragma unroll
            for (int u = 0; u < 4; ++u) a[u] = As[kk][ty * 4 + u];
#pragma unroll
            for (int v = 0; v < 4; ++v) b[v] = Bs[kk][tx * 4 + v];
#pragma unroll
            for (int u = 0; u < 4; ++u)
#pragma unroll
                for (int v = 0; v < 4; ++v) acc[u][v] += a[u] * b[v];
        }
        __syncthreads();
    }
    for (int u = 0; u < 4; ++u)
        for (int v = 0; v < 4; ++v) {
            int gi = i0 + ty * 4 + u, gj = j0 + tx * 4 + v;
            if (gi < M && gj < N) {
                float val = acc[u][v];
                if (bias) val += bias[gj];
                C[(size_t)gi * N + gj] = val;
            }
        }
}

// ---------------- augment path ----------------
__global__ void transpose_aug_b(const ushort* __restrict__ A, ushort* __restrict__ T, int n) {
    __shared__ float tile[64][65];
    int c0 = blockIdx.x * 64, r0 = blockIdx.y * 64;
    for (int t = threadIdx.x; t < 4096; t += TPB) {
        int r = t >> 6, c = t & 63;
        float v = bf2f(A[(size_t)(r0 + r) * n + (c0 + c)]);
        if (r0 + r == c0 + c) v += 1.0f;
        tile[c][r] = v;
    }
    __syncthreads();
    for (int t = threadIdx.x; t < 4096; t += TPB) {
        int c = t >> 6, r = t & 63;
        T[(size_t)(c0 + c) * n + (r0 + r)] = f32_to_bf16(tile[c][r]);
    }
}

__global__ void transpose_aug_hl(const ushort* __restrict__ Ahi, const ushort* __restrict__ Alo,
                                 ushort* __restrict__ T, int n) {
    __shared__ float tile[64][65];
    int c0 = blockIdx.x * 64, r0 = blockIdx.y * 64;
    for (int t = threadIdx.x; t < 4096; t += TPB) {
        int r = t >> 6, c = t & 63;
        size_t o = (size_t)(r0 + r) * n + (c0 + c);
        float v = bf2f(Ahi[o]) + bf2f(Alo[o]);
        if (r0 + r == c0 + c) v += 1.0f;
        tile[c][r] = v;
    }
    __syncthreads();
    for (int t = threadIdx.x; t < 4096; t += TPB) {
        int c = t >> 6, r = t & 63;
        T[(size_t)(c0 + c) * n + (r0 + r)] = f32_to_bf16(tile[c][r]);
    }
}

__global__ void gather_rows_aug_b(const ushort* __restrict__ A, const int* __restrict__ perm,
                                  ushort* __restrict__ Ag, int n, int rows) {
    int id = blockIdx.x * TPB + threadIdx.x;
    if (id >= rows * n) return;
    int r = id / n, t = id - r * n;
    int pr = perm[r];
    float v = bf2f(A[(size_t)pr * n + t]);
    if (pr == t) v += 1.0f;
    Ag[id] = f32_to_bf16(v);
}

__global__ void gather_rows_aug_hl(const ushort* __restrict__ Ahi, const ushort* __restrict__ Alo,
                                   const int* __restrict__ perm, ushort* __restrict__ Ag,
                                   int n, int rows) {
    int id = blockIdx.x * TPB + threadIdx.x;
    if (id >= rows * n) return;
    int r = id / n, t = id - r * n;
    int pr = perm[r];
    size_t o = (size_t)pr * n + t;
    float v = bf2f(Ahi[o]) + bf2f(Alo[o]);
    if (pr == t) v += 1.0f;
    Ag[id] = f32_to_bf16(v);
}

__global__ void gather_rows_u16(const ushort* __restrict__ T, const int* __restrict__ perm,
                                ushort* __restrict__ Bg, int n, int rows) {
    int id = blockIdx.x * TPB + threadIdx.x;
    if (id >= rows * n) return;
    int r = id / n, t = id - r * n;
    Bg[id] = T[(size_t)perm[r] * n + t];
}

// 128x128-tile B^T GEMM via global_load_lds, XOR-swizzled LDS (2-way conflicts only).
// C[r][c] = sum_t Ag[r][t]*Bg[c][t]; diag zeroed; split hi/lo output.
__global__ void __launch_bounds__(256)
aug_gemm128(const ushort* __restrict__ Ag, const ushort* __restrict__ Bg,
            ushort* __restrict__ Chi, ushort* __restrict__ Clo, int K, int ldc) {
    __shared__ __align__(16) ushort As[128 * 64];
    __shared__ __align__(16) ushort Bs[128 * 64];
    int tid = threadIdx.x, wave = tid >> 6, lane = tid & 63;
    int wr = wave >> 1, wc = wave & 1;
    int m = lane & 15, quad = lane >> 4;
    int i0 = blockIdx.y * 128, j0 = blockIdx.x * 128;
    int lr = lane >> 3;                      // row within 8-row chunk
    int lc8 = ((lane & 7) ^ lr) * 8;         // swizzled global col-block
    const ushort* Abase = Ag + (size_t)(i0 + lr) * K + lc8;
    const ushort* Bbase = Bg + (size_t)(j0 + lr) * K + lc8;
    f32x4 acc[4][4];
#pragma unroll
    for (int a = 0; a < 4; ++a)
#pragma unroll
        for (int b = 0; b < 4; ++b) acc[a][b] = (f32x4){0.f, 0.f, 0.f, 0.f};
    int sw = m & 7;                          // swizzle key for fragment reads
    for (int k0 = 0; k0 < K; k0 += 64) {
#pragma unroll
        for (int c = 0; c < 4; ++c) {
            int ch = wave + c * 4;           // chunk 0..15 (8 rows each)
            gl_lds16(Abase + (size_t)ch * 8 * K + k0, &As[ch * 512 + lane * 8]);
            gl_lds16(Bbase + (size_t)ch * 8 * K + k0, &Bs[ch * 512 + lane * 8]);
        }
        __syncthreads();
#pragma unroll
        for (int kk = 0; kk < 2; ++kk) {
            int cbs = ((kk * 4 + quad) ^ sw) * 8;
            bf16x8 af[4], bfr[4];
#pragma unroll
            for (int t = 0; t < 4; ++t) {
                af[t]  = *(const bf16x8*)&As[(wr * 64 + t * 16 + m) * 64 + cbs];
                bfr[t] = *(const bf16x8*)&Bs[(wc * 64 + t * 16 + m) * 64 + cbs];
            }
#pragma unroll
            for (int mi = 0; mi < 4; ++mi)
#pragma unroll
                for (int ni = 0; ni < 4; ++ni)
                    acc[mi][ni] = __builtin_amdgcn_mfma_f32_16x16x32_bf16(
                        af[mi], bfr[ni], acc[mi][ni], 0, 0, 0);
        }
        __syncthreads();
    }
#pragma unroll
    for (int mi = 0; mi < 4; ++mi)
#pragma unroll
        for (int ni = 0; ni < 4; ++ni)
#pragma unroll
            for (int r = 0; r < 4; ++r) {
                int gi = i0 + wr * 64 + mi * 16 + quad * 4 + r;
                int gj = j0 + wc * 64 + ni * 16 + m;
                float val = (gi == gj) ? 0.f : acc[mi][ni][r];
                ushort hi = f32_to_bf16(val);
                size_t o = (size_t)gi * ldc + gj;
                Chi[o] = hi;
                Clo[o] = f32_to_bf16(val - bf2f(hi));
            }
}

// 64-tile variant for small levels (K2, K3 — too few blocks for 128-tile).
__global__ void __launch_bounds__(256)
augment_gemm_hl(const ushort* __restrict__ Ag, const ushort* __restrict__ Bg,
                ushort* __restrict__ Chi, ushort* __restrict__ Clo, int K, int ldc) {
    __shared__ __align__(16) ushort As[64 * LDK];
    __shared__ __align__(16) ushort Bs[64 * LDK];
    int tid = threadIdx.x;
    int wave = tid >> 6, lane = tid & 63;
    int wr = wave >> 1, wc = wave & 1;
    int m = lane & 15, quad = lane >> 4;
    int i0 = blockIdx.y * 64, j0 = blockIdx.x * 64;
    f32x4 acc[2][2];
#pragma unroll
    for (int a = 0; a < 2; ++a)
#pragma unroll
        for (int b = 0; b < 2; ++b) acc[a][b] = (f32x4){0.f, 0.f, 0.f, 0.f};
    const ushort* Ab = Ag + (size_t)i0 * K;
    const ushort* Bb = Bg + (size_t)j0 * K;
    for (int k0 = 0; k0 < K; k0 += 64) {
#pragma unroll
        for (int v = 0; v < 2; ++v) {
            int idx = tid + (v << 8);
            int r = idx >> 3, c8 = idx & 7;
            *(uint4*)&As[r * LDK + c8 * 8] = *(const uint4*)&Ab[(size_t)r * K + k0 + c8 * 8];
            *(uint4*)&Bs[r * LDK + c8 * 8] = *(const uint4*)&Bb[(size_t)r * K + k0 + c8 * 8];
        }
        __syncthreads();
#pragma unroll
        for (int kk = 0; kk < 2; ++kk) {
            bf16x8 af[2], bfr[2];
#pragma unroll
            for (int mi = 0; mi < 2; ++mi)
                af[mi] = *(const bf16x8*)&As[(wr * 32 + mi * 16 + m) * LDK + kk * 32 + quad * 8];
#pragma unroll
            for (int ni = 0; ni < 2; ++ni)
                bfr[ni] = *(const bf16x8*)&Bs[(wc * 32 + ni * 16 + m) * LDK + kk * 32 + quad * 8];
#pragma unroll
            for (int mi = 0; mi < 2; ++mi)
#pragma unroll
                for (int ni = 0; ni < 2; ++ni)
                    acc[mi][ni] = __builtin_amdgcn_mfma_f32_16x16x32_bf16(
                        af[mi], bfr[ni], acc[mi][ni], 0, 0, 0);
        }
        __syncthreads();
    }
#pragma unroll
    for (int mi = 0; mi < 2; ++mi)
#pragma unroll
        for (int ni = 0; ni < 2; ++ni)
#pragma unroll
            for (int r = 0; r < 4; ++r) {
                int gi = i0 + wr * 32 + mi * 16 + quad * 4 + r;
                int gj = j0 + wc * 32 + ni * 16 + m;
                float val = (gi == gj) ? 0.f : acc[mi][ni][r];
                ushort hi = f32_to_bf16(val);
                size_t o = (size_t)gi * ldc + gj;
                Chi[o] = hi;
                Clo[o] = f32_to_bf16(val - bf2f(hi));
            }
}

// ---------------- GCN aggregation (split bf16 MFMA, split-K atomics) -------
__global__ void __launch_bounds__(256)
gcn_gemm(const ushort* __restrict__ Ahi, const ushort* __restrict__ Alo,
         const ushort* __restrict__ Bhi, const ushort* __restrict__ Blo,
         float* __restrict__ C, int K, int ldc, int kpb, int amode) {
    __shared__ __align__(16) ushort sAh[64 * LDK];
    __shared__ __align__(16) ushort sAl[64 * LDK];
    __shared__ __align__(16) ushort sBh[64 * LDK];
    __shared__ __align__(16) ushort sBl[64 * LDK];
    int tid = threadIdx.x;
    int wave = tid >> 6, lane = tid & 63;
    int wr = wave >> 1, wc = wave & 1;
    int m = lane & 15, quad = lane >> 4;
    int i0 = blockIdx.y * 64, j0 = blockIdx.x * 64;
    int kbeg = blockIdx.z * kpb;
    f32x4 acc[2][2];
#pragma unroll
    for (int a = 0; a < 2; ++a)
#pragma unroll
        for (int b = 0; b < 2; ++b) acc[a][b] = (f32x4){0.f, 0.f, 0.f, 0.f};
    for (int k0 = kbeg; k0 < kbeg + kpb; k0 += 64) {
#pragma unroll
        for (int v = 0; v < 2; ++v) {
            int idx = tid + (v << 8);
            int r = idx >> 3, c8 = idx & 7;
            size_t boff = (size_t)(j0 + r) * K + k0 + c8 * 8;
            *(uint4*)&sBh[r * LDK + c8 * 8] = *(const uint4*)&Bhi[boff];
            *(uint4*)&sBl[r * LDK + c8 * 8] = *(const uint4*)&Blo[boff];
            size_t aoff = (size_t)(i0 + r) * K + k0 + c8 * 8;
            *(uint4*)&sAh[r * LDK + c8 * 8] = *(const uint4*)&Ahi[aoff];
            if (amode)
                *(uint4*)&sAl[r * LDK + c8 * 8] = *(const uint4*)&Alo[aoff];
        }
        __syncthreads();
#pragma unroll
        for (int kk = 0; kk < 2; ++kk) {
            bf16x8 ah[2], bh[2], bl[2];
#pragma unroll
            for (int mi = 0; mi < 2; ++mi)
                ah[mi] = *(const bf16x8*)&sAh[(wr * 32 + mi * 16 + m) * LDK + kk * 32 + quad * 8];
#pragma unroll
            for (int ni = 0; ni < 2; ++ni) {
                bh[ni] = *(const bf16x8*)&sBh[(wc * 32 + ni * 16 + m) * LDK + kk * 32 + quad * 8];
                bl[ni] = *(const bf16x8*)&sBl[(wc * 32 + ni * 16 + m) * LDK + kk * 32 + quad * 8];
            }
#pragma unroll
            for (int mi = 0; mi < 2; ++mi)
#pragma unroll
                for (int ni = 0; ni < 2; ++ni) {
                    acc[mi][ni] = __builtin_amdgcn_mfma_f32_16x16x32_bf16(ah[mi], bh[ni], acc[mi][ni], 0, 0, 0);
                    acc[mi][ni] = __builtin_amdgcn_mfma_f32_16x16x32_bf16(ah[mi], bl[ni], acc[mi][ni], 0, 0, 0);
                }
            if (amode) {
                bf16x8 al[2];
#pragma unroll
                for (int mi = 0; mi < 2; ++mi)
                    al[mi] = *(const bf16x8*)&sAl[(wr * 32 + mi * 16 + m) * LDK + kk * 32 + quad * 8];
#pragma unroll
                for (int mi = 0; mi < 2; ++mi)
#pragma unroll
                    for (int ni = 0; ni < 2; ++ni)
                        acc[mi][ni] = __builtin_amdgcn_mfma_f32_16x16x32_bf16(al[mi], bh[ni], acc[mi][ni], 0, 0, 0);
            }
        }
        __syncthreads();
    }
#pragma unroll
    for (int mi = 0; mi < 2; ++mi)
#pragma unroll
        for (int ni = 0; ni < 2; ++ni)
#pragma unroll
            for (int r = 0; r < 4; ++r) {
                int gi = i0 + wr * 32 + mi * 16 + quad * 4 + r;
                int gj = j0 + wc * 32 + ni * 16 + m;
                atomicAdd(&C[(size_t)gi * ldc + gj], acc[mi][ni][r]);
            }
}

__global__ void build_yT(const float* __restrict__ xw, const float* __restrict__ dinv,
                         ushort* __restrict__ Bhi, ushort* __restrict__ Blo, int n, int f) {
    __shared__ float t[64][65];
    int k0 = blockIdx.x * 64, c0 = blockIdx.y * 64;
#pragma unroll
    for (int v = 0; v < 16; ++v) {
        int idx = threadIdx.x + v * 256;
        int r = idx >> 6, c = idx & 63;
        t[r][c] = xw[(size_t)(k0 + r) * f + (c0 + c)] * dinv[k0 + r];
    }
    __syncthreads();
#pragma unroll
    for (int v = 0; v < 16; ++v) {
        int idx = threadIdx.x + v * 256;
        int c = idx >> 6, k = idx & 63;
        float val = t[k][c];
        ushort hi = f32_to_bf16(val);
        size_t o = (size_t)(c0 + c) * n + (k0 + k);
        Bhi[o] = hi;
        Blo[o] = f32_to_bf16(val - bf2f(hi));
    }
}

__global__ void gcn_epilogue(const float* __restrict__ C, const float* __restrict__ xw,
                             const float* __restrict__ dinv, const float* __restrict__ selfw,
                             const float* __restrict__ b, float* __restrict__ out,
                             int n, int f, int relu) {
    int id = blockIdx.x * TPB + threadIdx.x;
    if (id >= n * f) return;
    int i = id / f, c = id - i * f;
    float y = xw[id] * dinv[i];
    float v = dinv[i] * (C[id] + selfw[i] * y) + b[c];
    if (relu) v = fmaxf(v, 0.f);
    out[id] = v;
}

__global__ void rowsum_dinv_hl(const ushort* __restrict__ Ahi, const ushort* __restrict__ Alo,
                               int n, float* dinv, float* selfw) {
    int i = blockIdx.x;
    const ushort* rh = Ahi + (size_t)i * n;
    const ushort* rl = Alo + (size_t)i * n;
    float s = 0.f;
    for (int j = threadIdx.x; j < n; j += TPB) s += bf2f(rh[j]) + bf2f(rl[j]);
    for (int o = 32; o; o >>= 1) s += __shfl_xor(s, o);
    __shared__ float sh[4];
    if ((threadIdx.x & 63) == 0) sh[threadIdx.x >> 6] = s;
    __syncthreads();
    if (threadIdx.x == 0) {
        float tot = sh[0] + sh[1] + sh[2] + sh[3];
        float d = bf2f(rh[i]) + bf2f(rl[i]);
        float sw = (d == 0.f) ? 2.f : 0.f;
        dinv[i] = 1.0f / sqrtf(tot + sw);
        selfw[i] = sw;
    }
}

// ---------------- pooling ----------------
__global__ void vec_norm(const float* __restrict__ p, int f, float* out) {
    float s = 0.f;
    for (int c = threadIdx.x; c < f; c += 64) { float v = p[c]; s += v * v; }
    for (int o = 32; o; o >>= 1) s += __shfl_xor(s, o);
    if (threadIdx.x == 0) out[0] = sqrtf(s);
}

__global__ void score_kernel(const float* __restrict__ x, const float* __restrict__ p,
                             const float* __restrict__ nrm, float* __restrict__ s, int n, int f) {
    int i = blockIdx.x * TPB + threadIdx.x;
    if (i >= n) return;
    float a = 0.f;
    for (int c = 0; c < f; ++c) a += x[(size_t)i * f + c] * p[c];
    s[i] = tanhf(a / nrm[0]);
}

__global__ void rank_count(const float* __restrict__ s, int n, int* __restrict__ rank) {
    __shared__ float sj[256];
    int i = blockIdx.x * 256 + threadIdx.x;
    int j0 = blockIdx.y * 256;
    sj[threadIdx.x] = s[j0 + threadIdx.x];
    float si = s[i];
    __syncthreads();
    int r = 0;
#pragma unroll 8
    for (int jj = 0; jj < 256; ++jj) {
        float v = sj[jj];
        r += (v > si) || (v == si && (j0 + jj) < i);
    }
    atomicAdd(&rank[i], r);
}

__global__ void scatter_topk(const float* __restrict__ s, const int* __restrict__ rank,
                             int n, int k, int* __restrict__ perm, float* __restrict__ vals) {
    int i = blockIdx.x * TPB + threadIdx.x;
    if (i >= n) return;
    int r = rank[i];
    if (r < k) { perm[r] = i; vals[r] = s[i]; }
}

__global__ void gather_feat(const float* __restrict__ x, const int* __restrict__ perm,
                            const float* __restrict__ vals, int k, int f, float* __restrict__ h) {
    int id = blockIdx.x * TPB + threadIdx.x;
    if (id >= k * f) return;
    int r = id / f, c = id - r * f;
    h[id] = x[(size_t)perm[r] * f + c] * vals[r];
}

// ---------------- up path ----------------
__global__ void copy_k(const float* __restrict__ s, float* __restrict__ d, int n) {
    int id = blockIdx.x * TPB + threadIdx.x;
    if (id < n) d[id] = s[id];
}

__global__ void scatter_add_rows(const float* __restrict__ s, const int* __restrict__ perm,
                                 int k, int f, float* __restrict__ t) {
    int id = blockIdx.x * TPB + threadIdx.x;
    if (id >= k * f) return;
    int r = id / f, c = id - r * f;
    t[(size_t)perm[r] * f + c] += s[id];
}

// ---------------- layernorm ----------------
__global__ void layernorm(const float* __restrict__ h, const float* __restrict__ g,
                          const float* __restrict__ b, float* __restrict__ u, int n) {
    int i = blockIdx.x;
    int t = threadIdx.x;
    float v = h[(size_t)i * 128 + t];
    __shared__ float s0[2], s1[2];
    float sum = v;
    for (int o = 32; o; o >>= 1) sum += __shfl_xor(sum, o);
    if ((t & 63) == 0) s0[t >> 6] = sum;
    __syncthreads();
    float mu = (s0[0] + s0[1]) * (1.0f / 128.0f);
    float d = v - mu;
    float sq = d * d;
    for (int o = 32; o; o >>= 1) sq += __shfl_xor(sq, o);
    if ((t & 63) == 0) s1[t >> 6] = sq;
    __syncthreads();
    float var = (s1[0] + s1[1]) * (1.0f / 128.0f);
    u[(size_t)i * 128 + t] = d / sqrtf(var + 1e-6f) * g[t] + b[t];
}

// ---------------- dense projections via split-bf16 MFMA --------------------
// W[K x N] fp32 -> Bhi/Blo[N x K] bf16 hi/lo
__global__ void transpose_split(const float* __restrict__ W, ushort* __restrict__ Bhi,
                                ushort* __restrict__ Blo, int K, int N) {
    __shared__ float tile[64][65];
    int n0 = blockIdx.x * 64, k0 = blockIdx.y * 64;
    for (int t = threadIdx.x; t < 4096; t += TPB) {
        int r = t >> 6, c = t & 63;
        tile[r][c] = W[(size_t)(k0 + r) * N + (n0 + c)];
    }
    __syncthreads();
    for (int t = threadIdx.x; t < 4096; t += TPB) {
        int c = t >> 6, r = t & 63;
        float v = tile[r][c];
        ushort hi = f32_to_bf16(v);
        size_t o = (size_t)(n0 + c) * K + (k0 + r);
        Bhi[o] = hi;
        Blo[o] = f32_to_bf16(v - bf2f(hi));
    }
}

// C[i][j] = sum_k A[i][k]*B[j][k] (+bias); A fp32 (split in staging), B pre-split.
__global__ void __launch_bounds__(256)
gemm_bt_split(const float* __restrict__ A, const ushort* __restrict__ Bhi,
              const ushort* __restrict__ Blo, const float* __restrict__ bias,
              float* __restrict__ C, int K, int N) {
    __shared__ __align__(16) ushort sAh[64 * LDK];
    __shared__ __align__(16) ushort sAl[64 * LDK];
    __shared__ __align__(16) ushort sBh[64 * LDK];
    __shared__ __align__(16) ushort sBl[64 * LDK];
    int tid = threadIdx.x;
    int wave = tid >> 6, lane = tid & 63;
    int wr = wave >> 1, wc = wave & 1;
    int m = lane & 15, quad = lane >> 4;
    int i0 = blockIdx.y * 64, j0 = blockIdx.x * 64;
    f32x4 acc[2][2];
#pragma unroll
    for (int a = 0; a < 2; ++a)
#pragma unroll
        for (int b = 0; b < 2; ++b) acc[a][b] = (f32x4){0.f, 0.f, 0.f, 0.f};
    for (int k0 = 0; k0 < K; k0 += 64) {
#pragma unroll
        for (int v = 0; v < 2; ++v) {
            int idx = tid + (v << 8);
            int r = idx >> 3, c8 = idx & 7;
            size_t boff = (size_t)(j0 + r) * K + k0 + c8 * 8;
            *(uint4*)&sBh[r * LDK + c8 * 8] = *(const uint4*)&Bhi[boff];
            *(uint4*)&sBl[r * LDK + c8 * 8] = *(const uint4*)&Blo[boff];
            size_t aoff = (size_t)(i0 + r) * K + k0 + c8 * 8;
            float4 fa = *(const float4*)&A[aoff];
            float4 fb = *(const float4*)&A[aoff + 4];
            ushort h0 = f32_to_bf16(fa.x), h1 = f32_to_bf16(fa.y);
            ushort h2 = f32_to_bf16(fa.z), h3 = f32_to_bf16(fa.w);
            ushort h4 = f32_to_bf16(fb.x), h5 = f32_to_bf16(fb.y);
            ushort h6 = f32_to_bf16(fb.z), h7 = f32_to_bf16(fb.w);
            uint4 ph, pl;
            ph.x = (uint)h0 | ((uint)h1 << 16);
            ph.y = (uint)h2 | ((uint)h3 << 16);
            ph.z = (uint)h4 | ((uint)h5 << 16);
            ph.w = (uint)h6 | ((uint)h7 << 16);
            pl.x = (uint)f32_to_bf16(fa.x - bf2f(h0)) | ((uint)f32_to_bf16(fa.y - bf2f(h1)) << 16);
            pl.y = (uint)f32_to_bf16(fa.z - bf2f(h2)) | ((uint)f32_to_bf16(fa.w - bf2f(h3)) << 16);
            pl.z = (uint)f32_to_bf16(fb.x - bf2f(h4)) | ((uint)f32_to_bf16(fb.y - bf2f(h5)) << 16);
            pl.w = (uint)f32_to_bf16(fb.z - bf2f(h6)) | ((uint)f32_to_bf16(fb.w - bf2f(h7)) << 16);
            *(uint4*)&sAh[r * LDK + c8 * 8] = ph;
            *(uint4*)&sAl[r * LDK + c8 * 8] = pl;
        }
        __syncthreads();
#pragma unroll
        for (int kk = 0; kk < 2; ++kk) {
            bf16x8 ah[2], al[2], bh[2], bl[2];
#pragma unroll
            for (int mi = 0; mi < 2; ++mi) {
                ah[mi] = *(const bf16x8*)&sAh[(wr * 32 + mi * 16 + m) * LDK + kk * 32 + quad * 8];
                al[mi] = *(const bf16x8*)&sAl[(wr * 32 + mi * 16 + m) * LDK + kk * 32 + quad * 8];
            }
#pragma unroll
            for (int ni = 0; ni < 2; ++ni) {
                bh[ni] = *(const bf16x8*)&sBh[(wc * 32 + ni * 16 + m) * LDK + kk * 32 + quad * 8];
                bl[ni] = *(const bf16x8*)&sBl[(wc * 32 + ni * 16 + m) * LDK + kk * 32 + quad * 8];
            }
#pragma unroll
            for (int mi = 0; mi < 2; ++mi)
#pragma unroll
                for (int ni = 0; ni < 2; ++ni) {
                    acc[mi][ni] = __builtin_amdgcn_mfma_f32_16x16x32_bf16(ah[mi], bh[ni], acc[mi][ni], 0, 0, 0);
                    acc[mi][ni] = __builtin_amdgcn_mfma_f32_16x16x32_bf16(ah[mi], bl[ni], acc[mi][ni], 0, 0, 0);
                    acc[mi][ni] = __builtin_amdgcn_mfma_f32_16x16x32_bf16(al[mi], bh[ni], acc[mi][ni], 0, 0, 0);
                }
        }
        __syncthreads();
    }
#pragma unroll
    for (int mi = 0; mi < 2; ++mi)
#pragma unroll
        for (int ni = 0; ni < 2; ++ni)
#pragma unroll
            for (int r = 0; r < 4; ++r) {
                int gi = i0 + wr * 32 + mi * 16 + quad * 4 + r;
                int gj = j0 + wc * 32 + ni * 16 + m;
                float v = acc[mi][ni][r];
                if (bias) v += bias[gj];
                C[(size_t)gi * N + gj] = v;
            }
}

// ---------------- GAT (sparse neighbor list) ----------------
__global__ void attn_coef(const float* __restrict__ hf, const float* __restrict__ asrc,
                          const float* __restrict__ adst, float* __restrict__ es,
                          float* __restrict__ ed, int n, int heads) {
    int id = blockIdx.x * TPB + threadIdx.x;
    if (id >= n * heads) return;
    int j = id / heads, h = id - j * heads;
    const float* hp = hf + (size_t)j * heads * 128 + h * 128;
    float a = 0.f, d = 0.f;
    for (int c = 0; c < 128; ++c) {
        float v = hp[c];
        a += v * asrc[h * 128 + c];
        d += v * adst[h * 128 + c];
    }
    es[id] = a;
    ed[id] = d;
}

__global__ void extract_nbr(const ushort* __restrict__ A0b, int n,
                            int* __restrict__ nbr, int* __restrict__ ncnt) {
    int i = blockIdx.x, tid = threadIdx.x;
    __shared__ int cnt;
    if (tid == 0) cnt = 0;
    __syncthreads();
    const ushort* row = A0b + (size_t)i * n;
    for (int j = tid; j < n; j += TPB) {
        if (row[j] != 0 || j == i) {
            int p = atomicAdd(&cnt, 1);
            if (p < MAXN) nbr[i * MAXN + p] = j;
        }
    }
    __syncthreads();
    if (tid == 0) ncnt[i] = min(cnt, MAXN);
}

__global__ void gat_sparse(const int* __restrict__ nbr, const int* __restrict__ ncnt, int n,
                           const float* __restrict__ hf, const float* __restrict__ es,
                           const float* __restrict__ ed, const float* __restrict__ bias,
                           const float* __restrict__ resid, float* __restrict__ out,
                           int heads, int mode) {
    int i = blockIdx.x;
    int tid = threadIdx.x;
    __shared__ int idx[MAXN];
    __shared__ float lg[MAXN * 4];
    __shared__ float hmax[4], hsum[4];
    int m = ncnt[i];
    for (int t = tid; t < m; t += TPB) idx[t] = nbr[i * MAXN + t];
    __syncthreads();
    for (int t = tid; t < m * heads; t += TPB) {
        int jl = t / heads, h = t - jl * heads;
        float l = ed[i * heads + h] + es[idx[jl] * heads + h];
        lg[jl * heads + h] = (l > 0.f) ? l : 0.2f * l;
    }
    __syncthreads();
    int h = tid >> 6, lane = tid & 63;
    if (h < heads) {
        float mx = -3.4e38f;
        for (int jl = lane; jl < m; jl += 64) mx = fmaxf(mx, lg[jl * heads + h]);
        for (int o = 32; o; o >>= 1) mx = fmaxf(mx, __shfl_xor(mx, o));
        if (lane == 0) hmax[h] = mx;
    }
    __syncthreads();
    if (h < heads) {
        float mx = hmax[h];
        float sm = 0.f;
        for (int jl = lane; jl < m; jl += 64) {
            float p = expf(lg[jl * heads + h] - mx);
            lg[jl * heads + h] = p;
            sm += p;
        }
        for (int o = 32; o; o >>= 1) sm += __shfl_xor(sm, o);
        if (lane == 0) hsum[h] = sm;
    }
    __syncthreads();
    int width = heads * 128;
    for (int o = tid; o < width; o += TPB) {
        int hh = o >> 7;
        float acc = 0.f;
        for (int jl = 0; jl < m; ++jl)
            acc += lg[jl * heads + hh] * hf[(size_t)idx[jl] * width + o];
        float v = acc / hsum[hh] + bias[o];
        if (mode == 0) v = (v > 0.f) ? v : expm1f(v);
        else v += resid[(size_t)i * width + o];
        out[(size_t)i * width + o] = v;
    }
}

// ---------------------------------------------------------------------------
static inline int cdiv(int a, int b) { return (a + b - 1) / b; }

static int pick_z(int gx, int gy, int K) {
    int z = 1;
    while (gx * gy * z < 384 && K / (2 * z) >= 64) z <<= 1;
    return z;
}

static void run_gcn(hipStream_t stream, int amode, const ushort* Ahi, const ushort* Alo,
                    int n, const float* xin, int fin,
                    const float* W, const float* bias, int f,
                    const float* dinv, const float* selfw,
                    float* xw, ushort* yThi, ushort* yTlo, float* Cp,
                    float* out, int relu) {
    gemm_bias<<<dim3(cdiv(f, 64), cdiv(n, 64)), TPB, 0, stream>>>(xin, W, nullptr, xw, n, fin, f);
    build_yT<<<dim3(n / 64, f / 64), TPB, 0, stream>>>(xw, dinv, yThi, yTlo, n, f);
    hipMemsetAsync(Cp, 0, (size_t)n * f * sizeof(float), stream);
    int z = pick_z(f / 64, n / 64, n);
    gcn_gemm<<<dim3(f / 64, n / 64, z), TPB, 0, stream>>>(Ahi, Alo, yThi, yTlo, Cp, n, f, n / z, amode);
    gcn_epilogue<<<cdiv(n * f, TPB), TPB, 0, stream>>>(Cp, xw, dinv, selfw, bias, out, n, f, relu);
}

static void run_topk(hipStream_t stream, const float* score, int n, int k, int* rank,
                     int* perm, float* vals) {
    hipMemsetAsync(rank, 0, n * sizeof(int), stream);
    rank_count<<<dim3(n / 256, n / 256), 256, 0, stream>>>(score, n, rank);
    scatter_topk<<<cdiv(n, TPB), TPB, 0, stream>>>(score, rank, n, k, perm, vals);
}

extern "C" void kernel_launch(void* const* d_in, const int* in_sizes, int n_in,
                              void* d_out, int out_size, void* d_ws, size_t ws_size,
                              hipStream_t stream) {
    const float* x   = (const float*)d_in[0];
    const int*   ei  = (const int*)d_in[1];
    const float* w0  = (const float*)d_in[2];  const float* b0  = (const float*)d_in[3];
    const float* w1  = (const float*)d_in[4];  const float* b1  = (const float*)d_in[5];
    const float* w2  = (const float*)d_in[6];  const float* b2  = (const float*)d_in[7];
    const float* w3  = (const float*)d_in[8];  const float* b3  = (const float*)d_in[9];
    const float* p1  = (const float*)d_in[10];
    const float* p2  = (const float*)d_in[11];
    const float* p3  = (const float*)d_in[12];
    const float* uw0 = (const float*)d_in[13]; const float* ub0 = (const float*)d_in[14];
    const float* uw1 = (const float*)d_in[15]; const float* ub1 = (const float*)d_in[16];
    const float* uw2 = (const float*)d_in[17]; const float* ub2 = (const float*)d_in[18];
    const float* lng = (const float*)d_in[19]; const float* lnb = (const float*)d_in[20];
    const float* rw  = (const float*)d_in[21]; const float* rb  = (const float*)d_in[22];
    const float* g1w = (const float*)d_in[23];
    const float* g1as = (const float*)d_in[24]; const float* g1ad = (const float*)d_in[25];
    const float* g1b = (const float*)d_in[26];
    const float* g2w = (const float*)d_in[27];
    const float* g2as = (const float*)d_in[28]; const float* g2ad = (const float*)d_in[29];
    const float* g2b = (const float*)d_in[30];

    const int N = 4096, E = 65536;
    const int K1 = 2048, K2 = 1024, K3 = 512;

    float* base = (float*)d_ws;
    size_t off = 0;
    auto alloc = [&](size_t nf) { float* p = base + off; off += (nf + 63) & ~(size_t)63; return p; };

    ushort* A0b  = (ushort*)alloc((size_t)N * N / 2);
    ushort* A1hi = (ushort*)alloc((size_t)K1 * K1 / 2);
    ushort* A1lo = (ushort*)alloc((size_t)K1 * K1 / 2);
    ushort* A2hi = (ushort*)alloc((size_t)K2 * K2 / 2);
    ushort* A2lo = (ushort*)alloc((size_t)K2 * K2 / 2);
    ushort* A3hi = (ushort*)alloc((size_t)K3 * K3 / 2);
    ushort* A3lo = (ushort*)alloc((size_t)K3 * K3 / 2);
    ushort* Tbf  = (ushort*)alloc((size_t)N * N / 2);
    ushort* Agb  = (ushort*)alloc((size_t)K1 * N / 2);
    ushort* Bgb  = (ushort*)alloc((size_t)K1 * N / 2);
    ushort* yThi = (ushort*)alloc((size_t)128 * N / 2);
    ushort* yTlo = (ushort*)alloc((size_t)128 * N / 2);
    ushort* Whi  = (ushort*)alloc((size_t)512 * 128 / 2);
    ushort* Wlo  = (ushort*)alloc((size_t)512 * 128 / 2);
    float* Cp    = alloc((size_t)N * 128);
    float* x0    = alloc((size_t)N * 64);
    float* x1    = alloc((size_t)K1 * 64);
    float* x2    = alloc((size_t)K2 * 64);
    float* x3    = alloc((size_t)K3 * 64);
    float* h1    = alloc((size_t)K1 * 64);
    float* h2    = alloc((size_t)K2 * 64);
    float* h3    = alloc((size_t)K3 * 64);
    float* xw    = alloc((size_t)N * 128);
    float* dinv0 = alloc(N);  float* selfw0 = alloc(N);
    float* dinv1 = alloc(K1); float* selfw1 = alloc(K1);
    float* dinv2 = alloc(K2); float* selfw2 = alloc(K2);
    float* dinv3 = alloc(K3); float* selfw3 = alloc(K3);
    int*   deg   = (int*)alloc(N);
    int*   diag  = (int*)alloc(N);
    float* score = alloc(N);
    int*   rank  = (int*)alloc(N);
    float* vals1 = alloc(K1); float* vals2 = alloc(K2); float* vals3 = alloc(K3);
    int*   perm1 = (int*)alloc(K1); int* perm2 = (int*)alloc(K2); int* perm3 = (int*)alloc(K3);
    int*   nbr   = (int*)alloc((size_t)N * MAXN);
    int*   ncnt  = (int*)alloc(N);
    float* t2    = alloc((size_t)K2 * 64);
    float* t1    = alloc((size_t)K1 * 64);
    float* t0    = alloc((size_t)N * 64);
    float* hfin  = alloc((size_t)N * 128);
    float* u     = alloc((size_t)N * 128);
    float* resid = alloc((size_t)N * 128);
    float* hf1   = alloc((size_t)N * 512);
    float* es1   = alloc((size_t)N * 4); float* ed1 = alloc((size_t)N * 4);
    float* g1    = alloc((size_t)N * 512);
    float* hf2   = alloc((size_t)N * 128);
    float* es2   = alloc(N); float* ed2 = alloc(N);
    float* pn    = alloc(64);
    (void)ws_size; (void)n_in; (void)in_sizes; (void)out_size;

    // ---- A0 build (bf16 direct) + degrees + neighbor list ----
    hipMemsetAsync(A0b, 0, (size_t)N * N * sizeof(ushort), stream);
    hipMemsetAsync(deg, 0, N * sizeof(int), stream);
    hipMemsetAsync(diag, 0, N * sizeof(int), stream);
    scatter_edges_b<<<cdiv(E, TPB), TPB, 0, stream>>>(ei, E, A0b, N, deg, diag);
    dinv_from_deg<<<cdiv(N, TPB), TPB, 0, stream>>>(deg, diag, N, dinv0, selfw0);
    extract_nbr<<<N, TPB, 0, stream>>>(A0b, N, nbr, ncnt);

    // ---- down level 0 ----
    run_gcn(stream, 0, A0b, nullptr, N, x, 3, w0, b0, 64,
            dinv0, selfw0, xw, yThi, yTlo, Cp, x0, 1);

    // ---- level 1 ----
    vec_norm<<<1, 64, 0, stream>>>(p1, 64, pn);
    score_kernel<<<cdiv(N, TPB), TPB, 0, stream>>>(x0, p1, pn, score, N, 64);
    run_topk(stream, score, N, K1, rank, perm1, vals1);
    transpose_aug_b<<<dim3(N / 64, N / 64), TPB, 0, stream>>>(A0b, Tbf, N);
    gather_rows_aug_b<<<cdiv(K1 * N, TPB), TPB, 0, stream>>>(A0b, perm1, Agb, N, K1);
    gather_rows_u16<<<cdiv(K1 * N, TPB), TPB, 0, stream>>>(Tbf, perm1, Bgb, N, K1);
    aug_gemm128<<<dim3(K1 / 128, K1 / 128), TPB, 0, stream>>>(Agb, Bgb, A1hi, A1lo, N, K1);
    rowsum_dinv_hl<<<K1, TPB, 0, stream>>>(A1hi, A1lo, K1, dinv1, selfw1);
    gather_feat<<<cdiv(K1 * 64, TPB), TPB, 0, stream>>>(x0, perm1, vals1, K1, 64, h1);
    run_gcn(stream, 1, A1hi, A1lo, K1, h1, 64, w1, b1, 64,
            dinv1, selfw1, xw, yThi, yTlo, Cp, x1, 1);

    // ---- level 2 ----
    vec_norm<<<1, 64, 0, stream>>>(p2, 64, pn);
    score_kernel<<<cdiv(K1, TPB), TPB, 0, stream>>>(x1, p2, pn, score, K1, 64);
    run_topk(stream, score, K1, K2, rank, perm2, vals2);
    transpose_aug_hl<<<dim3(K1 / 64, K1 / 64), TPB, 0, stream>>>(A1hi, A1lo, Tbf, K1);
    gather_rows_aug_hl<<<cdiv(K2 * K1, TPB), TPB, 0, stream>>>(A1hi, A1lo, perm2, Agb, K1, K2);
    gather_rows_u16<<<cdiv(K2 * K1, TPB), TPB, 0, stream>>>(Tbf, perm2, Bgb, K1, K2);
    augment_gemm_hl<<<dim3(K2 / 64, K2 / 64), TPB, 0, stream>>>(Agb, Bgb, A2hi, A2lo, K1, K2);
    rowsum_dinv_hl<<<K2, TPB, 0, stream>>>(A2hi, A2lo, K2, dinv2, selfw2);
    gather_feat<<<cdiv(K2 * 64, TPB), TPB, 0, stream>>>(x1, perm2, vals2, K2, 64, h2);
    run_gcn(stream, 1, A2hi, A2lo, K2, h2, 64, w2, b2, 64,
            dinv2, selfw2, xw, yThi, yTlo, Cp, x2, 1);

    // ---- level 3 ----
    vec_norm<<<1, 64, 0, stream>>>(p3, 64, pn);
    score_kernel<<<cdiv(K2, TPB), TPB, 0, stream>>>(x2, p3, pn, score, K2, 64);
    run_topk(stream, score, K2, K3, rank, perm3, vals3);
    transpose_aug_hl<<<dim3(K2 / 64, K2 / 64), TPB, 0, stream>>>(A2hi, A2lo, Tbf, K2);
    gather_rows_aug_hl<<<cdiv(K3 * K2, TPB), TPB, 0, stream>>>(A2hi, A2lo, perm3, Agb, K2, K3);
    gather_rows_u16<<<cdiv(K3 * K2, TPB), TPB, 0, stream>>>(Tbf, perm3, Bgb, K2, K3);
    augment_gemm_hl<<<dim3(K3 / 64, K3 / 64), TPB, 0, stream>>>(Agb, Bgb, A3hi, A3lo, K2, K3);
    rowsum_dinv_hl<<<K3, TPB, 0, stream>>>(A3hi, A3lo, K3, dinv3, selfw3);
    gather_feat<<<cdiv(K3 * 64, TPB), TPB, 0, stream>>>(x2, perm3, vals3, K3, 64, h3);
    run_gcn(stream, 1, A3hi, A3lo, K3, h3, 64, w3, b3, 64,
            dinv3, selfw3, xw, yThi, yTlo, Cp, x3, 1);

    // ---- up path ----
    copy_k<<<cdiv(K2 * 64, TPB), TPB, 0, stream>>>(x2, t2, K2 * 64);
    scatter_add_rows<<<cdiv(K3 * 64, TPB), TPB, 0, stream>>>(x3, perm3, K3, 64, t2);
    run_gcn(stream, 1, A2hi, A2lo, K2, t2, 64, uw0, ub0, 64,
            dinv2, selfw2, xw, yThi, yTlo, Cp, h2, 1);

    copy_k<<<cdiv(K1 * 64, TPB), TPB, 0, stream>>>(x1, t1, K1 * 64);
    scatter_add_rows<<<cdiv(K2 * 64, TPB), TPB, 0, stream>>>(h2, perm2, K2, 64, t1);
    run_gcn(stream, 1, A1hi, A1lo, K1, t1, 64, uw1, ub1, 64,
            dinv1, selfw1, xw, yThi, yTlo, Cp, h1, 1);

    copy_k<<<cdiv(N * 64, TPB), TPB, 0, stream>>>(x0, t0, N * 64);
    scatter_add_rows<<<cdiv(K1 * 64, TPB), TPB, 0, stream>>>(h1, perm1, K1, 64, t0);
    run_gcn(stream, 0, A0b, nullptr, N, t0, 64, uw2, ub2, 128,
            dinv0, selfw0, xw, yThi, yTlo, Cp, hfin, 0);

    // ---- layernorm + residual ----
    layernorm<<<N, 128, 0, stream>>>(hfin, lng, lnb, u, N);
    transpose_split<<<dim3(2, 2), TPB, 0, stream>>>(rw, Whi, Wlo, 128, 128);
    gemm_bt_split<<<dim3(2, N / 64), TPB, 0, stream>>>(u, Whi, Wlo, rb, resid, 128, 128);

    // ---- GAT layer 1 (4 heads, concat, ELU) ----
    transpose_split<<<dim3(8, 2), TPB, 0, stream>>>(g1w, Whi, Wlo, 128, 512);
    gemm_bt_split<<<dim3(8, N / 64), TPB, 0, stream>>>(u, Whi, Wlo, nullptr, hf1, 128, 512);
    attn_coef<<<cdiv(N * 4, TPB), TPB, 0, stream>>>(hf1, g1as, g1ad, es1, ed1, N, 4);
    gat_sparse<<<N, TPB, 0, stream>>>(nbr, ncnt, N, hf1, es1, ed1, g1b, nullptr, g1, 4, 0);

    // ---- GAT layer 2 (1 head) + residual ----
    transpose_split<<<dim3(2, 8), TPB, 0, stream>>>(g2w, Whi, Wlo, 512, 128);
    gemm_bt_split<<<dim3(2, N / 64), TPB, 0, stream>>>(g1, Whi, Wlo, nullptr, hf2, 512, 128);
    attn_coef<<<cdiv(N, TPB), TPB, 0, stream>>>(hf2, g2as, g2ad, es2, ed2, N, 1);
    gat_sparse<<<N, TPB, 0, stream>>>(nbr, ncnt, N, hf2, es2, ed2, g2b, resid, (float*)d_out, 1, 1);
}

// Round 6
// 634.485 us; speedup vs baseline: 7.7915x; 1.2161x over previous
//
#include <hip/hip_runtime.h>
#include <math.h>

// ---------------------------------------------------------------------------
// GraphUNet + GAT pipeline. N=4096, E=65536, IN=3, H=64, OUT=128, HEADS=4
// Round 6: level-1 augment via sparse SpGEMM (Ahat ~17 nnz/row, exact int
// accumulation in LDS); level-0 GCN aggregation via fused sparse SpMV.
// Dense MFMA retained for levels >=1 (A1.. are dense-ish).
// ---------------------------------------------------------------------------

#define TPB 256
#define LDK 88
#define MAXN 128

typedef __attribute__((ext_vector_type(8))) short bf16x8;
typedef __attribute__((ext_vector_type(4))) float f32x4;

__device__ inline ushort f32_to_bf16(float v) {
    unsigned b = __float_as_uint(v);
    return (ushort)((b + 0x7FFF + ((b >> 16) & 1)) >> 16);
}
__device__ inline float bf2f(ushort u) { return __uint_as_float(((unsigned)u) << 16); }

// ---------------- adjacency build ----------------
__global__ void scatter_edges_b(const int* __restrict__ ei, int E, ushort* __restrict__ A,
                                int n, int* __restrict__ deg, int* __restrict__ diag) {
    int e = blockIdx.x * TPB + threadIdx.x;
    if (e >= E) return;
    int src = ei[e];
    int dst = ei[E + e];
    atomicAdd(&deg[dst], 1);
    if (src == dst) diag[src] = 1;
    size_t idx = (size_t)dst * n + src;
    uint* word = (uint*)(A + (idx & ~(size_t)1));
    bool hi = (idx & 1);
    uint old = *word, assumed;
    do {
        assumed = old;
        ushort cur = hi ? (ushort)(assumed >> 16) : (ushort)(assumed & 0xffff);
        ushort nv = f32_to_bf16(bf2f(cur) + 1.0f);
        uint neww = hi ? ((assumed & 0x0000ffffu) | ((uint)nv << 16))
                       : ((assumed & 0xffff0000u) | nv);
        old = atomicCAS(word, assumed, neww);
    } while (old != assumed);
}

__global__ void dinv_from_deg(const int* __restrict__ deg, const int* __restrict__ diag,
                              int n, float* __restrict__ dinv, float* __restrict__ selfw) {
    int i = blockIdx.x * TPB + threadIdx.x;
    if (i >= n) return;
    float sw = diag[i] ? 0.f : 2.f;
    dinv[i] = 1.0f / sqrtf((float)deg[i] + sw);
    selfw[i] = sw;
}

// CSR of Ahat=(A+I): per row i, entries j with A[i][j]!=0 or j==i;
// weight = A[i][j] + (j==i). Same index set serves the GAT mask.
__global__ void extract_csr(const ushort* __restrict__ A0b, int n,
                            int* __restrict__ nbr, float* __restrict__ awt,
                            int* __restrict__ acnt) {
    int i = blockIdx.x, tid = threadIdx.x;
    __shared__ int cnt;
    if (tid == 0) cnt = 0;
    __syncthreads();
    const ushort* row = A0b + (size_t)i * n;
    for (int j = tid; j < n; j += TPB) {
        ushort w = row[j];
        if (w != 0 || j == i) {
            int p = atomicAdd(&cnt, 1);
            if (p < MAXN) {
                nbr[i * MAXN + p] = j;
                awt[i * MAXN + p] = bf2f(w) + (j == i ? 1.0f : 0.0f);
            }
        }
    }
    __syncthreads();
    if (tid == 0) acnt[i] = min(cnt, MAXN);
}

// ---------------- generic fp32 GEMM (xw projections) ----------------
__global__ void gemm_bias(const float* __restrict__ A, const float* __restrict__ B,
                          const float* __restrict__ bias, float* __restrict__ C,
                          int M, int K, int N) {
    __shared__ float As[16][65];
    __shared__ float Bs[16][65];
    int tx = threadIdx.x & 15, ty = threadIdx.x >> 4;
    int i0 = blockIdx.y * 64, j0 = blockIdx.x * 64;
    float acc[4][4] = {};
    for (int k0 = 0; k0 < K; k0 += 16) {
        for (int t = threadIdx.x; t < 1024; t += TPB) {
            int r = t >> 4, c = t & 15;
            int gi = i0 + r, gk = k0 + c;
            As[c][r] = (gi < M && gk < K) ? A[(size_t)gi * K + gk] : 0.f;
        }
        for (int t = threadIdx.x; t < 1024; t += TPB) {
            int r = t >> 6, c = t & 63;
            int gk = k0 + r, gj = j0 + c;
            Bs[r][c] = (gk < K && gj < N) ? B[(size_t)gk * N + gj] : 0.f;
        }
        __syncthreads();
        for (int kk = 0; kk < 16; ++kk) {
            float a[4], b[4];
#pragma unroll
            for (int u = 0; u < 4; ++u) a[u] = As[kk][ty * 4 + u];
#pragma unroll
            for (int v = 0; v < 4; ++v) b[v] = Bs[kk][tx * 4 + v];
#pragma unroll
            for (int u = 0; u < 4; ++u)
#pragma unroll
                for (int v = 0; v < 4; ++v) acc[u][v] += a[u] * b[v];
        }
        __syncthreads();
    }
    for (int u = 0; u < 4; ++u)
        for (int v = 0; v < 4; ++v) {
            int gi = i0 + ty * 4 + u, gj = j0 + tx * 4 + v;
            if (gi < M && gj < N) {
                float val = acc[u][v];
                if (bias) val += bias[gj];
                C[(size_t)gi * N + gj] = val;
            }
        }
}

// ---------------- level-0 GCN: fused sparse SpMV ----------------
// out[i,c] = dinv_i*( sum_a w_a*y[j_a,c] - y[i,c] + selfw_i*y[i,c] ) + b[c]
// where y[j,c] = xw[j,c]*dinv[j]; CSR holds w = A[i][j] + (j==i).
__global__ void spmv_gcn(const int* __restrict__ nbr, const float* __restrict__ awt,
                         const int* __restrict__ acnt, const float* __restrict__ xw,
                         const float* __restrict__ dinv, const float* __restrict__ selfw,
                         const float* __restrict__ bias, float* __restrict__ out,
                         int f, int relu) {
    int i = blockIdx.x;
    int o = threadIdx.x;
    __shared__ int sj[MAXN];
    __shared__ float sw_[MAXN];
    int cnt = acnt[i];
    for (int a = o; a < cnt; a += blockDim.x) {
        sj[a] = nbr[i * MAXN + a];
        sw_[a] = awt[i * MAXN + a];
    }
    __syncthreads();
    if (o >= f) return;
    float sum = 0.f;
    for (int a = 0; a < cnt; ++a) {
        int j = sj[a];
        sum += sw_[a] * (xw[(size_t)j * f + o] * dinv[j]);
    }
    float yi = xw[(size_t)i * f + o] * dinv[i];
    sum -= yi;                         // remove the +I part of the CSR weight
    float v = dinv[i] * (sum + selfw[i] * yi) + bias[o];
    if (relu) v = fmaxf(v, 0.f);
    out[(size_t)i * f + o] = v;
}

// ---------------- level-1 augment: sparse SpGEMM ----------------
// invperm scatter
__global__ void scatter_invperm(const int* __restrict__ perm, int k, int* __restrict__ invp) {
    int r = blockIdx.x * TPB + threadIdx.x;
    if (r < k) invp[perm[r]] = r;
}

// Row r of A1: A1[r][j] = sum_t Ahat[pi][t] * Ahat[t][s], j=invp[s]; diag 0.
// Exact integer accumulation in LDS fp32; writes split hi/lo + dinv/selfw.
__global__ void spgemm_aug(const int* __restrict__ nbr, const float* __restrict__ awt,
                           const int* __restrict__ acnt, const int* __restrict__ perm,
                           const int* __restrict__ invp, int k,
                           ushort* __restrict__ Chi, ushort* __restrict__ Clo,
                           float* __restrict__ dinv, float* __restrict__ selfw) {
    __shared__ float row[2048];
    int r = blockIdx.x, tid = threadIdx.x;
    int pi = perm[r];
    for (int j = tid; j < k; j += TPB) row[j] = 0.f;
    __syncthreads();
    int cnt = acnt[pi];
    for (int a = 0; a < cnt; ++a) {
        int t = nbr[pi * MAXN + a];
        float w1 = awt[pi * MAXN + a];
        int c2 = acnt[t];
        for (int b = tid; b < c2; b += TPB) {
            int s = nbr[t * MAXN + b];
            int j = invp[s];
            if (j >= 0) atomicAdd(&row[j], w1 * awt[t * MAXN + b]);
        }
    }
    __syncthreads();
    // zero diag, write split hi/lo, reduce row sum
    float psum = 0.f;
    for (int j = tid; j < k; j += TPB) {
        float v = (j == r) ? 0.f : row[j];
        psum += v;
        ushort hi = f32_to_bf16(v);
        size_t o = (size_t)r * k + j;
        Chi[o] = hi;
        Clo[o] = f32_to_bf16(v - bf2f(hi));
    }
    for (int o = 32; o; o >>= 1) psum += __shfl_xor(psum, o);
    __shared__ float sh[4];
    if ((tid & 63) == 0) sh[tid >> 6] = psum;
    __syncthreads();
    if (tid == 0) {
        float tot = sh[0] + sh[1] + sh[2] + sh[3];
        dinv[r] = 1.0f / sqrtf(tot + 2.0f);   // diag is always 0 -> selfw=2
        selfw[r] = 2.0f;
    }
}

// ---------------- dense augment (levels 2,3) ----------------
__global__ void transpose_aug_hl(const ushort* __restrict__ Ahi, const ushort* __restrict__ Alo,
                                 ushort* __restrict__ T, int n) {
    __shared__ float tile[64][65];
    int c0 = blockIdx.x * 64, r0 = blockIdx.y * 64;
    for (int t = threadIdx.x; t < 4096; t += TPB) {
        int r = t >> 6, c = t & 63;
        size_t o = (size_t)(r0 + r) * n + (c0 + c);
        float v = bf2f(Ahi[o]) + bf2f(Alo[o]);
        if (r0 + r == c0 + c) v += 1.0f;
        tile[c][r] = v;
    }
    __syncthreads();
    for (int t = threadIdx.x; t < 4096; t += TPB) {
        int c = t >> 6, r = t & 63;
        T[(size_t)(c0 + c) * n + (r0 + r)] = f32_to_bf16(tile[c][r]);
    }
}

__global__ void gather_rows_aug_hl(const ushort* __restrict__ Ahi, const ushort* __restrict__ Alo,
                                   const int* __restrict__ perm, ushort* __restrict__ Ag,
                                   int n, int rows) {
    int id = blockIdx.x * TPB + threadIdx.x;
    if (id >= rows * n) return;
    int r = id / n, t = id - r * n;
    int pr = perm[r];
    size_t o = (size_t)pr * n + t;
    float v = bf2f(Ahi[o]) + bf2f(Alo[o]);
    if (pr == t) v += 1.0f;
    Ag[id] = f32_to_bf16(v);
}

__global__ void gather_rows_u16(const ushort* __restrict__ T, const int* __restrict__ perm,
                                ushort* __restrict__ Bg, int n, int rows) {
    int id = blockIdx.x * TPB + threadIdx.x;
    if (id >= rows * n) return;
    int r = id / n, t = id - r * n;
    Bg[id] = T[(size_t)perm[r] * n + t];
}

__global__ void __launch_bounds__(256)
augment_gemm_hl(const ushort* __restrict__ Ag, const ushort* __restrict__ Bg,
                ushort* __restrict__ Chi, ushort* __restrict__ Clo, int K, int ldc) {
    __shared__ __align__(16) ushort As[64 * LDK];
    __shared__ __align__(16) ushort Bs[64 * LDK];
    int tid = threadIdx.x;
    int wave = tid >> 6, lane = tid & 63;
    int wr = wave >> 1, wc = wave & 1;
    int m = lane & 15, quad = lane >> 4;
    int i0 = blockIdx.y * 64, j0 = blockIdx.x * 64;
    f32x4 acc[2][2];
#pragma unroll
    for (int a = 0; a < 2; ++a)
#pragma unroll
        for (int b = 0; b < 2; ++b) acc[a][b] = (f32x4){0.f, 0.f, 0.f, 0.f};
    const ushort* Ab = Ag + (size_t)i0 * K;
    const ushort* Bb = Bg + (size_t)j0 * K;
    for (int k0 = 0; k0 < K; k0 += 64) {
#pragma unroll
        for (int v = 0; v < 2; ++v) {
            int idx = tid + (v << 8);
            int r = idx >> 3, c8 = idx & 7;
            *(uint4*)&As[r * LDK + c8 * 8] = *(const uint4*)&Ab[(size_t)r * K + k0 + c8 * 8];
            *(uint4*)&Bs[r * LDK + c8 * 8] = *(const uint4*)&Bb[(size_t)r * K + k0 + c8 * 8];
        }
        __syncthreads();
#pragma unroll
        for (int kk = 0; kk < 2; ++kk) {
            bf16x8 af[2], bfr[2];
#pragma unroll
            for (int mi = 0; mi < 2; ++mi)
                af[mi] = *(const bf16x8*)&As[(wr * 32 + mi * 16 + m) * LDK + kk * 32 + quad * 8];
#pragma unroll
            for (int ni = 0; ni < 2; ++ni)
                bfr[ni] = *(const bf16x8*)&Bs[(wc * 32 + ni * 16 + m) * LDK + kk * 32 + quad * 8];
#pragma unroll
            for (int mi = 0; mi < 2; ++mi)
#pragma unroll
                for (int ni = 0; ni < 2; ++ni)
                    acc[mi][ni] = __builtin_amdgcn_mfma_f32_16x16x32_bf16(
                        af[mi], bfr[ni], acc[mi][ni], 0, 0, 0);
        }
        __syncthreads();
    }
#pragma unroll
    for (int mi = 0; mi < 2; ++mi)
#pragma unroll
        for (int ni = 0; ni < 2; ++ni)
#pragma unroll
            for (int r = 0; r < 4; ++r) {
                int gi = i0 + wr * 32 + mi * 16 + quad * 4 + r;
                int gj = j0 + wc * 32 + ni * 16 + m;
                float val = (gi == gj) ? 0.f : acc[mi][ni][r];
                ushort hi = f32_to_bf16(val);
                size_t o = (size_t)gi * ldc + gj;
                Chi[o] = hi;
                Clo[o] = f32_to_bf16(val - bf2f(hi));
            }
}

// ---------------- dense GCN aggregation (levels >=1) ----------------
__global__ void __launch_bounds__(256)
gcn_gemm(const ushort* __restrict__ Ahi, const ushort* __restrict__ Alo,
         const ushort* __restrict__ Bhi, const ushort* __restrict__ Blo,
         float* __restrict__ C, int K, int ldc, int kpb) {
    __shared__ __align__(16) ushort sAh[64 * LDK];
    __shared__ __align__(16) ushort sAl[64 * LDK];
    __shared__ __align__(16) ushort sBh[64 * LDK];
    __shared__ __align__(16) ushort sBl[64 * LDK];
    int tid = threadIdx.x;
    int wave = tid >> 6, lane = tid & 63;
    int wr = wave >> 1, wc = wave & 1;
    int m = lane & 15, quad = lane >> 4;
    int i0 = blockIdx.y * 64, j0 = blockIdx.x * 64;
    int kbeg = blockIdx.z * kpb;
    f32x4 acc[2][2];
#pragma unroll
    for (int a = 0; a < 2; ++a)
#pragma unroll
        for (int b = 0; b < 2; ++b) acc[a][b] = (f32x4){0.f, 0.f, 0.f, 0.f};
    for (int k0 = kbeg; k0 < kbeg + kpb; k0 += 64) {
#pragma unroll
        for (int v = 0; v < 2; ++v) {
            int idx = tid + (v << 8);
            int r = idx >> 3, c8 = idx & 7;
            size_t boff = (size_t)(j0 + r) * K + k0 + c8 * 8;
            *(uint4*)&sBh[r * LDK + c8 * 8] = *(const uint4*)&Bhi[boff];
            *(uint4*)&sBl[r * LDK + c8 * 8] = *(const uint4*)&Blo[boff];
            size_t aoff = (size_t)(i0 + r) * K + k0 + c8 * 8;
            *(uint4*)&sAh[r * LDK + c8 * 8] = *(const uint4*)&Ahi[aoff];
            *(uint4*)&sAl[r * LDK + c8 * 8] = *(const uint4*)&Alo[aoff];
        }
        __syncthreads();
#pragma unroll
        for (int kk = 0; kk < 2; ++kk) {
            bf16x8 ah[2], al[2], bh[2], bl[2];
#pragma unroll
            for (int mi = 0; mi < 2; ++mi) {
                ah[mi] = *(const bf16x8*)&sAh[(wr * 32 + mi * 16 + m) * LDK + kk * 32 + quad * 8];
                al[mi] = *(const bf16x8*)&sAl[(wr * 32 + mi * 16 + m) * LDK + kk * 32 + quad * 8];
            }
#pragma unroll
            for (int ni = 0; ni < 2; ++ni) {
                bh[ni] = *(const bf16x8*)&sBh[(wc * 32 + ni * 16 + m) * LDK + kk * 32 + quad * 8];
                bl[ni] = *(const bf16x8*)&sBl[(wc * 32 + ni * 16 + m) * LDK + kk * 32 + quad * 8];
            }
#pragma unroll
            for (int mi = 0; mi < 2; ++mi)
#pragma unroll
                for (int ni = 0; ni < 2; ++ni) {
                    acc[mi][ni] = __builtin_amdgcn_mfma_f32_16x16x32_bf16(ah[mi], bh[ni], acc[mi][ni], 0, 0, 0);
                    acc[mi][ni] = __builtin_amdgcn_mfma_f32_16x16x32_bf16(ah[mi], bl[ni], acc[mi][ni], 0, 0, 0);
                    acc[mi][ni] = __builtin_amdgcn_mfma_f32_16x16x32_bf16(al[mi], bh[ni], acc[mi][ni], 0, 0, 0);
                }
        }
        __syncthreads();
    }
#pragma unroll
    for (int mi = 0; mi < 2; ++mi)
#pragma unroll
        for (int ni = 0; ni < 2; ++ni)
#pragma unroll
            for (int r = 0; r < 4; ++r) {
                int gi = i0 + wr * 32 + mi * 16 + quad * 4 + r;
                int gj = j0 + wc * 32 + ni * 16 + m;
                atomicAdd(&C[(size_t)gi * ldc + gj], acc[mi][ni][r]);
            }
}

__global__ void build_yT(const float* __restrict__ xw, const float* __restrict__ dinv,
                         ushort* __restrict__ Bhi, ushort* __restrict__ Blo, int n, int f) {
    __shared__ float t[64][65];
    int k0 = blockIdx.x * 64, c0 = blockIdx.y * 64;
#pragma unroll
    for (int v = 0; v < 16; ++v) {
        int idx = threadIdx.x + v * 256;
        int r = idx >> 6, c = idx & 63;
        t[r][c] = xw[(size_t)(k0 + r) * f + (c0 + c)] * dinv[k0 + r];
    }
    __syncthreads();
#pragma unroll
    for (int v = 0; v < 16; ++v) {
        int idx = threadIdx.x + v * 256;
        int c = idx >> 6, k = idx & 63;
        float val = t[k][c];
        ushort hi = f32_to_bf16(val);
        size_t o = (size_t)(c0 + c) * n + (k0 + k);
        Bhi[o] = hi;
        Blo[o] = f32_to_bf16(val - bf2f(hi));
    }
}

__global__ void gcn_epilogue(const float* __restrict__ C, const float* __restrict__ xw,
                             const float* __restrict__ dinv, const float* __restrict__ selfw,
                             const float* __restrict__ b, float* __restrict__ out,
                             int n, int f, int relu) {
    int id = blockIdx.x * TPB + threadIdx.x;
    if (id >= n * f) return;
    int i = id / f, c = id - i * f;
    float y = xw[id] * dinv[i];
    float v = dinv[i] * (C[id] + selfw[i] * y) + b[c];
    if (relu) v = fmaxf(v, 0.f);
    out[id] = v;
}

__global__ void rowsum_dinv_hl(const ushort* __restrict__ Ahi, const ushort* __restrict__ Alo,
                               int n, float* dinv, float* selfw) {
    int i = blockIdx.x;
    const ushort* rh = Ahi + (size_t)i * n;
    const ushort* rl = Alo + (size_t)i * n;
    float s = 0.f;
    for (int j = threadIdx.x; j < n; j += TPB) s += bf2f(rh[j]) + bf2f(rl[j]);
    for (int o = 32; o; o >>= 1) s += __shfl_xor(s, o);
    __shared__ float sh[4];
    if ((threadIdx.x & 63) == 0) sh[threadIdx.x >> 6] = s;
    __syncthreads();
    if (threadIdx.x == 0) {
        float tot = sh[0] + sh[1] + sh[2] + sh[3];
        float d = bf2f(rh[i]) + bf2f(rl[i]);
        float sw = (d == 0.f) ? 2.f : 0.f;
        dinv[i] = 1.0f / sqrtf(tot + sw);
        selfw[i] = sw;
    }
}

// ---------------- pooling ----------------
__global__ void vec_norm(const float* __restrict__ p, int f, float* out) {
    float s = 0.f;
    for (int c = threadIdx.x; c < f; c += 64) { float v = p[c]; s += v * v; }
    for (int o = 32; o; o >>= 1) s += __shfl_xor(s, o);
    if (threadIdx.x == 0) out[0] = sqrtf(s);
}

__global__ void score_kernel(const float* __restrict__ x, const float* __restrict__ p,
                             const float* __restrict__ nrm, float* __restrict__ s, int n, int f) {
    int i = blockIdx.x * TPB + threadIdx.x;
    if (i >= n) return;
    float a = 0.f;
    for (int c = 0; c < f; ++c) a += x[(size_t)i * f + c] * p[c];
    s[i] = tanhf(a / nrm[0]);
}

__global__ void rank_count(const float* __restrict__ s, int n, int* __restrict__ rank) {
    __shared__ float sj[256];
    int i = blockIdx.x * 256 + threadIdx.x;
    int j0 = blockIdx.y * 256;
    sj[threadIdx.x] = s[j0 + threadIdx.x];
    float si = s[i];
    __syncthreads();
    int r = 0;
#pragma unroll 8
    for (int jj = 0; jj < 256; ++jj) {
        float v = sj[jj];
        r += (v > si) || (v == si && (j0 + jj) < i);
    }
    atomicAdd(&rank[i], r);
}

__global__ void scatter_topk(const float* __restrict__ s, const int* __restrict__ rank,
                             int n, int k, int* __restrict__ perm, float* __restrict__ vals) {
    int i = blockIdx.x * TPB + threadIdx.x;
    if (i >= n) return;
    int r = rank[i];
    if (r < k) { perm[r] = i; vals[r] = s[i]; }
}

__global__ void gather_feat(const float* __restrict__ x, const int* __restrict__ perm,
                            const float* __restrict__ vals, int k, int f, float* __restrict__ h) {
    int id = blockIdx.x * TPB + threadIdx.x;
    if (id >= k * f) return;
    int r = id / f, c = id - r * f;
    h[id] = x[(size_t)perm[r] * f + c] * vals[r];
}

// ---------------- up path ----------------
__global__ void copy_k(const float* __restrict__ s, float* __restrict__ d, int n) {
    int id = blockIdx.x * TPB + threadIdx.x;
    if (id < n) d[id] = s[id];
}

__global__ void scatter_add_rows(const float* __restrict__ s, const int* __restrict__ perm,
                                 int k, int f, float* __restrict__ t) {
    int id = blockIdx.x * TPB + threadIdx.x;
    if (id >= k * f) return;
    int r = id / f, c = id - r * f;
    t[(size_t)perm[r] * f + c] += s[id];
}

// ---------------- layernorm ----------------
__global__ void layernorm(const float* __restrict__ h, const float* __restrict__ g,
                          const float* __restrict__ b, float* __restrict__ u, int n) {
    int i = blockIdx.x;
    int t = threadIdx.x;
    float v = h[(size_t)i * 128 + t];
    __shared__ float s0[2], s1[2];
    float sum = v;
    for (int o = 32; o; o >>= 1) sum += __shfl_xor(sum, o);
    if ((t & 63) == 0) s0[t >> 6] = sum;
    __syncthreads();
    float mu = (s0[0] + s0[1]) * (1.0f / 128.0f);
    float d = v - mu;
    float sq = d * d;
    for (int o = 32; o; o >>= 1) sq += __shfl_xor(sq, o);
    if ((t & 63) == 0) s1[t >> 6] = sq;
    __syncthreads();
    float var = (s1[0] + s1[1]) * (1.0f / 128.0f);
    u[(size_t)i * 128 + t] = d / sqrtf(var + 1e-6f) * g[t] + b[t];
}

// ---------------- dense projections via split-bf16 MFMA --------------------
__global__ void transpose_split(const float* __restrict__ W, ushort* __restrict__ Bhi,
                                ushort* __restrict__ Blo, int K, int N) {
    __shared__ float tile[64][65];
    int n0 = blockIdx.x * 64, k0 = blockIdx.y * 64;
    for (int t = threadIdx.x; t < 4096; t += TPB) {
        int r = t >> 6, c = t & 63;
        tile[r][c] = W[(size_t)(k0 + r) * N + (n0 + c)];
    }
    __syncthreads();
    for (int t = threadIdx.x; t < 4096; t += TPB) {
        int c = t >> 6, r = t & 63;
        float v = tile[r][c];
        ushort hi = f32_to_bf16(v);
        size_t o = (size_t)(n0 + c) * K + (k0 + r);
        Bhi[o] = hi;
        Blo[o] = f32_to_bf16(v - bf2f(hi));
    }
}

__global__ void __launch_bounds__(256)
gemm_bt_split(const float* __restrict__ A, const ushort* __restrict__ Bhi,
              const ushort* __restrict__ Blo, const float* __restrict__ bias,
              float* __restrict__ C, int K, int N) {
    __shared__ __align__(16) ushort sAh[64 * LDK];
    __shared__ __align__(16) ushort sAl[64 * LDK];
    __shared__ __align__(16) ushort sBh[64 * LDK];
    __shared__ __align__(16) ushort sBl[64 * LDK];
    int tid = threadIdx.x;
    int wave = tid >> 6, lane = tid & 63;
    int wr = wave >> 1, wc = wave & 1;
    int m = lane & 15, quad = lane >> 4;
    int i0 = blockIdx.y * 64, j0 = blockIdx.x * 64;
    f32x4 acc[2][2];
#pragma unroll
    for (int a = 0; a < 2; ++a)
#pragma unroll
        for (int b = 0; b < 2; ++b) acc[a][b] = (f32x4){0.f, 0.f, 0.f, 0.f};
    for (int k0 = 0; k0 < K; k0 += 64) {
#pragma unroll
        for (int v = 0; v < 2; ++v) {
            int idx = tid + (v << 8);
            int r = idx >> 3, c8 = idx & 7;
            size_t boff = (size_t)(j0 + r) * K + k0 + c8 * 8;
            *(uint4*)&sBh[r * LDK + c8 * 8] = *(const uint4*)&Bhi[boff];
            *(uint4*)&sBl[r * LDK + c8 * 8] = *(const uint4*)&Blo[boff];
            size_t aoff = (size_t)(i0 + r) * K + k0 + c8 * 8;
            float4 fa = *(const float4*)&A[aoff];
            float4 fb = *(const float4*)&A[aoff + 4];
            ushort h0 = f32_to_bf16(fa.x), h1 = f32_to_bf16(fa.y);
            ushort h2 = f32_to_bf16(fa.z), h3 = f32_to_bf16(fa.w);
            ushort h4 = f32_to_bf16(fb.x), h5 = f32_to_bf16(fb.y);
            ushort h6 = f32_to_bf16(fb.z), h7 = f32_to_bf16(fb.w);
            uint4 ph, pl;
            ph.x = (uint)h0 | ((uint)h1 << 16);
            ph.y = (uint)h2 | ((uint)h3 << 16);
            ph.z = (uint)h4 | ((uint)h5 << 16);
            ph.w = (uint)h6 | ((uint)h7 << 16);
            pl.x = (uint)f32_to_bf16(fa.x - bf2f(h0)) | ((uint)f32_to_bf16(fa.y - bf2f(h1)) << 16);
            pl.y = (uint)f32_to_bf16(fa.z - bf2f(h2)) | ((uint)f32_to_bf16(fa.w - bf2f(h3)) << 16);
            pl.z = (uint)f32_to_bf16(fb.x - bf2f(h4)) | ((uint)f32_to_bf16(fb.y - bf2f(h5)) << 16);
            pl.w = (uint)f32_to_bf16(fb.z - bf2f(h6)) | ((uint)f32_to_bf16(fb.w - bf2f(h7)) << 16);
            *(uint4*)&sAh[r * LDK + c8 * 8] = ph;
            *(uint4*)&sAl[r * LDK + c8 * 8] = pl;
        }
        __syncthreads();
#pragma unroll
        for (int kk = 0; kk < 2; ++kk) {
            bf16x8 ah[2], al[2], bh[2], bl[2];
#pragma unroll
            for (int mi = 0; mi < 2; ++mi) {
                ah[mi] = *(const bf16x8*)&sAh[(wr * 32 + mi * 16 + m) * LDK + kk * 32 + quad * 8];
                al[mi] = *(const bf16x8*)&sAl[(wr * 32 + mi * 16 + m) * LDK + kk * 32 + quad * 8];
            }
#pragma unroll
            for (int ni = 0; ni < 2; ++ni) {
                bh[ni] = *(const bf16x8*)&sBh[(wc * 32 + ni * 16 + m) * LDK + kk * 32 + quad * 8];
                bl[ni] = *(const bf16x8*)&sBl[(wc * 32 + ni * 16 + m) * LDK + kk * 32 + quad * 8];
            }
#pragma unroll
            for (int mi = 0; mi < 2; ++mi)
#pragma unroll
                for (int ni = 0; ni < 2; ++ni) {
                    acc[mi][ni] = __builtin_amdgcn_mfma_f32_16x16x32_bf16(ah[mi], bh[ni], acc[mi][ni], 0, 0, 0);
                    acc[mi][ni] = __builtin_amdgcn_mfma_f32_16x16x32_bf16(ah[mi], bl[ni], acc[mi][ni], 0, 0, 0);
                    acc[mi][ni] = __builtin_amdgcn_mfma_f32_16x16x32_bf16(al[mi], bh[ni], acc[mi][ni], 0, 0, 0);
                }
        }
        __syncthreads();
    }
#pragma unroll
    for (int mi = 0; mi < 2; ++mi)
#pragma unroll
        for (int ni = 0; ni < 2; ++ni)
#pragma unroll
            for (int r = 0; r < 4; ++r) {
                int gi = i0 + wr * 32 + mi * 16 + quad * 4 + r;
                int gj = j0 + wc * 32 + ni * 16 + m;
                float v = acc[mi][ni][r];
                if (bias) v += bias[gj];
                C[(size_t)gi * N + gj] = v;
            }
}

// ---------------- GAT (sparse neighbor list = CSR indices) ----------------
__global__ void attn_coef(const float* __restrict__ hf, const float* __restrict__ asrc,
                          const float* __restrict__ adst, float* __restrict__ es,
                          float* __restrict__ ed, int n, int heads) {
    int id = blockIdx.x * TPB + threadIdx.x;
    if (id >= n * heads) return;
    int j = id / heads, h = id - j * heads;
    const float* hp = hf + (size_t)j * heads * 128 + h * 128;
    float a = 0.f, d = 0.f;
    for (int c = 0; c < 128; ++c) {
        float v = hp[c];
        a += v * asrc[h * 128 + c];
        d += v * adst[h * 128 + c];
    }
    es[id] = a;
    ed[id] = d;
}

__global__ void gat_sparse(const int* __restrict__ nbr, const int* __restrict__ ncnt, int n,
                           const float* __restrict__ hf, const float* __restrict__ es,
                           const float* __restrict__ ed, const float* __restrict__ bias,
                           const float* __restrict__ resid, float* __restrict__ out,
                           int heads, int mode) {
    int i = blockIdx.x;
    int tid = threadIdx.x;
    __shared__ int idx[MAXN];
    __shared__ float lg[MAXN * 4];
    __shared__ float hmax[4], hsum[4];
    int m = ncnt[i];
    for (int t = tid; t < m; t += TPB) idx[t] = nbr[i * MAXN + t];
    __syncthreads();
    for (int t = tid; t < m * heads; t += TPB) {
        int jl = t / heads, h = t - jl * heads;
        float l = ed[i * heads + h] + es[idx[jl] * heads + h];
        lg[jl * heads + h] = (l > 0.f) ? l : 0.2f * l;
    }
    __syncthreads();
    int h = tid >> 6, lane = tid & 63;
    if (h < heads) {
        float mx = -3.4e38f;
        for (int jl = lane; jl < m; jl += 64) mx = fmaxf(mx, lg[jl * heads + h]);
        for (int o = 32; o; o >>= 1) mx = fmaxf(mx, __shfl_xor(mx, o));
        if (lane == 0) hmax[h] = mx;
    }
    __syncthreads();
    if (h < heads) {
        float mx = hmax[h];
        float sm = 0.f;
        for (int jl = lane; jl < m; jl += 64) {
            float p = expf(lg[jl * heads + h] - mx);
            lg[jl * heads + h] = p;
            sm += p;
        }
        for (int o = 32; o; o >>= 1) sm += __shfl_xor(sm, o);
        if (lane == 0) hsum[h] = sm;
    }
    __syncthreads();
    int width = heads * 128;
    for (int o = tid; o < width; o += TPB) {
        int hh = o >> 7;
        float acc = 0.f;
        for (int jl = 0; jl < m; ++jl)
            acc += lg[jl * heads + hh] * hf[(size_t)idx[jl] * width + o];
        float v = acc / hsum[hh] + bias[o];
        if (mode == 0) v = (v > 0.f) ? v : expm1f(v);
        else v += resid[(size_t)i * width + o];
        out[(size_t)i * width + o] = v;
    }
}

// ---------------------------------------------------------------------------
static inline int cdiv(int a, int b) { return (a + b - 1) / b; }

static int pick_z(int gx, int gy, int K) {
    int z = 1;
    while (gx * gy * z < 384 && K / (2 * z) >= 64) z <<= 1;
    return z;
}

// dense GCN for levels >= 1
static void run_gcn_dense(hipStream_t stream, const ushort* Ahi, const ushort* Alo,
                          int n, const float* xin, int fin,
                          const float* W, const float* bias, int f,
                          const float* dinv, const float* selfw,
                          float* xw, ushort* yThi, ushort* yTlo, float* Cp,
                          float* out, int relu) {
    gemm_bias<<<dim3(cdiv(f, 64), cdiv(n, 64)), TPB, 0, stream>>>(xin, W, nullptr, xw, n, fin, f);
    build_yT<<<dim3(n / 64, f / 64), TPB, 0, stream>>>(xw, dinv, yThi, yTlo, n, f);
    hipMemsetAsync(Cp, 0, (size_t)n * f * sizeof(float), stream);
    int z = pick_z(f / 64, n / 64, n);
    gcn_gemm<<<dim3(f / 64, n / 64, z), TPB, 0, stream>>>(Ahi, Alo, yThi, yTlo, Cp, n, f, n / z);
    gcn_epilogue<<<cdiv(n * f, TPB), TPB, 0, stream>>>(Cp, xw, dinv, selfw, bias, out, n, f, relu);
}

// sparse GCN for level 0
static void run_gcn_sparse(hipStream_t stream, const int* nbr, const float* awt,
                           const int* acnt, int n, const float* xin, int fin,
                           const float* W, const float* bias, int f,
                           const float* dinv, const float* selfw,
                           float* xw, float* out, int relu) {
    gemm_bias<<<dim3(cdiv(f, 64), cdiv(n, 64)), TPB, 0, stream>>>(xin, W, nullptr, xw, n, fin, f);
    spmv_gcn<<<n, f, 0, stream>>>(nbr, awt, acnt, xw, dinv, selfw, bias, out, f, relu);
}

static void run_topk(hipStream_t stream, const float* score, int n, int k, int* rank,
                     int* perm, float* vals) {
    hipMemsetAsync(rank, 0, n * sizeof(int), stream);
    rank_count<<<dim3(n / 256, n / 256), 256, 0, stream>>>(score, n, rank);
    scatter_topk<<<cdiv(n, TPB), TPB, 0, stream>>>(score, rank, n, k, perm, vals);
}

extern "C" void kernel_launch(void* const* d_in, const int* in_sizes, int n_in,
                              void* d_out, int out_size, void* d_ws, size_t ws_size,
                              hipStream_t stream) {
    const float* x   = (const float*)d_in[0];
    const int*   ei  = (const int*)d_in[1];
    const float* w0  = (const float*)d_in[2];  const float* b0  = (const float*)d_in[3];
    const float* w1  = (const float*)d_in[4];  const float* b1  = (const float*)d_in[5];
    const float* w2  = (const float*)d_in[6];  const float* b2  = (const float*)d_in[7];
    const float* w3  = (const float*)d_in[8];  const float* b3  = (const float*)d_in[9];
    const float* p1  = (const float*)d_in[10];
    const float* p2  = (const float*)d_in[11];
    const float* p3  = (const float*)d_in[12];
    const float* uw0 = (const float*)d_in[13]; const float* ub0 = (const float*)d_in[14];
    const float* uw1 = (const float*)d_in[15]; const float* ub1 = (const float*)d_in[16];
    const float* uw2 = (const float*)d_in[17]; const float* ub2 = (const float*)d_in[18];
    const float* lng = (const float*)d_in[19]; const float* lnb = (const float*)d_in[20];
    const float* rw  = (const float*)d_in[21]; const float* rb  = (const float*)d_in[22];
    const float* g1w = (const float*)d_in[23];
    const float* g1as = (const float*)d_in[24]; const float* g1ad = (const float*)d_in[25];
    const float* g1b = (const float*)d_in[26];
    const float* g2w = (const float*)d_in[27];
    const float* g2as = (const float*)d_in[28]; const float* g2ad = (const float*)d_in[29];
    const float* g2b = (const float*)d_in[30];

    const int N = 4096, E = 65536;
    const int K1 = 2048, K2 = 1024, K3 = 512;

    float* base = (float*)d_ws;
    size_t off = 0;
    auto alloc = [&](size_t nf) { float* p = base + off; off += (nf + 63) & ~(size_t)63; return p; };

    ushort* A0b  = (ushort*)alloc((size_t)N * N / 2);
    ushort* A1hi = (ushort*)alloc((size_t)K1 * K1 / 2);
    ushort* A1lo = (ushort*)alloc((size_t)K1 * K1 / 2);
    ushort* A2hi = (ushort*)alloc((size_t)K2 * K2 / 2);
    ushort* A2lo = (ushort*)alloc((size_t)K2 * K2 / 2);
    ushort* A3hi = (ushort*)alloc((size_t)K3 * K3 / 2);
    ushort* A3lo = (ushort*)alloc((size_t)K3 * K3 / 2);
    ushort* Tbf  = (ushort*)alloc((size_t)K1 * K1 / 2);
    ushort* Agb  = (ushort*)alloc((size_t)K2 * K1 / 2);
    ushort* Bgb  = (ushort*)alloc((size_t)K2 * K1 / 2);
    ushort* yThi = (ushort*)alloc((size_t)128 * N / 2);
    ushort* yTlo = (ushort*)alloc((size_t)128 * N / 2);
    ushort* Whi  = (ushort*)alloc((size_t)512 * 128 / 2);
    ushort* Wlo  = (ushort*)alloc((size_t)512 * 128 / 2);
    float* Cp    = alloc((size_t)N * 128);
    float* x0    = alloc((size_t)N * 64);
    float* x1    = alloc((size_t)K1 * 64);
    float* x2    = alloc((size_t)K2 * 64);
    float* x3    = alloc((size_t)K3 * 64);
    float* h1    = alloc((size_t)K1 * 64);
    float* h2    = alloc((size_t)K2 * 64);
    float* h3    = alloc((size_t)K3 * 64);
    float* xw    = alloc((size_t)N * 128);
    float* dinv0 = alloc(N);  float* selfw0 = alloc(N);
    float* dinv1 = alloc(K1); float* selfw1 = alloc(K1);
    float* dinv2 = alloc(K2); float* selfw2 = alloc(K2);
    float* dinv3 = alloc(K3); float* selfw3 = alloc(K3);
    int*   deg   = (int*)alloc(N);
    int*   diag  = (int*)alloc(N);
    float* score = alloc(N);
    int*   rank  = (int*)alloc(N);
    float* vals1 = alloc(K1); float* vals2 = alloc(K2); float* vals3 = alloc(K3);
    int*   perm1 = (int*)alloc(K1); int* perm2 = (int*)alloc(K2); int* perm3 = (int*)alloc(K3);
    int*   nbr   = (int*)alloc((size_t)N * MAXN);
    float* awt   = alloc((size_t)N * MAXN);
    int*   acnt  = (int*)alloc(N);
    int*   invp  = (int*)alloc(N);
    float* t2    = alloc((size_t)K2 * 64);
    float* t1    = alloc((size_t)K1 * 64);
    float* t0    = alloc((size_t)N * 64);
    float* hfin  = alloc((size_t)N * 128);
    float* u     = alloc((size_t)N * 128);
    float* resid = alloc((size_t)N * 128);
    float* hf1   = alloc((size_t)N * 512);
    float* es1   = alloc((size_t)N * 4); float* ed1 = alloc((size_t)N * 4);
    float* g1    = alloc((size_t)N * 512);
    float* hf2   = alloc((size_t)N * 128);
    float* es2   = alloc(N); float* ed2 = alloc(N);
    float* pn    = alloc(64);
    (void)ws_size; (void)n_in; (void)in_sizes; (void)out_size;

    // ---- A0 build (bf16 dense for CSR extraction) + degrees + CSR ----
    hipMemsetAsync(A0b, 0, (size_t)N * N * sizeof(ushort), stream);
    hipMemsetAsync(deg, 0, N * sizeof(int), stream);
    hipMemsetAsync(diag, 0, N * sizeof(int), stream);
    scatter_edges_b<<<cdiv(E, TPB), TPB, 0, stream>>>(ei, E, A0b, N, deg, diag);
    dinv_from_deg<<<cdiv(N, TPB), TPB, 0, stream>>>(deg, diag, N, dinv0, selfw0);
    extract_csr<<<N, TPB, 0, stream>>>(A0b, N, nbr, awt, acnt);

    // ---- down level 0 (sparse) ----
    run_gcn_sparse(stream, nbr, awt, acnt, N, x, 3, w0, b0, 64, dinv0, selfw0, xw, x0, 1);

    // ---- level 1: topk + sparse SpGEMM augment ----
    vec_norm<<<1, 64, 0, stream>>>(p1, 64, pn);
    score_kernel<<<cdiv(N, TPB), TPB, 0, stream>>>(x0, p1, pn, score, N, 64);
    run_topk(stream, score, N, K1, rank, perm1, vals1);
    hipMemsetAsync(invp, 0xFF, N * sizeof(int), stream);
    scatter_invperm<<<cdiv(K1, TPB), TPB, 0, stream>>>(perm1, K1, invp);
    spgemm_aug<<<K1, TPB, 0, stream>>>(nbr, awt, acnt, perm1, invp, K1,
                                       A1hi, A1lo, dinv1, selfw1);
    gather_feat<<<cdiv(K1 * 64, TPB), TPB, 0, stream>>>(x0, perm1, vals1, K1, 64, h1);
    run_gcn_dense(stream, A1hi, A1lo, K1, h1, 64, w1, b1, 64,
                  dinv1, selfw1, xw, yThi, yTlo, Cp, x1, 1);

    // ---- level 2 (dense augment) ----
    vec_norm<<<1, 64, 0, stream>>>(p2, 64, pn);
    score_kernel<<<cdiv(K1, TPB), TPB, 0, stream>>>(x1, p2, pn, score, K1, 64);
    run_topk(stream, score, K1, K2, rank, perm2, vals2);
    transpose_aug_hl<<<dim3(K1 / 64, K1 / 64), TPB, 0, stream>>>(A1hi, A1lo, Tbf, K1);
    gather_rows_aug_hl<<<cdiv(K2 * K1, TPB), TPB, 0, stream>>>(A1hi, A1lo, perm2, Agb, K1, K2);
    gather_rows_u16<<<cdiv(K2 * K1, TPB), TPB, 0, stream>>>(Tbf, perm2, Bgb, K1, K2);
    augment_gemm_hl<<<dim3(K2 / 64, K2 / 64), TPB, 0, stream>>>(Agb, Bgb, A2hi, A2lo, K1, K2);
    rowsum_dinv_hl<<<K2, TPB, 0, stream>>>(A2hi, A2lo, K2, dinv2, selfw2);
    gather_feat<<<cdiv(K2 * 64, TPB), TPB, 0, stream>>>(x1, perm2, vals2, K2, 64, h2);
    run_gcn_dense(stream, A2hi, A2lo, K2, h2, 64, w2, b2, 64,
                  dinv2, selfw2, xw, yThi, yTlo, Cp, x2, 1);

    // ---- level 3 (dense augment) ----
    vec_norm<<<1, 64, 0, stream>>>(p3, 64, pn);
    score_kernel<<<cdiv(K2, TPB), TPB, 0, stream>>>(x2, p3, pn, score, K2, 64);
    run_topk(stream, score, K2, K3, rank, perm3, vals3);
    transpose_aug_hl<<<dim3(K2 / 64, K2 / 64), TPB, 0, stream>>>(A2hi, A2lo, Tbf, K2);
    gather_rows_aug_hl<<<cdiv(K3 * K2, TPB), TPB, 0, stream>>>(A2hi, A2lo, perm3, Agb, K2, K3);
    gather_rows_u16<<<cdiv(K3 * K2, TPB), TPB, 0, stream>>>(Tbf, perm3, Bgb, K2, K3);
    augment_gemm_hl<<<dim3(K3 / 64, K3 / 64), TPB, 0, stream>>>(Agb, Bgb, A3hi, A3lo, K2, K3);
    rowsum_dinv_hl<<<K3, TPB, 0, stream>>>(A3hi, A3lo, K3, dinv3, selfw3);
    gather_feat<<<cdiv(K3 * 64, TPB), TPB, 0, stream>>>(x2, perm3, vals3, K3, 64, h3);
    run_gcn_dense(stream, A3hi, A3lo, K3, h3, 64, w3, b3, 64,
                  dinv3, selfw3, xw, yThi, yTlo, Cp, x3, 1);

    // ---- up path ----
    copy_k<<<cdiv(K2 * 64, TPB), TPB, 0, stream>>>(x2, t2, K2 * 64);
    scatter_add_rows<<<cdiv(K3 * 64, TPB), TPB, 0, stream>>>(x3, perm3, K3, 64, t2);
    run_gcn_dense(stream, A2hi, A2lo, K2, t2, 64, uw0, ub0, 64,
                  dinv2, selfw2, xw, yThi, yTlo, Cp, h2, 1);

    copy_k<<<cdiv(K1 * 64, TPB), TPB, 0, stream>>>(x1, t1, K1 * 64);
    scatter_add_rows<<<cdiv(K2 * 64, TPB), TPB, 0, stream>>>(h2, perm2, K2, 64, t1);
    run_gcn_dense(stream, A1hi, A1lo, K1, t1, 64, uw1, ub1, 64,
                  dinv1, selfw1, xw, yThi, yTlo, Cp, h1, 1);

    copy_k<<<cdiv(N * 64, TPB), TPB, 0, stream>>>(x0, t0, N * 64);
    scatter_add_rows<<<cdiv(K1 * 64, TPB), TPB, 0, stream>>>(h1, perm1, K1, 64, t0);
    run_gcn_sparse(stream, nbr, awt, acnt, N, t0, 64, uw2, ub2, 128,
                   dinv0, selfw0, xw, hfin, 0);

    // ---- layernorm + residual ----
    layernorm<<<N, 128, 0, stream>>>(hfin, lng, lnb, u, N);
    transpose_split<<<dim3(2, 2), TPB, 0, stream>>>(rw, Whi, Wlo, 128, 128);
    gemm_bt_split<<<dim3(2, N / 64), TPB, 0, stream>>>(u, Whi, Wlo, rb, resid, 128, 128);

    // ---- GAT layer 1 (4 heads, concat, ELU) ----
    transpose_split<<<dim3(8, 2), TPB, 0, stream>>>(g1w, Whi, Wlo, 128, 512);
    gemm_bt_split<<<dim3(8, N / 64), TPB, 0, stream>>>(u, Whi, Wlo, nullptr, hf1, 128, 512);
    attn_coef<<<cdiv(N * 4, TPB), TPB, 0, stream>>>(hf1, g1as, g1ad, es1, ed1, N, 4);
    gat_sparse<<<N, TPB, 0, stream>>>(nbr, acnt, N, hf1, es1, ed1, g1b, nullptr, g1, 4, 0);

    // ---- GAT layer 2 (1 head) + residual ----
    transpose_split<<<dim3(2, 8), TPB, 0, stream>>>(g2w, Whi, Wlo, 512, 128);
    gemm_bt_split<<<dim3(2, N / 64), TPB, 0, stream>>>(g1, Whi, Wlo, nullptr, hf2, 512, 128);
    attn_coef<<<cdiv(N, TPB), TPB, 0, stream>>>(hf2, g2as, g2ad, es2, ed2, N, 1);
    gat_sparse<<<N, TPB, 0, stream>>>(nbr, acnt, N, hf2, es2, ed2, g2b, resid, (float*)d_out, 1, 1);
}

// Round 7
// 560.914 us; speedup vs baseline: 8.8134x; 1.1312x over previous
//
#include <hip/hip_runtime.h>
#include <math.h>

// ---------------------------------------------------------------------------
// GraphUNet + GAT pipeline. N=4096, E=65536, IN=3, H=64, OUT=128, HEADS=4
// Round 7: kill latency-starved small grids — split-K augment (+fused
// finalize), LDS-W thread-per-output xw projections, split-K bt projections,
// block-per-node attn coefficients.
// ---------------------------------------------------------------------------

#define TPB 256
#define LDK 88
#define MAXN 128

typedef __attribute__((ext_vector_type(8))) short bf16x8;
typedef __attribute__((ext_vector_type(4))) float f32x4;

__device__ inline ushort f32_to_bf16(float v) {
    unsigned b = __float_as_uint(v);
    return (ushort)((b + 0x7FFF + ((b >> 16) & 1)) >> 16);
}
__device__ inline float bf2f(ushort u) { return __uint_as_float(((unsigned)u) << 16); }

// ---------------- adjacency build ----------------
__global__ void scatter_edges_b(const int* __restrict__ ei, int E, ushort* __restrict__ A,
                                int n, int* __restrict__ deg, int* __restrict__ diag) {
    int e = blockIdx.x * TPB + threadIdx.x;
    if (e >= E) return;
    int src = ei[e];
    int dst = ei[E + e];
    atomicAdd(&deg[dst], 1);
    if (src == dst) diag[src] = 1;
    size_t idx = (size_t)dst * n + src;
    uint* word = (uint*)(A + (idx & ~(size_t)1));
    bool hi = (idx & 1);
    uint old = *word, assumed;
    do {
        assumed = old;
        ushort cur = hi ? (ushort)(assumed >> 16) : (ushort)(assumed & 0xffff);
        ushort nv = f32_to_bf16(bf2f(cur) + 1.0f);
        uint neww = hi ? ((assumed & 0x0000ffffu) | ((uint)nv << 16))
                       : ((assumed & 0xffff0000u) | nv);
        old = atomicCAS(word, assumed, neww);
    } while (old != assumed);
}

__global__ void dinv_from_deg(const int* __restrict__ deg, const int* __restrict__ diag,
                              int n, float* __restrict__ dinv, float* __restrict__ selfw) {
    int i = blockIdx.x * TPB + threadIdx.x;
    if (i >= n) return;
    float sw = diag[i] ? 0.f : 2.f;
    dinv[i] = 1.0f / sqrtf((float)deg[i] + sw);
    selfw[i] = sw;
}

// CSR of Ahat=(A+I)
__global__ void extract_csr(const ushort* __restrict__ A0b, int n,
                            int* __restrict__ nbr, float* __restrict__ awt,
                            int* __restrict__ acnt) {
    int i = blockIdx.x, tid = threadIdx.x;
    __shared__ int cnt;
    if (tid == 0) cnt = 0;
    __syncthreads();
    const ushort* row = A0b + (size_t)i * n;
    for (int j = tid; j < n; j += TPB) {
        ushort w = row[j];
        if (w != 0 || j == i) {
            int p = atomicAdd(&cnt, 1);
            if (p < MAXN) {
                nbr[i * MAXN + p] = j;
                awt[i * MAXN + p] = bf2f(w) + (j == i ? 1.0f : 0.0f);
            }
        }
    }
    __syncthreads();
    if (tid == 0) acnt[i] = min(cnt, MAXN);
}

// ---------------- xw projection: C[n x f] = xin[n x fin] @ W[fin x f] ------
// W staged in LDS; thread-per-output; rpb = 256/f rows per block.
__global__ void xw_gemm(const float* __restrict__ xin, const float* __restrict__ W,
                        float* __restrict__ C, int n, int fin, int f) {
    __shared__ float sW[64 * 128];
    int tid = threadIdx.x;
    for (int t = tid; t < fin * f; t += TPB) sW[t] = W[t];
    __syncthreads();
    int rpb = TPB / f;
    int r = blockIdx.x * rpb + tid / f;
    int c = tid - (tid / f) * f;
    if (r >= n) return;
    const float* xr = xin + (size_t)r * fin;
    float acc = 0.f;
    for (int k = 0; k < fin; ++k) acc += xr[k] * sW[k * f + c];
    C[(size_t)r * f + c] = acc;
}

// ---------------- level-0 GCN: fused sparse SpMV ----------------
__global__ void spmv_gcn(const int* __restrict__ nbr, const float* __restrict__ awt,
                         const int* __restrict__ acnt, const float* __restrict__ xw,
                         const float* __restrict__ dinv, const float* __restrict__ selfw,
                         const float* __restrict__ bias, float* __restrict__ out,
                         int f, int relu) {
    int i = blockIdx.x;
    int o = threadIdx.x;
    __shared__ int sj[MAXN];
    __shared__ float sw_[MAXN];
    int cnt = acnt[i];
    for (int a = o; a < cnt; a += blockDim.x) {
        sj[a] = nbr[i * MAXN + a];
        sw_[a] = awt[i * MAXN + a];
    }
    __syncthreads();
    if (o >= f) return;
    float sum = 0.f;
    for (int a = 0; a < cnt; ++a) {
        int j = sj[a];
        sum += sw_[a] * (xw[(size_t)j * f + o] * dinv[j]);
    }
    float yi = xw[(size_t)i * f + o] * dinv[i];
    sum -= yi;
    float v = dinv[i] * (sum + selfw[i] * yi) + bias[o];
    if (relu) v = fmaxf(v, 0.f);
    out[(size_t)i * f + o] = v;
}

// ---------------- level-1 augment: sparse SpGEMM ----------------
__global__ void scatter_invperm(const int* __restrict__ perm, int k, int* __restrict__ invp) {
    int r = blockIdx.x * TPB + threadIdx.x;
    if (r < k) invp[perm[r]] = r;
}

__global__ void spgemm_aug(const int* __restrict__ nbr, const float* __restrict__ awt,
                           const int* __restrict__ acnt, const int* __restrict__ perm,
                           const int* __restrict__ invp, int k,
                           ushort* __restrict__ Chi, ushort* __restrict__ Clo,
                           float* __restrict__ dinv, float* __restrict__ selfw) {
    __shared__ float row[2048];
    int r = blockIdx.x, tid = threadIdx.x;
    int pi = perm[r];
    for (int j = tid; j < k; j += TPB) row[j] = 0.f;
    __syncthreads();
    int cnt = acnt[pi];
    for (int a = 0; a < cnt; ++a) {
        int t = nbr[pi * MAXN + a];
        float w1 = awt[pi * MAXN + a];
        int c2 = acnt[t];
        for (int b = tid; b < c2; b += TPB) {
            int s = nbr[t * MAXN + b];
            int j = invp[s];
            if (j >= 0) atomicAdd(&row[j], w1 * awt[t * MAXN + b]);
        }
    }
    __syncthreads();
    float psum = 0.f;
    for (int j = tid; j < k; j += TPB) {
        float v = (j == r) ? 0.f : row[j];
        psum += v;
        ushort hi = f32_to_bf16(v);
        size_t o = (size_t)r * k + j;
        Chi[o] = hi;
        Clo[o] = f32_to_bf16(v - bf2f(hi));
    }
    for (int o = 32; o; o >>= 1) psum += __shfl_xor(psum, o);
    __shared__ float sh[4];
    if ((tid & 63) == 0) sh[tid >> 6] = psum;
    __syncthreads();
    if (tid == 0) {
        float tot = sh[0] + sh[1] + sh[2] + sh[3];
        dinv[r] = 1.0f / sqrtf(tot + 2.0f);
        selfw[r] = 2.0f;
    }
}

// ---------------- dense augment (levels 2,3): split-K + finalize -----------
__global__ void transpose_aug_hl(const ushort* __restrict__ Ahi, const ushort* __restrict__ Alo,
                                 ushort* __restrict__ T, int n) {
    __shared__ float tile[64][65];
    int c0 = blockIdx.x * 64, r0 = blockIdx.y * 64;
    for (int t = threadIdx.x; t < 4096; t += TPB) {
        int r = t >> 6, c = t & 63;
        size_t o = (size_t)(r0 + r) * n + (c0 + c);
        float v = bf2f(Ahi[o]) + bf2f(Alo[o]);
        if (r0 + r == c0 + c) v += 1.0f;
        tile[c][r] = v;
    }
    __syncthreads();
    for (int t = threadIdx.x; t < 4096; t += TPB) {
        int c = t >> 6, r = t & 63;
        T[(size_t)(c0 + c) * n + (r0 + r)] = f32_to_bf16(tile[c][r]);
    }
}

__global__ void gather_rows_aug_hl(const ushort* __restrict__ Ahi, const ushort* __restrict__ Alo,
                                   const int* __restrict__ perm, ushort* __restrict__ Ag,
                                   int n, int rows) {
    int id = blockIdx.x * TPB + threadIdx.x;
    if (id >= rows * n) return;
    int r = id / n, t = id - r * n;
    int pr = perm[r];
    size_t o = (size_t)pr * n + t;
    float v = bf2f(Ahi[o]) + bf2f(Alo[o]);
    if (pr == t) v += 1.0f;
    Ag[id] = f32_to_bf16(v);
}

__global__ void gather_rows_u16(const ushort* __restrict__ T, const int* __restrict__ perm,
                                ushort* __restrict__ Bg, int n, int rows) {
    int id = blockIdx.x * TPB + threadIdx.x;
    if (id >= rows * n) return;
    int r = id / n, t = id - r * n;
    Bg[id] = T[(size_t)perm[r] * n + t];
}

// split-K accumulate: Caug[r][c] += sum_t Ag[r][t]*Bg[c][t] over k-chunk
__global__ void __launch_bounds__(256)
aug_gemm_acc(const ushort* __restrict__ Ag, const ushort* __restrict__ Bg,
             float* __restrict__ Caug, int K, int ldc, int kpb) {
    __shared__ __align__(16) ushort As[64 * LDK];
    __shared__ __align__(16) ushort Bs[64 * LDK];
    int tid = threadIdx.x;
    int wave = tid >> 6, lane = tid & 63;
    int wr = wave >> 1, wc = wave & 1;
    int m = lane & 15, quad = lane >> 4;
    int i0 = blockIdx.y * 64, j0 = blockIdx.x * 64;
    int kbeg = blockIdx.z * kpb;
    f32x4 acc[2][2];
#pragma unroll
    for (int a = 0; a < 2; ++a)
#pragma unroll
        for (int b = 0; b < 2; ++b) acc[a][b] = (f32x4){0.f, 0.f, 0.f, 0.f};
    const ushort* Ab = Ag + (size_t)i0 * K;
    const ushort* Bb = Bg + (size_t)j0 * K;
    for (int k0 = kbeg; k0 < kbeg + kpb; k0 += 64) {
#pragma unroll
        for (int v = 0; v < 2; ++v) {
            int idx = tid + (v << 8);
            int r = idx >> 3, c8 = idx & 7;
            *(uint4*)&As[r * LDK + c8 * 8] = *(const uint4*)&Ab[(size_t)r * K + k0 + c8 * 8];
            *(uint4*)&Bs[r * LDK + c8 * 8] = *(const uint4*)&Bb[(size_t)r * K + k0 + c8 * 8];
        }
        __syncthreads();
#pragma unroll
        for (int kk = 0; kk < 2; ++kk) {
            bf16x8 af[2], bfr[2];
#pragma unroll
            for (int mi = 0; mi < 2; ++mi)
                af[mi] = *(const bf16x8*)&As[(wr * 32 + mi * 16 + m) * LDK + kk * 32 + quad * 8];
#pragma unroll
            for (int ni = 0; ni < 2; ++ni)
                bfr[ni] = *(const bf16x8*)&Bs[(wc * 32 + ni * 16 + m) * LDK + kk * 32 + quad * 8];
#pragma unroll
            for (int mi = 0; mi < 2; ++mi)
#pragma unroll
                for (int ni = 0; ni < 2; ++ni)
                    acc[mi][ni] = __builtin_amdgcn_mfma_f32_16x16x32_bf16(
                        af[mi], bfr[ni], acc[mi][ni], 0, 0, 0);
        }
        __syncthreads();
    }
#pragma unroll
    for (int mi = 0; mi < 2; ++mi)
#pragma unroll
        for (int ni = 0; ni < 2; ++ni)
#pragma unroll
            for (int r = 0; r < 4; ++r) {
                int gi = i0 + wr * 32 + mi * 16 + quad * 4 + r;
                int gj = j0 + wc * 32 + ni * 16 + m;
                atomicAdd(&Caug[(size_t)gi * ldc + gj], acc[mi][ni][r]);
            }
}

// finalize: diag zero, split hi/lo, rowsum -> dinv/selfw (diag always 0)
__global__ void aug_finalize(const float* __restrict__ Caug, int k,
                             ushort* __restrict__ Chi, ushort* __restrict__ Clo,
                             float* __restrict__ dinv, float* __restrict__ selfw) {
    int r = blockIdx.x, tid = threadIdx.x;
    const float* row = Caug + (size_t)r * k;
    float psum = 0.f;
    for (int j = tid; j < k; j += TPB) {
        float v = (j == r) ? 0.f : row[j];
        psum += v;
        ushort hi = f32_to_bf16(v);
        size_t o = (size_t)r * k + j;
        Chi[o] = hi;
        Clo[o] = f32_to_bf16(v - bf2f(hi));
    }
    for (int o = 32; o; o >>= 1) psum += __shfl_xor(psum, o);
    __shared__ float sh[4];
    if ((tid & 63) == 0) sh[tid >> 6] = psum;
    __syncthreads();
    if (tid == 0) {
        float tot = sh[0] + sh[1] + sh[2] + sh[3];
        dinv[r] = 1.0f / sqrtf(tot + 2.0f);
        selfw[r] = 2.0f;
    }
}

// ---------------- dense GCN aggregation (levels >=1) ----------------
__global__ void __launch_bounds__(256)
gcn_gemm(const ushort* __restrict__ Ahi, const ushort* __restrict__ Alo,
         const ushort* __restrict__ Bhi, const ushort* __restrict__ Blo,
         float* __restrict__ C, int K, int ldc, int kpb) {
    __shared__ __align__(16) ushort sAh[64 * LDK];
    __shared__ __align__(16) ushort sAl[64 * LDK];
    __shared__ __align__(16) ushort sBh[64 * LDK];
    __shared__ __align__(16) ushort sBl[64 * LDK];
    int tid = threadIdx.x;
    int wave = tid >> 6, lane = tid & 63;
    int wr = wave >> 1, wc = wave & 1;
    int m = lane & 15, quad = lane >> 4;
    int i0 = blockIdx.y * 64, j0 = blockIdx.x * 64;
    int kbeg = blockIdx.z * kpb;
    f32x4 acc[2][2];
#pragma unroll
    for (int a = 0; a < 2; ++a)
#pragma unroll
        for (int b = 0; b < 2; ++b) acc[a][b] = (f32x4){0.f, 0.f, 0.f, 0.f};
    for (int k0 = kbeg; k0 < kbeg + kpb; k0 += 64) {
#pragma unroll
        for (int v = 0; v < 2; ++v) {
            int idx = tid + (v << 8);
            int r = idx >> 3, c8 = idx & 7;
            size_t boff = (size_t)(j0 + r) * K + k0 + c8 * 8;
            *(uint4*)&sBh[r * LDK + c8 * 8] = *(const uint4*)&Bhi[boff];
            *(uint4*)&sBl[r * LDK + c8 * 8] = *(const uint4*)&Blo[boff];
            size_t aoff = (size_t)(i0 + r) * K + k0 + c8 * 8;
            *(uint4*)&sAh[r * LDK + c8 * 8] = *(const uint4*)&Ahi[aoff];
            *(uint4*)&sAl[r * LDK + c8 * 8] = *(const uint4*)&Alo[aoff];
        }
        __syncthreads();
#pragma unroll
        for (int kk = 0; kk < 2; ++kk) {
            bf16x8 ah[2], al[2], bh[2], bl[2];
#pragma unroll
            for (int mi = 0; mi < 2; ++mi) {
                ah[mi] = *(const bf16x8*)&sAh[(wr * 32 + mi * 16 + m) * LDK + kk * 32 + quad * 8];
                al[mi] = *(const bf16x8*)&sAl[(wr * 32 + mi * 16 + m) * LDK + kk * 32 + quad * 8];
            }
#pragma unroll
            for (int ni = 0; ni < 2; ++ni) {
                bh[ni] = *(const bf16x8*)&sBh[(wc * 32 + ni * 16 + m) * LDK + kk * 32 + quad * 8];
                bl[ni] = *(const bf16x8*)&sBl[(wc * 32 + ni * 16 + m) * LDK + kk * 32 + quad * 8];
            }
#pragma unroll
            for (int mi = 0; mi < 2; ++mi)
#pragma unroll
                for (int ni = 0; ni < 2; ++ni) {
                    acc[mi][ni] = __builtin_amdgcn_mfma_f32_16x16x32_bf16(ah[mi], bh[ni], acc[mi][ni], 0, 0, 0);
                    acc[mi][ni] = __builtin_amdgcn_mfma_f32_16x16x32_bf16(ah[mi], bl[ni], acc[mi][ni], 0, 0, 0);
                    acc[mi][ni] = __builtin_amdgcn_mfma_f32_16x16x32_bf16(al[mi], bh[ni], acc[mi][ni], 0, 0, 0);
                }
        }
        __syncthreads();
    }
#pragma unroll
    for (int mi = 0; mi < 2; ++mi)
#pragma unroll
        for (int ni = 0; ni < 2; ++ni)
#pragma unroll
            for (int r = 0; r < 4; ++r) {
                int gi = i0 + wr * 32 + mi * 16 + quad * 4 + r;
                int gj = j0 + wc * 32 + ni * 16 + m;
                atomicAdd(&C[(size_t)gi * ldc + gj], acc[mi][ni][r]);
            }
}

__global__ void build_yT(const float* __restrict__ xw, const float* __restrict__ dinv,
                         ushort* __restrict__ Bhi, ushort* __restrict__ Blo, int n, int f) {
    __shared__ float t[64][65];
    int k0 = blockIdx.x * 64, c0 = blockIdx.y * 64;
#pragma unroll
    for (int v = 0; v < 16; ++v) {
        int idx = threadIdx.x + v * 256;
        int r = idx >> 6, c = idx & 63;
        t[r][c] = xw[(size_t)(k0 + r) * f + (c0 + c)] * dinv[k0 + r];
    }
    __syncthreads();
#pragma unroll
    for (int v = 0; v < 16; ++v) {
        int idx = threadIdx.x + v * 256;
        int c = idx >> 6, k = idx & 63;
        float val = t[k][c];
        ushort hi = f32_to_bf16(val);
        size_t o = (size_t)(c0 + c) * n + (k0 + k);
        Bhi[o] = hi;
        Blo[o] = f32_to_bf16(val - bf2f(hi));
    }
}

__global__ void gcn_epilogue(const float* __restrict__ C, const float* __restrict__ xw,
                             const float* __restrict__ dinv, const float* __restrict__ selfw,
                             const float* __restrict__ b, float* __restrict__ out,
                             int n, int f, int relu) {
    int id = blockIdx.x * TPB + threadIdx.x;
    if (id >= n * f) return;
    int i = id / f, c = id - i * f;
    float y = xw[id] * dinv[i];
    float v = dinv[i] * (C[id] + selfw[i] * y) + b[c];
    if (relu) v = fmaxf(v, 0.f);
    out[id] = v;
}

// ---------------- pooling ----------------
__global__ void vec_norm(const float* __restrict__ p, int f, float* out) {
    float s = 0.f;
    for (int c = threadIdx.x; c < f; c += 64) { float v = p[c]; s += v * v; }
    for (int o = 32; o; o >>= 1) s += __shfl_xor(s, o);
    if (threadIdx.x == 0) out[0] = sqrtf(s);
}

__global__ void score_kernel(const float* __restrict__ x, const float* __restrict__ p,
                             const float* __restrict__ nrm, float* __restrict__ s, int n, int f) {
    int i = blockIdx.x * TPB + threadIdx.x;
    if (i >= n) return;
    float a = 0.f;
    for (int c = 0; c < f; ++c) a += x[(size_t)i * f + c] * p[c];
    s[i] = tanhf(a / nrm[0]);
}

__global__ void rank_count(const float* __restrict__ s, int n, int* __restrict__ rank) {
    __shared__ float sj[256];
    int i = blockIdx.x * 256 + threadIdx.x;
    int j0 = blockIdx.y * 256;
    sj[threadIdx.x] = s[j0 + threadIdx.x];
    float si = s[i];
    __syncthreads();
    int r = 0;
#pragma unroll 8
    for (int jj = 0; jj < 256; ++jj) {
        float v = sj[jj];
        r += (v > si) || (v == si && (j0 + jj) < i);
    }
    atomicAdd(&rank[i], r);
}

__global__ void scatter_topk(const float* __restrict__ s, const int* __restrict__ rank,
                             int n, int k, int* __restrict__ perm, float* __restrict__ vals) {
    int i = blockIdx.x * TPB + threadIdx.x;
    if (i >= n) return;
    int r = rank[i];
    if (r < k) { perm[r] = i; vals[r] = s[i]; }
}

__global__ void gather_feat(const float* __restrict__ x, const int* __restrict__ perm,
                            const float* __restrict__ vals, int k, int f, float* __restrict__ h) {
    int id = blockIdx.x * TPB + threadIdx.x;
    if (id >= k * f) return;
    int r = id / f, c = id - r * f;
    h[id] = x[(size_t)perm[r] * f + c] * vals[r];
}

// ---------------- up path ----------------
__global__ void copy_k(const float* __restrict__ s, float* __restrict__ d, int n) {
    int id = blockIdx.x * TPB + threadIdx.x;
    if (id < n) d[id] = s[id];
}

__global__ void scatter_add_rows(const float* __restrict__ s, const int* __restrict__ perm,
                                 int k, int f, float* __restrict__ t) {
    int id = blockIdx.x * TPB + threadIdx.x;
    if (id >= k * f) return;
    int r = id / f, c = id - r * f;
    t[(size_t)perm[r] * f + c] += s[id];
}

// ---------------- layernorm ----------------
__global__ void layernorm(const float* __restrict__ h, const float* __restrict__ g,
                          const float* __restrict__ b, float* __restrict__ u, int n) {
    int i = blockIdx.x;
    int t = threadIdx.x;
    float v = h[(size_t)i * 128 + t];
    __shared__ float s0[2], s1[2];
    float sum = v;
    for (int o = 32; o; o >>= 1) sum += __shfl_xor(sum, o);
    if ((t & 63) == 0) s0[t >> 6] = sum;
    __syncthreads();
    float mu = (s0[0] + s0[1]) * (1.0f / 128.0f);
    float d = v - mu;
    float sq = d * d;
    for (int o = 32; o; o >>= 1) sq += __shfl_xor(sq, o);
    if ((t & 63) == 0) s1[t >> 6] = sq;
    __syncthreads();
    float var = (s1[0] + s1[1]) * (1.0f / 128.0f);
    u[(size_t)i * 128 + t] = d / sqrtf(var + 1e-6f) * g[t] + b[t];
}

// ---------------- dense projections via split-bf16 MFMA (split-K) ---------
__global__ void transpose_split(const float* __restrict__ W, ushort* __restrict__ Bhi,
                                ushort* __restrict__ Blo, int K, int N) {
    __shared__ float tile[64][65];
    int n0 = blockIdx.x * 64, k0 = blockIdx.y * 64;
    for (int t = threadIdx.x; t < 4096; t += TPB) {
        int r = t >> 6, c = t & 63;
        tile[r][c] = W[(size_t)(k0 + r) * N + (n0 + c)];
    }
    __syncthreads();
    for (int t = threadIdx.x; t < 4096; t += TPB) {
        int c = t >> 6, r = t & 63;
        float v = tile[r][c];
        ushort hi = f32_to_bf16(v);
        size_t o = (size_t)(n0 + c) * K + (k0 + r);
        Bhi[o] = hi;
        Blo[o] = f32_to_bf16(v - bf2f(hi));
    }
}

__global__ void init_bias(float* __restrict__ C, const float* __restrict__ bias, int n, int f) {
    int id = blockIdx.x * TPB + threadIdx.x;
    if (id >= n * f) return;
    C[id] = bias ? bias[id % f] : 0.f;
}

// C[i][j] += sum_{k in chunk} A[i][k]*B[j][k]; A fp32 split in staging.
__global__ void __launch_bounds__(256)
gemm_bt_split(const float* __restrict__ A, const ushort* __restrict__ Bhi,
              const ushort* __restrict__ Blo, float* __restrict__ C,
              int K, int N, int kpb) {
    __shared__ __align__(16) ushort sAh[64 * LDK];
    __shared__ __align__(16) ushort sAl[64 * LDK];
    __shared__ __align__(16) ushort sBh[64 * LDK];
    __shared__ __align__(16) ushort sBl[64 * LDK];
    int tid = threadIdx.x;
    int wave = tid >> 6, lane = tid & 63;
    int wr = wave >> 1, wc = wave & 1;
    int m = lane & 15, quad = lane >> 4;
    int i0 = blockIdx.y * 64, j0 = blockIdx.x * 64;
    int kbeg = blockIdx.z * kpb;
    f32x4 acc[2][2];
#pragma unroll
    for (int a = 0; a < 2; ++a)
#pragma unroll
        for (int b = 0; b < 2; ++b) acc[a][b] = (f32x4){0.f, 0.f, 0.f, 0.f};
    for (int k0 = kbeg; k0 < kbeg + kpb; k0 += 64) {
#pragma unroll
        for (int v = 0; v < 2; ++v) {
            int idx = tid + (v << 8);
            int r = idx >> 3, c8 = idx & 7;
            size_t boff = (size_t)(j0 + r) * K + k0 + c8 * 8;
            *(uint4*)&sBh[r * LDK + c8 * 8] = *(const uint4*)&Bhi[boff];
            *(uint4*)&sBl[r * LDK + c8 * 8] = *(const uint4*)&Blo[boff];
            size_t aoff = (size_t)(i0 + r) * K + k0 + c8 * 8;
            float4 fa = *(const float4*)&A[aoff];
            float4 fb = *(const float4*)&A[aoff + 4];
            ushort h0 = f32_to_bf16(fa.x), h1 = f32_to_bf16(fa.y);
            ushort h2 = f32_to_bf16(fa.z), h3 = f32_to_bf16(fa.w);
            ushort h4 = f32_to_bf16(fb.x), h5 = f32_to_bf16(fb.y);
            ushort h6 = f32_to_bf16(fb.z), h7 = f32_to_bf16(fb.w);
            uint4 ph, pl;
            ph.x = (uint)h0 | ((uint)h1 << 16);
            ph.y = (uint)h2 | ((uint)h3 << 16);
            ph.z = (uint)h4 | ((uint)h5 << 16);
            ph.w = (uint)h6 | ((uint)h7 << 16);
            pl.x = (uint)f32_to_bf16(fa.x - bf2f(h0)) | ((uint)f32_to_bf16(fa.y - bf2f(h1)) << 16);
            pl.y = (uint)f32_to_bf16(fa.z - bf2f(h2)) | ((uint)f32_to_bf16(fa.w - bf2f(h3)) << 16);
            pl.z = (uint)f32_to_bf16(fb.x - bf2f(h4)) | ((uint)f32_to_bf16(fb.y - bf2f(h5)) << 16);
            pl.w = (uint)f32_to_bf16(fb.z - bf2f(h6)) | ((uint)f32_to_bf16(fb.w - bf2f(h7)) << 16);
            *(uint4*)&sAh[r * LDK + c8 * 8] = ph;
            *(uint4*)&sAl[r * LDK + c8 * 8] = pl;
        }
        __syncthreads();
#pragma unroll
        for (int kk = 0; kk < 2; ++kk) {
            bf16x8 ah[2], al[2], bh[2], bl[2];
#pragma unroll
            for (int mi = 0; mi < 2; ++mi) {
                ah[mi] = *(const bf16x8*)&sAh[(wr * 32 + mi * 16 + m) * LDK + kk * 32 + quad * 8];
                al[mi] = *(const bf16x8*)&sAl[(wr * 32 + mi * 16 + m) * LDK + kk * 32 + quad * 8];
            }
#pragma unroll
            for (int ni = 0; ni < 2; ++ni) {
                bh[ni] = *(const bf16x8*)&sBh[(wc * 32 + ni * 16 + m) * LDK + kk * 32 + quad * 8];
                bl[ni] = *(const bf16x8*)&sBl[(wc * 32 + ni * 16 + m) * LDK + kk * 32 + quad * 8];
            }
#pragma unroll
            for (int mi = 0; mi < 2; ++mi)
#pragma unroll
                for (int ni = 0; ni < 2; ++ni) {
                    acc[mi][ni] = __builtin_amdgcn_mfma_f32_16x16x32_bf16(ah[mi], bh[ni], acc[mi][ni], 0, 0, 0);
                    acc[mi][ni] = __builtin_amdgcn_mfma_f32_16x16x32_bf16(ah[mi], bl[ni], acc[mi][ni], 0, 0, 0);
                    acc[mi][ni] = __builtin_amdgcn_mfma_f32_16x16x32_bf16(al[mi], bh[ni], acc[mi][ni], 0, 0, 0);
                }
        }
        __syncthreads();
    }
#pragma unroll
    for (int mi = 0; mi < 2; ++mi)
#pragma unroll
        for (int ni = 0; ni < 2; ++ni)
#pragma unroll
            for (int r = 0; r < 4; ++r) {
                int gi = i0 + wr * 32 + mi * 16 + quad * 4 + r;
                int gj = j0 + wc * 32 + ni * 16 + m;
                atomicAdd(&C[(size_t)gi * N + gj], acc[mi][ni][r]);
            }
}

// ---------------- GAT ----------------
// block per node j; wave w computes head w's dot products.
__global__ void attn_coef2(const float* __restrict__ hf, const float* __restrict__ asrc,
                           const float* __restrict__ adst, float* __restrict__ es,
                           float* __restrict__ ed, int heads) {
    int j = blockIdx.x;
    int wave = threadIdx.x >> 6, lane = threadIdx.x & 63;
    if (wave >= heads) return;
    const float* hp = hf + (size_t)j * heads * 128 + wave * 128;
    float v0 = hp[lane], v1 = hp[lane + 64];
    float a = v0 * asrc[wave * 128 + lane] + v1 * asrc[wave * 128 + lane + 64];
    float d = v0 * adst[wave * 128 + lane] + v1 * adst[wave * 128 + lane + 64];
    for (int o = 32; o; o >>= 1) { a += __shfl_xor(a, o); d += __shfl_xor(d, o); }
    if (lane == 0) { es[j * heads + wave] = a; ed[j * heads + wave] = d; }
}

__global__ void gat_sparse(const int* __restrict__ nbr, const int* __restrict__ ncnt, int n,
                           const float* __restrict__ hf, const float* __restrict__ es,
                           const float* __restrict__ ed, const float* __restrict__ bias,
                           const float* __restrict__ resid, float* __restrict__ out,
                           int heads, int mode) {
    int i = blockIdx.x;
    int tid = threadIdx.x;
    __shared__ int idx[MAXN];
    __shared__ float lg[MAXN * 4];
    __shared__ float hmax[4], hsum[4];
    int m = ncnt[i];
    for (int t = tid; t < m; t += TPB) idx[t] = nbr[i * MAXN + t];
    __syncthreads();
    for (int t = tid; t < m * heads; t += TPB) {
        int jl = t / heads, h = t - jl * heads;
        float l = ed[i * heads + h] + es[idx[jl] * heads + h];
        lg[jl * heads + h] = (l > 0.f) ? l : 0.2f * l;
    }
    __syncthreads();
    int h = tid >> 6, lane = tid & 63;
    if (h < heads) {
        float mx = -3.4e38f;
        for (int jl = lane; jl < m; jl += 64) mx = fmaxf(mx, lg[jl * heads + h]);
        for (int o = 32; o; o >>= 1) mx = fmaxf(mx, __shfl_xor(mx, o));
        if (lane == 0) hmax[h] = mx;
    }
    __syncthreads();
    if (h < heads) {
        float mx = hmax[h];
        float sm = 0.f;
        for (int jl = lane; jl < m; jl += 64) {
            float p = expf(lg[jl * heads + h] - mx);
            lg[jl * heads + h] = p;
            sm += p;
        }
        for (int o = 32; o; o >>= 1) sm += __shfl_xor(sm, o);
        if (lane == 0) hsum[h] = sm;
    }
    __syncthreads();
    int width = heads * 128;
    for (int o = tid; o < width; o += TPB) {
        int hh = o >> 7;
        float acc = 0.f;
        for (int jl = 0; jl < m; ++jl)
            acc += lg[jl * heads + hh] * hf[(size_t)idx[jl] * width + o];
        float v = acc / hsum[hh] + bias[o];
        if (mode == 0) v = (v > 0.f) ? v : expm1f(v);
        else v += resid[(size_t)i * width + o];
        out[(size_t)i * width + o] = v;
    }
}

// ---------------------------------------------------------------------------
static inline int cdiv(int a, int b) { return (a + b - 1) / b; }

static int pick_z(int gx, int gy, int K) {
    int z = 1;
    while (gx * gy * z < 384 && K / (2 * z) >= 64) z <<= 1;
    return z;
}

static void run_gcn_dense(hipStream_t stream, const ushort* Ahi, const ushort* Alo,
                          int n, const float* xin, int fin,
                          const float* W, const float* bias, int f,
                          const float* dinv, const float* selfw,
                          float* xw, ushort* yThi, ushort* yTlo, float* Cp,
                          float* out, int relu) {
    xw_gemm<<<cdiv(n, TPB / f), TPB, 0, stream>>>(xin, W, xw, n, fin, f);
    build_yT<<<dim3(n / 64, f / 64), TPB, 0, stream>>>(xw, dinv, yThi, yTlo, n, f);
    hipMemsetAsync(Cp, 0, (size_t)n * f * sizeof(float), stream);
    int z = pick_z(f / 64, n / 64, n);
    gcn_gemm<<<dim3(f / 64, n / 64, z), TPB, 0, stream>>>(Ahi, Alo, yThi, yTlo, Cp, n, f, n / z);
    gcn_epilogue<<<cdiv(n * f, TPB), TPB, 0, stream>>>(Cp, xw, dinv, selfw, bias, out, n, f, relu);
}

static void run_gcn_sparse(hipStream_t stream, const int* nbr, const float* awt,
                           const int* acnt, int n, const float* xin, int fin,
                           const float* W, const float* bias, int f,
                           const float* dinv, const float* selfw,
                           float* xw, float* out, int relu) {
    xw_gemm<<<cdiv(n, TPB / f), TPB, 0, stream>>>(xin, W, xw, n, fin, f);
    spmv_gcn<<<n, f, 0, stream>>>(nbr, awt, acnt, xw, dinv, selfw, bias, out, f, relu);
}

static void run_topk(hipStream_t stream, const float* score, int n, int k, int* rank,
                     int* perm, float* vals) {
    hipMemsetAsync(rank, 0, n * sizeof(int), stream);
    rank_count<<<dim3(n / 256, n / 256), 256, 0, stream>>>(score, n, rank);
    scatter_topk<<<cdiv(n, TPB), TPB, 0, stream>>>(score, rank, n, k, perm, vals);
}

// dense augment level: out A(k x k) from A(n x n) hi/lo + perm
static void run_aug_dense(hipStream_t stream, const ushort* Ahi, const ushort* Alo, int n,
                          const int* perm, int k, ushort* Tbf, ushort* Agb, ushort* Bgb,
                          float* Caug, ushort* Chi, ushort* Clo, float* dinv, float* selfw) {
    transpose_aug_hl<<<dim3(n / 64, n / 64), TPB, 0, stream>>>(Ahi, Alo, Tbf, n);
    gather_rows_aug_hl<<<cdiv(k * n, TPB), TPB, 0, stream>>>(Ahi, Alo, perm, Agb, n, k);
    gather_rows_u16<<<cdiv(k * n, TPB), TPB, 0, stream>>>(Tbf, perm, Bgb, n, k);
    hipMemsetAsync(Caug, 0, (size_t)k * k * sizeof(float), stream);
    int z = 8;
    aug_gemm_acc<<<dim3(k / 64, k / 64, z), TPB, 0, stream>>>(Agb, Bgb, Caug, n, k, n / z);
    aug_finalize<<<k, TPB, 0, stream>>>(Caug, k, Chi, Clo, dinv, selfw);
}

extern "C" void kernel_launch(void* const* d_in, const int* in_sizes, int n_in,
                              void* d_out, int out_size, void* d_ws, size_t ws_size,
                              hipStream_t stream) {
    const float* x   = (const float*)d_in[0];
    const int*   ei  = (const int*)d_in[1];
    const float* w0  = (const float*)d_in[2];  const float* b0  = (const float*)d_in[3];
    const float* w1  = (const float*)d_in[4];  const float* b1  = (const float*)d_in[5];
    const float* w2  = (const float*)d_in[6];  const float* b2  = (const float*)d_in[7];
    const float* w3  = (const float*)d_in[8];  const float* b3  = (const float*)d_in[9];
    const float* p1  = (const float*)d_in[10];
    const float* p2  = (const float*)d_in[11];
    const float* p3  = (const float*)d_in[12];
    const float* uw0 = (const float*)d_in[13]; const float* ub0 = (const float*)d_in[14];
    const float* uw1 = (const float*)d_in[15]; const float* ub1 = (const float*)d_in[16];
    const float* uw2 = (const float*)d_in[17]; const float* ub2 = (const float*)d_in[18];
    const float* lng = (const float*)d_in[19]; const float* lnb = (const float*)d_in[20];
    const float* rw  = (const float*)d_in[21]; const float* rb  = (const float*)d_in[22];
    const float* g1w = (const float*)d_in[23];
    const float* g1as = (const float*)d_in[24]; const float* g1ad = (const float*)d_in[25];
    const float* g1b = (const float*)d_in[26];
    const float* g2w = (const float*)d_in[27];
    const float* g2as = (const float*)d_in[28]; const float* g2ad = (const float*)d_in[29];
    const float* g2b = (const float*)d_in[30];

    const int N = 4096, E = 65536;
    const int K1 = 2048, K2 = 1024, K3 = 512;

    float* base = (float*)d_ws;
    size_t off = 0;
    auto alloc = [&](size_t nf) { float* p = base + off; off += (nf + 63) & ~(size_t)63; return p; };

    ushort* A0b  = (ushort*)alloc((size_t)N * N / 2);
    ushort* A1hi = (ushort*)alloc((size_t)K1 * K1 / 2);
    ushort* A1lo = (ushort*)alloc((size_t)K1 * K1 / 2);
    ushort* A2hi = (ushort*)alloc((size_t)K2 * K2 / 2);
    ushort* A2lo = (ushort*)alloc((size_t)K2 * K2 / 2);
    ushort* A3hi = (ushort*)alloc((size_t)K3 * K3 / 2);
    ushort* A3lo = (ushort*)alloc((size_t)K3 * K3 / 2);
    ushort* Tbf  = (ushort*)alloc((size_t)K1 * K1 / 2);
    ushort* Agb  = (ushort*)alloc((size_t)K2 * K1 / 2);
    ushort* Bgb  = (ushort*)alloc((size_t)K2 * K1 / 2);
    ushort* yThi = (ushort*)alloc((size_t)128 * N / 2);
    ushort* yTlo = (ushort*)alloc((size_t)128 * N / 2);
    ushort* Whi  = (ushort*)alloc((size_t)512 * 128 / 2);
    ushort* Wlo  = (ushort*)alloc((size_t)512 * 128 / 2);
    float* Caug  = alloc((size_t)K2 * K2);
    float* Cp    = alloc((size_t)N * 128);
    float* x0    = alloc((size_t)N * 64);
    float* x1    = alloc((size_t)K1 * 64);
    float* x2    = alloc((size_t)K2 * 64);
    float* x3    = alloc((size_t)K3 * 64);
    float* h1    = alloc((size_t)K1 * 64);
    float* h2    = alloc((size_t)K2 * 64);
    float* h3    = alloc((size_t)K3 * 64);
    float* xw    = alloc((size_t)N * 128);
    float* dinv0 = alloc(N);  float* selfw0 = alloc(N);
    float* dinv1 = alloc(K1); float* selfw1 = alloc(K1);
    float* dinv2 = alloc(K2); float* selfw2 = alloc(K2);
    float* dinv3 = alloc(K3); float* selfw3 = alloc(K3);
    int*   deg   = (int*)alloc(N);
    int*   diag  = (int*)alloc(N);
    float* score = alloc(N);
    int*   rank  = (int*)alloc(N);
    float* vals1 = alloc(K1); float* vals2 = alloc(K2); float* vals3 = alloc(K3);
    int*   perm1 = (int*)alloc(K1); int* perm2 = (int*)alloc(K2); int* perm3 = (int*)alloc(K3);
    int*   nbr   = (int*)alloc((size_t)N * MAXN);
    float* awt   = alloc((size_t)N * MAXN);
    int*   acnt  = (int*)alloc(N);
    int*   invp  = (int*)alloc(N);
    float* t2    = alloc((size_t)K2 * 64);
    float* t1    = alloc((size_t)K1 * 64);
    float* t0    = alloc((size_t)N * 64);
    float* hfin  = alloc((size_t)N * 128);
    float* u     = alloc((size_t)N * 128);
    float* resid = alloc((size_t)N * 128);
    float* hf1   = alloc((size_t)N * 512);
    float* es1   = alloc((size_t)N * 4); float* ed1 = alloc((size_t)N * 4);
    float* g1    = alloc((size_t)N * 512);
    float* hf2   = alloc((size_t)N * 128);
    float* es2   = alloc(N); float* ed2 = alloc(N);
    float* pn    = alloc(64);
    (void)ws_size; (void)n_in; (void)in_sizes; (void)out_size;

    // ---- A0 build + degrees + CSR ----
    hipMemsetAsync(A0b, 0, (size_t)N * N * sizeof(ushort), stream);
    hipMemsetAsync(deg, 0, N * sizeof(int), stream);
    hipMemsetAsync(diag, 0, N * sizeof(int), stream);
    scatter_edges_b<<<cdiv(E, TPB), TPB, 0, stream>>>(ei, E, A0b, N, deg, diag);
    dinv_from_deg<<<cdiv(N, TPB), TPB, 0, stream>>>(deg, diag, N, dinv0, selfw0);
    extract_csr<<<N, TPB, 0, stream>>>(A0b, N, nbr, awt, acnt);

    // ---- down level 0 (sparse) ----
    run_gcn_sparse(stream, nbr, awt, acnt, N, x, 3, w0, b0, 64, dinv0, selfw0, xw, x0, 1);

    // ---- level 1: topk + sparse SpGEMM augment ----
    vec_norm<<<1, 64, 0, stream>>>(p1, 64, pn);
    score_kernel<<<cdiv(N, TPB), TPB, 0, stream>>>(x0, p1, pn, score, N, 64);
    run_topk(stream, score, N, K1, rank, perm1, vals1);
    hipMemsetAsync(invp, 0xFF, N * sizeof(int), stream);
    scatter_invperm<<<cdiv(K1, TPB), TPB, 0, stream>>>(perm1, K1, invp);
    spgemm_aug<<<K1, TPB, 0, stream>>>(nbr, awt, acnt, perm1, invp, K1,
                                       A1hi, A1lo, dinv1, selfw1);
    gather_feat<<<cdiv(K1 * 64, TPB), TPB, 0, stream>>>(x0, perm1, vals1, K1, 64, h1);
    run_gcn_dense(stream, A1hi, A1lo, K1, h1, 64, w1, b1, 64,
                  dinv1, selfw1, xw, yThi, yTlo, Cp, x1, 1);

    // ---- level 2 (dense split-K augment) ----
    vec_norm<<<1, 64, 0, stream>>>(p2, 64, pn);
    score_kernel<<<cdiv(K1, TPB), TPB, 0, stream>>>(x1, p2, pn, score, K1, 64);
    run_topk(stream, score, K1, K2, rank, perm2, vals2);
    run_aug_dense(stream, A1hi, A1lo, K1, perm2, K2, Tbf, Agb, Bgb, Caug,
                  A2hi, A2lo, dinv2, selfw2);
    gather_feat<<<cdiv(K2 * 64, TPB), TPB, 0, stream>>>(x1, perm2, vals2, K2, 64, h2);
    run_gcn_dense(stream, A2hi, A2lo, K2, h2, 64, w2, b2, 64,
                  dinv2, selfw2, xw, yThi, yTlo, Cp, x2, 1);

    // ---- level 3 (dense split-K augment) ----
    vec_norm<<<1, 64, 0, stream>>>(p3, 64, pn);
    score_kernel<<<cdiv(K2, TPB), TPB, 0, stream>>>(x2, p3, pn, score, K2, 64);
    run_topk(stream, score, K2, K3, rank, perm3, vals3);
    run_aug_dense(stream, A2hi, A2lo, K2, perm3, K3, Tbf, Agb, Bgb, Caug,
                  A3hi, A3lo, dinv3, selfw3);
    gather_feat<<<cdiv(K3 * 64, TPB), TPB, 0, stream>>>(x2, perm3, vals3, K3, 64, h3);
    run_gcn_dense(stream, A3hi, A3lo, K3, h3, 64, w3, b3, 64,
                  dinv3, selfw3, xw, yThi, yTlo, Cp, x3, 1);

    // ---- up path ----
    copy_k<<<cdiv(K2 * 64, TPB), TPB, 0, stream>>>(x2, t2, K2 * 64);
    scatter_add_rows<<<cdiv(K3 * 64, TPB), TPB, 0, stream>>>(x3, perm3, K3, 64, t2);
    run_gcn_dense(stream, A2hi, A2lo, K2, t2, 64, uw0, ub0, 64,
                  dinv2, selfw2, xw, yThi, yTlo, Cp, h2, 1);

    copy_k<<<cdiv(K1 * 64, TPB), TPB, 0, stream>>>(x1, t1, K1 * 64);
    scatter_add_rows<<<cdiv(K2 * 64, TPB), TPB, 0, stream>>>(h2, perm2, K2, 64, t1);
    run_gcn_dense(stream, A1hi, A1lo, K1, t1, 64, uw1, ub1, 64,
                  dinv1, selfw1, xw, yThi, yTlo, Cp, h1, 1);

    copy_k<<<cdiv(N * 64, TPB), TPB, 0, stream>>>(x0, t0, N * 64);
    scatter_add_rows<<<cdiv(K1 * 64, TPB), TPB, 0, stream>>>(h1, perm1, K1, 64, t0);
    run_gcn_sparse(stream, nbr, awt, acnt, N, t0, 64, uw2, ub2, 128,
                   dinv0, selfw0, xw, hfin, 0);

    // ---- layernorm + residual (split-K) ----
    layernorm<<<N, 128, 0, stream>>>(hfin, lng, lnb, u, N);
    transpose_split<<<dim3(2, 2), TPB, 0, stream>>>(rw, Whi, Wlo, 128, 128);
    init_bias<<<cdiv(N * 128, TPB), TPB, 0, stream>>>(resid, rb, N, 128);
    gemm_bt_split<<<dim3(2, N / 64, 2), TPB, 0, stream>>>(u, Whi, Wlo, resid, 128, 128, 64);

    // ---- GAT layer 1 (4 heads, concat, ELU) ----
    transpose_split<<<dim3(8, 2), TPB, 0, stream>>>(g1w, Whi, Wlo, 128, 512);
    init_bias<<<cdiv(N * 512, TPB), TPB, 0, stream>>>(hf1, nullptr, N, 512);
    gemm_bt_split<<<dim3(8, N / 64, 2), TPB, 0, stream>>>(u, Whi, Wlo, hf1, 128, 512, 64);
    attn_coef2<<<N, 256, 0, stream>>>(hf1, g1as, g1ad, es1, ed1, 4);
    gat_sparse<<<N, TPB, 0, stream>>>(nbr, acnt, N, hf1, es1, ed1, g1b, nullptr, g1, 4, 0);

    // ---- GAT layer 2 (1 head) + residual ----
    transpose_split<<<dim3(2, 8), TPB, 0, stream>>>(g2w, Whi, Wlo, 512, 128);
    init_bias<<<cdiv(N * 128, TPB), TPB, 0, stream>>>(hf2, nullptr, N, 128);
    gemm_bt_split<<<dim3(2, N / 64, 4), TPB, 0, stream>>>(g1, Whi, Wlo, hf2, 512, 128, 128);
    attn_coef2<<<N, 64, 0, stream>>>(hf2, g2as, g2ad, es2, ed2, 1);
    gat_sparse<<<N, TPB, 0, stream>>>(nbr, acnt, N, hf2, es2, ed2, g2b, resid, (float*)d_out, 1, 1);
}